// Round 5
// baseline (5658.831 us; speedup 1.0000x reference)
//
#include <hip/hip_runtime.h>
#include <hip/hip_bf16.h>
#include <stdint.h>

#define NB 8
#define NN 8192
#define NC 64
#define NS 2048
#define NK 32
#define NCOL (NB*NS*NK)   // 524288 columns (b,s,n)

typedef float v2f __attribute__((ext_vector_type(2)));

// ---------- bf16 helpers (RNE) ----------
__device__ __forceinline__ unsigned short f2bf(float x) {
    union { float f; unsigned u; } c; c.f = x;
    unsigned r = c.u + 0x7fffu + ((c.u >> 16) & 1u);
    return (unsigned short)(r >> 16);
}
__device__ __forceinline__ float bf2f(unsigned v16) {
    union { float f; unsigned u; } c; c.u = v16 << 16;
    return c.f;
}

// ---------- DPP cross-lane helpers (VALU-speed, no LDS) ----------
// row_shr:n = 0x110|n, row_bcast15 = 0x142, row_bcast31 = 0x143
template<int CTRL>
__device__ __forceinline__ float dpp_add_f32(float x) {   // zero-fill identity
    int o = __builtin_amdgcn_update_dpp(0, __float_as_int(x), CTRL, 0xf, 0xf, true);
    return x + __int_as_float(o);
}
template<int CTRL>
__device__ __forceinline__ float dpp_max_f32(float x) {   // self identity
    int o = __builtin_amdgcn_update_dpp(__float_as_int(x), __float_as_int(x), CTRL, 0xf, 0xf, false);
    return fmaxf(x, __int_as_float(o));
}
template<int CTRL>
__device__ __forceinline__ float dpp_min_f32(float x) {   // self identity
    int o = __builtin_amdgcn_update_dpp(__float_as_int(x), __float_as_int(x), CTRL, 0xf, 0xf, false);
    return fminf(x, __int_as_float(o));
}
template<int CTRL>
__device__ __forceinline__ unsigned dpp_max_u32(unsigned x) {  // self identity
    int o = __builtin_amdgcn_update_dpp((int)x, (int)x, CTRL, 0xf, 0xf, false);
    unsigned ou = (unsigned)o;
    return x > ou ? x : ou;   // v_max_u32
}
template<int CTRL, int RM>
__device__ __forceinline__ unsigned dpp_add_u32(unsigned x) {  // zero-fill, row-masked
    int o = __builtin_amdgcn_update_dpp(0, (int)x, CTRL, RM, 0xf, true);
    return x + (unsigned)o;
}
__device__ __forceinline__ float wave_red_min(float x) {  // full 64-lane min -> all lanes
    x = dpp_min_f32<0x111>(x); x = dpp_min_f32<0x112>(x);
    x = dpp_min_f32<0x114>(x); x = dpp_min_f32<0x118>(x);
    x = dpp_min_f32<0x142>(x); x = dpp_min_f32<0x143>(x);
    return __int_as_float(__builtin_amdgcn_readlane(__float_as_int(x), 63));
}
__device__ __forceinline__ float wave_red_max(float x) {  // full 64-lane max -> all lanes
    x = dpp_max_f32<0x111>(x); x = dpp_max_f32<0x112>(x);
    x = dpp_max_f32<0x114>(x); x = dpp_max_f32<0x118>(x);
    x = dpp_max_f32<0x142>(x); x = dpp_max_f32<0x143>(x);
    return __int_as_float(__builtin_amdgcn_readlane(__float_as_int(x), 63));
}
__device__ __forceinline__ v2f relu2(v2f v) {
    v.x = fmaxf(v.x, 0.f); v.y = fmaxf(v.y, 0.f); return v;
}

// ============================================================================
// 0) Spatial partition: counting sort on top-11 Morton bits (2048 buckets).
//    Any permutation is CORRECT (ordering only affects pruning rate); FPS
//    tie-breaking uses original indices.
// ============================================================================
__device__ __forceinline__ unsigned expand_bits10(unsigned v) {
    v = (v * 0x00010001u) & 0xFF0000FFu;
    v = (v * 0x00000101u) & 0x0F00F00Fu;
    v = (v * 0x00000011u) & 0xC30C30C3u;
    v = (v * 0x00000005u) & 0x49249249u;
    return v;
}
__global__ __launch_bounds__(1024) void sort_kernel(const float* __restrict__ xyz,
    float4* __restrict__ sorted)
{
    __shared__ unsigned cnt[2048];     // bucket counts -> start offsets
    __shared__ unsigned codes[NN];     // bucket id per point (32 KB)
    __shared__ unsigned wsum[16];
    const int b = blockIdx.x;
    const int tid = threadIdx.x;
    const int w = tid >> 6;
    const int lane = tid & 63;
    const float* xb = xyz + (size_t)b * NN * 3;
    cnt[tid] = 0; cnt[tid + 1024] = 0;
    __syncthreads();
    for (int p = tid; p < NN; p += 1024) {
        float x = xb[3*p+0], y = xb[3*p+1], z = xb[3*p+2];
        int qx = (int)(x * 1024.f); qx = qx < 0 ? 0 : (qx > 1023 ? 1023 : qx);
        int qy = (int)(y * 1024.f); qy = qy < 0 ? 0 : (qy > 1023 ? 1023 : qy);
        int qz = (int)(z * 1024.f); qz = qz < 0 ? 0 : (qz > 1023 ? 1023 : qz);
        unsigned m = expand_bits10((unsigned)qx)
                   | (expand_bits10((unsigned)qy) << 1)
                   | (expand_bits10((unsigned)qz) << 2);
        unsigned bk = m >> 19;                 // top 11 of 30 bits
        codes[p] = bk;
        atomicAdd(&cnt[bk], 1u);
    }
    __syncthreads();
    // exclusive scan of 2048 counts: thread t owns pair (2t, 2t+1)
    unsigned c0 = cnt[2*tid], c1 = cnt[2*tid+1];
    unsigned s = c0 + c1;
    unsigned v = s;                            // wave64 inclusive scan (canonical DPP)
    v = dpp_add_u32<0x111, 0xf>(v);
    v = dpp_add_u32<0x112, 0xf>(v);
    v = dpp_add_u32<0x114, 0xf>(v);
    v = dpp_add_u32<0x118, 0xf>(v);
    v = dpp_add_u32<0x142, 0xa>(v);            // bcast15 -> rows 1,3
    v = dpp_add_u32<0x143, 0xc>(v);            // bcast31 -> rows 2,3
    if (lane == 63) wsum[w] = v;
    __syncthreads();
    unsigned wbase = 0;
#pragma unroll
    for (int j = 0; j < 15; ++j) {             // exclusive prefix of wave totals
        unsigned t = wsum[j];
        wbase += (j < w) ? t : 0u;
    }
    unsigned excl = wbase + v - s;             // global exclusive prefix for bucket 2t
    cnt[2*tid]   = excl;                       // each thread touches only its own pair
    cnt[2*tid+1] = excl + c0;
    __syncthreads();
    // scatter
    for (int p = tid; p < NN; p += 1024) {
        unsigned bk = codes[p];
        unsigned pos = atomicAdd(&cnt[bk], 1u);
        float4 o;
        o.x = xb[3*p+0]; o.y = xb[3*p+1]; o.z = xb[3*p+2];
        o.w = __int_as_float(p);
        sorted[(size_t)b * NN + pos] = o;
    }
}

// ============================================================================
// 1) FPS, 2 batches per block (latency hiding): 4 blocks x 1024 threads.
//    Waves 0-7 run batch A, waves 8-15 batch B; one shared barrier/iter.
//    Each wave owns 1024 sorted points (16/lane) as TWO 512-pt subchunks with
//    independent bbox pruning + cached records -> 16 records per batch.
//    Exact fp32 semantics: contract(off), (dx2+dy2)+dz2, argmax tie = first
//    ORIGINAL index (keys are 8192-idx: same order as ~idx, 0 = no-candidate).
//    Winner coords come from the winning LANE's registers. The winner lane is
//    identified by POINT OWNERSHIP (its point key == cki) -- unique since
//    point keys are unique -- NOT by comparing post-reduce DPP partials
//    (R4 bug: multiple lanes matched and clobbered the record).
//    Records double-buffered by parity; every subchunk republishes its
//    (possibly cached) record every iteration. Cross-wave merge per batch:
//    lanes 0-15 read kvki (b64), lanes 16-63 read coord[48] (b32); u32 DPP
//    max (non-negative f32 bits == u32 order) -> readlane -> ki-select ->
//    u32 DPP -> 3 dynamic readlanes for coords.
// ============================================================================
#define VMAX6(mv) \
    mv = dpp_max_f32<0x111>(mv); mv = dpp_max_f32<0x112>(mv); \
    mv = dpp_max_f32<0x114>(mv); mv = dpp_max_f32<0x118>(mv); \
    mv = dpp_max_f32<0x142>(mv); mv = dpp_max_f32<0x143>(mv);
#define UMAX6(cv) \
    cv = dpp_max_u32<0x111>(cv); cv = dpp_max_u32<0x112>(cv); \
    cv = dpp_max_u32<0x114>(cv); cv = dpp_max_u32<0x118>(cv); \
    cv = dpp_max_u32<0x142>(cv); cv = dpp_max_u32<0x143>(cv);
#define UPD(M) \
    dx = px[M]-l2x; dy = py[M]-l2y; dz = pz[M]-l2z; \
    d = (dx*dx + dy*dy) + dz*dz; \
    dmin[M].x = fminf(dmin[M].x, d.x); dmin[M].y = fminf(dmin[M].y, d.y);
#define TIE(M) \
    u = (dmin[M].x == vmax) ? (pidx[M] & 0xffffu) : 0u; cand = cand > u ? cand : u; \
    u = (dmin[M].y == vmax) ? (pidx[M] >> 16)     : 0u; cand = cand > u ? cand : u;
#define CSEL(S, M) \
    e = ((pidx[M] & 0xffffu) == cki##S); iwin##S = iwin##S | e; \
    wx##S = e ? px[M].x : wx##S; wy##S = e ? py[M].x : wy##S; wz##S = e ? pz[M].x : wz##S; \
    e = ((pidx[M] >> 16) == cki##S);     iwin##S = iwin##S | e; \
    wx##S = e ? px[M].y : wx##S; wy##S = e ? py[M].y : wy##S; wz##S = e ? pz[M].y : wz##S;
#define DO_SUB(S, MA, MB, MC, MD) \
  { \
    float cdx = fmaxf(fmaxf(bn##S##x - lx, lx - bx##S##x), 0.f); \
    float cdy = fmaxf(fmaxf(bn##S##y - ly, ly - bx##S##y), 0.f); \
    float cdz = fmaxf(fmaxf(bn##S##z - lz, lz - bx##S##z), 0.f); \
    float lb = (cdx*cdx + cdy*cdy) + cdz*cdz; \
    if (!(lb >= ckv##S)) {                       /* wave-uniform branch */ \
      v2f l2x; l2x.x = lx; l2x.y = lx; \
      v2f l2y; l2y.x = ly; l2y.y = ly; \
      v2f l2z; l2z.x = lz; l2z.y = lz; \
      v2f dx, dy, dz, d; \
      UPD(MA) UPD(MB) UPD(MC) UPD(MD) \
      float t0 = fmaxf(fmaxf(dmin[MA].x, dmin[MA].y), fmaxf(dmin[MB].x, dmin[MB].y)); \
      float t1 = fmaxf(fmaxf(dmin[MC].x, dmin[MC].y), fmaxf(dmin[MD].x, dmin[MD].y)); \
      float mv = fmaxf(t0, t1); \
      VMAX6(mv) \
      const float vmax = __uint_as_float( \
          (unsigned)__builtin_amdgcn_readlane(__float_as_int(mv), 63)); \
      unsigned cand = 0u, u; \
      TIE(MA) TIE(MB) TIE(MC) TIE(MD) \
      UMAX6(cand) \
      cki##S = (unsigned)__builtin_amdgcn_readlane((int)cand, 63); \
      ckv##S = vmax; \
      iwin##S = false;                          /* unique winner by ownership */ \
      bool e; \
      CSEL(S, MA) CSEL(S, MB) CSEL(S, MC) CSEL(S, MD) \
    } \
    if (lane == 0) { \
      uint2 kk2; kk2.x = __float_as_uint(ckv##S); kk2.y = (cki##S << 4) | (unsigned)sid##S; \
      W->kvki[sid##S] = kk2; \
    } \
    if (iwin##S) { \
      W->coord[sid##S]      = wx##S; \
      W->coord[16 + sid##S] = wy##S; \
      W->coord[32 + sid##S] = wz##S; \
    } \
  }

struct FpsRec { uint2 kvki[16]; float coord[48]; };   // 320 B per batch/parity

__global__ __launch_bounds__(1024) void fps_kernel(const float* __restrict__ xyz,
    const float4* __restrict__ sorted,
    float* __restrict__ new_xyz, float* __restrict__ out_newxyz)
{
#pragma clang fp contract(off)
    const int blk = blockIdx.x;                          // 0..3
    const int tid = threadIdx.x;
    const int w = tid >> 6;                              // 0..15
    const int lane = tid & 63;
    const int bbl = w >> 3;                              // batch-local 0/1
    const int ww = w & 7;                                // wave within batch
    const int batch = blk * 2 + bbl;

    __shared__ FpsRec s_rec[2][2];                       // [parity][batch-local]
    __shared__ float s_hist[2][NS * 3];                  // 48 KB history (contiguous)

    const float4* sp = sorted + (size_t)batch * NN + (size_t)ww * 1024 + lane;
    v2f px[8], py[8], pz[8], dmin[8];
    unsigned pidx[8];                                    // packed (8192-idx): lo=even slot, hi=odd
    float bn0x = 1e30f, bn0y = 1e30f, bn0z = 1e30f;
    float bx0x = -1e30f, bx0y = -1e30f, bx0z = -1e30f;
    float bn1x = 1e30f, bn1y = 1e30f, bn1z = 1e30f;
    float bx1x = -1e30f, bx1y = -1e30f, bx1z = -1e30f;
#pragma unroll
    for (int m = 0; m < 8; ++m) {
        float4 a = sp[128*m];                            // slot 2m (.x)
        float4 c = sp[128*m + 64];                       // slot 2m+1 (.y)
        px[m].x = a.x; px[m].y = c.x;
        py[m].x = a.y; py[m].y = c.y;
        pz[m].x = a.z; pz[m].y = c.z;
        dmin[m].x = 1e10f; dmin[m].y = 1e10f;
        unsigned ia = (unsigned)__float_as_int(a.w), ic = (unsigned)__float_as_int(c.w);
        pidx[m] = (8192u - ia) | ((8192u - ic) << 16);
        if (m < 4) {
            bn0x = fminf(bn0x, fminf(a.x, c.x)); bx0x = fmaxf(bx0x, fmaxf(a.x, c.x));
            bn0y = fminf(bn0y, fminf(a.y, c.y)); bx0y = fmaxf(bx0y, fmaxf(a.y, c.y));
            bn0z = fminf(bn0z, fminf(a.z, c.z)); bx0z = fmaxf(bx0z, fmaxf(a.z, c.z));
        } else {
            bn1x = fminf(bn1x, fminf(a.x, c.x)); bx1x = fmaxf(bx1x, fmaxf(a.x, c.x));
            bn1y = fminf(bn1y, fminf(a.y, c.y)); bx1y = fmaxf(bx1y, fmaxf(a.y, c.y));
            bn1z = fminf(bn1z, fminf(a.z, c.z)); bx1z = fmaxf(bx1z, fmaxf(a.z, c.z));
        }
    }
    bn0x = wave_red_min(bn0x); bn0y = wave_red_min(bn0y); bn0z = wave_red_min(bn0z);
    bx0x = wave_red_max(bx0x); bx0y = wave_red_max(bx0y); bx0z = wave_red_max(bx0z);
    bn1x = wave_red_min(bn1x); bn1y = wave_red_min(bn1y); bn1z = wave_red_min(bn1z);
    bx1x = wave_red_max(bx1x); bx1y = wave_red_max(bx1y); bx1z = wave_red_max(bx1z);

    // per-lane record read pointers, both parities
    const int roff = (lane < 16) ? lane * 8 : 128 + (lane - 16) * 4;
    const char* rb0 = (const char*)&s_rec[0][bbl] + roff;
    const char* rb1 = (const char*)&s_rec[1][bbl] + roff;

    const float* xb = xyz + (size_t)batch * NN * 3;
    float lx = xb[0], ly = xb[1], lz = xb[2];            // selection 0 = point 0
    if (lane == 0 && ww == 0) {
        s_hist[bbl][0] = lx; s_hist[bbl][1] = ly; s_hist[bbl][2] = lz;
    }
    float ckv0 = 1e30f, ckv1 = 1e30f;                    // force first compute
    unsigned cki0 = 0u, cki1 = 0u;
    bool iwin0 = false, iwin1 = false;
    float wx0 = 0, wy0 = 0, wz0 = 0, wx1 = 0, wy1 = 0, wz1 = 0;
    const int sid0 = ww * 2, sid1 = ww * 2 + 1;

    for (int i = 1; i < NS; ++i) {
        FpsRec* W = &s_rec[i & 1][bbl];
        DO_SUB(0, 0, 1, 2, 3)
        DO_SUB(1, 4, 5, 6, 7)
        __syncthreads();                                 // the ONLY barrier per iter
        // cross-wave merge (this wave's own batch only)
        const char* rp = (i & 1) ? rb1 : rb0;
        uint2 kk; kk.x = 0u; kk.y = 0u;
        unsigned rcbits = 0u;
        if (lane < 16) kk = *(const uint2*)rp;
        else rcbits = *(const unsigned*)rp;
        unsigned mkv = (lane < 16) ? kk.x : 0u;          // kv >= 0 -> u32 order == f32
        mkv = dpp_max_u32<0x111>(mkv); mkv = dpp_max_u32<0x112>(mkv);
        mkv = dpp_max_u32<0x114>(mkv); mkv = dpp_max_u32<0x118>(mkv);
        const unsigned gkv = (unsigned)__builtin_amdgcn_readlane((int)mkv, 15);
        unsigned c = (lane < 16 && kk.x == gkv) ? kk.y : 0u;
        c = dpp_max_u32<0x111>(c); c = dpp_max_u32<0x112>(c);
        c = dpp_max_u32<0x114>(c); c = dpp_max_u32<0x118>(c);
        const unsigned kwin = (unsigned)__builtin_amdgcn_readlane((int)c, 15);
        const int sub = (int)(kwin & 15u);               // winning subchunk (uniform)
        lx = __uint_as_float((unsigned)__builtin_amdgcn_readlane((int)rcbits, 16 + sub));
        ly = __uint_as_float((unsigned)__builtin_amdgcn_readlane((int)rcbits, 32 + sub));
        lz = __uint_as_float((unsigned)__builtin_amdgcn_readlane((int)rcbits, 48 + sub));
        if (lane == 0 && ww == 0) {
            s_hist[bbl][3*i+0] = lx; s_hist[bbl][3*i+1] = ly; s_hist[bbl][3*i+2] = lz;
        }
    }
    __syncthreads();                                     // last hist writes visible
    // coalesced flush: both batches are contiguous in output
    const float* hf = (const float*)s_hist;
    float* nw = new_xyz + (size_t)(blk * 2) * NS * 3;
    float* ow = out_newxyz + (size_t)(blk * 2) * NS * 3;
    for (int t = tid; t < 2 * NS * 3; t += 1024) {
        float v = hf[t];
        nw[t] = v; ow[t] = v;
    }
}

// ============================================================================
// 2) Transpose features (B,C,N) -> (B,N,C) for contiguous per-point gathers.
// ============================================================================
__global__ __launch_bounds__(256) void transpose_kernel(const float* __restrict__ f,
    float* __restrict__ ft)
{
    __shared__ float tile[64][65];
    int b = blockIdx.y;
    int p0 = blockIdx.x * 64;
    for (int k = threadIdx.x; k < 64*64; k += 256) {
        int c = k >> 6, p = k & 63;
        tile[c][p] = f[((size_t)b * NC + c) * NN + p0 + p];
    }
    __syncthreads();
    for (int k = threadIdx.x; k < 64*64; k += 256) {
        int p = k >> 6, c = k & 63;
        ft[((size_t)b * NN + p0 + p) * NC + c] = tile[c][p];
    }
}

// ============================================================================
// 3) Ball query: one wave per (b,s) query. First 32 smallest in-ball indices,
//    pad with first. r2 must be float(0.2*0.2) = 0.0399999991 (not 0.2f*0.2f).
// ============================================================================
__global__ __launch_bounds__(256) void ballquery_kernel(const float* __restrict__ xyz,
    const float* __restrict__ new_xyz, int* __restrict__ idx)
{
#pragma clang fp contract(off)
    const int q = blockIdx.x * 4 + (threadIdx.x >> 6);
    const int lane = threadIdx.x & 63;
    const int b = q >> 11;
    const float r2 = (float)(0.2 * 0.2);
    const float* xb = xyz + (size_t)b * NN * 3;
    const float* nx = new_xyz + (size_t)q * 3;
    float qx = nx[0], qy = nx[1], qz = nx[2];
    int cnt = 0, first = -1;
    int* out = idx + (size_t)q * NK;
    for (int base = 0; base < NN; base += 64) {
        int p = base + lane;
        float x = xb[p*3+0], y = xb[p*3+1], z = xb[p*3+2];
        float dx = qx - x, dy = qy - y, dz = qz - z;
        float d2 = (dx*dx + dy*dy) + dz*dz;
        bool in = d2 < r2;
        unsigned long long m = __ballot(in);
        if (m) {
            if (first < 0) first = base + __builtin_ctzll(m);
            if (in) {
                int rank = cnt + __popcll(m & ((1ull << lane) - 1ull));
                if (rank < NK) out[rank] = p;
            }
            cnt += __popcll(m);
            if (cnt >= NK) break;
        }
    }
    for (int k = cnt + lane; k < NK; k += 64) out[k] = first;  // cnt>=1 always
}

// ============================================================================
// 4) Layer 1: h1 = W1(64x67) @ g. v2f packed FMAs; h computed in two halves
//    of 32 outputs to keep VGPR below spill point. h1 bf16.
// ============================================================================
__global__ __launch_bounds__(256, 2) void layer1_kernel(const float* __restrict__ xyz,
    const float* __restrict__ new_xyz, const int* __restrict__ idx,
    const float* __restrict__ ft, const float* __restrict__ W1,
    unsigned short* __restrict__ h1)
{
    const int col = blockIdx.x * 256 + threadIdx.x;
    const int b = col >> 16;
    const int s = (col >> 5) & 2047;
    const int p = idx[col];
    v2f g[34];
    float* gf = (float*)g;
    {
        const float* nx = new_xyz + ((size_t)(b * NS + s)) * 3;
        const float* xp = xyz + ((size_t)(b * NN + p)) * 3;
        gf[0] = xp[0] - nx[0]; gf[1] = xp[1] - nx[1]; gf[2] = xp[2] - nx[2];
    }
    const float4* fp = (const float4*)(ft + ((size_t)(b * NN + p)) * NC);
#pragma unroll
    for (int c4 = 0; c4 < 16; ++c4) {
        float4 v = fp[c4];
        gf[3 + 4*c4 + 0] = v.x; gf[3 + 4*c4 + 1] = v.y;
        gf[3 + 4*c4 + 2] = v.z; gf[3 + 4*c4 + 3] = v.w;
    }
    gf[67] = 0.f;
    uint4* dst = (uint4*)(h1 + (size_t)col * 64);
#pragma unroll
    for (int half = 0; half < 2; ++half) {
        float h[32];
#pragma unroll 4
        for (int o16 = 0; o16 < 32; ++o16) {
            const float* w = W1 + (half*32 + o16) * 67;
            v2f acc; acc.x = 0.f; acc.y = 0.f;
#pragma unroll
            for (int k = 0; k < 33; ++k) {
                v2f wv; wv.x = w[2*k]; wv.y = w[2*k+1];
                acc = wv * g[k] + acc;                    // v_pk_fma_f32
            }
            h[o16] = fmaf(w[66], gf[66], acc.x + acc.y);
        }
#pragma unroll
        for (int k = 0; k < 4; ++k) {
            uint4 v;
            v.x = (unsigned)f2bf(h[8*k+0]) | ((unsigned)f2bf(h[8*k+1]) << 16);
            v.y = (unsigned)f2bf(h[8*k+2]) | ((unsigned)f2bf(h[8*k+3]) << 16);
            v.z = (unsigned)f2bf(h[8*k+4]) | ((unsigned)f2bf(h[8*k+5]) << 16);
            v.w = (unsigned)f2bf(h[8*k+6]) | ((unsigned)f2bf(h[8*k+7]) << 16);
            dst[half*4 + k] = v;
        }
    }
}

// ============================================================================
// 5) Stats pass over a bf16 [col][64] tensor: per-channel sum / sumsq.
// ============================================================================
__global__ __launch_bounds__(256) void stats_kernel(const unsigned short* __restrict__ h,
    float* __restrict__ sums)
{
    __shared__ float ls[64], lq[64];
    const int tid = threadIdx.x;
    if (tid < 64) { ls[tid] = 0.f; lq[tid] = 0.f; }
    __syncthreads();
    float s[8] = {0,0,0,0,0,0,0,0}, q[8] = {0,0,0,0,0,0,0,0};
    const int gt = blockIdx.x * 256 + tid;
    const int G = gridDim.x * 256;            // multiple of 8 -> channel phase fixed
    const uint4* src = (const uint4*)h;
    const int nvec = NCOL * 8;                 // uint4s (8 bf16 each)
    for (int i = gt; i < nvec; i += G) {
        uint4 v = src[i];
        float f0 = bf2f(v.x & 0xffffu), f1 = bf2f(v.x >> 16);
        float f2 = bf2f(v.y & 0xffffu), f3 = bf2f(v.y >> 16);
        float f4 = bf2f(v.z & 0xffffu), f5 = bf2f(v.z >> 16);
        float f6 = bf2f(v.w & 0xffffu), f7 = bf2f(v.w >> 16);
        s[0] += f0; q[0] = fmaf(f0, f0, q[0]);
        s[1] += f1; q[1] = fmaf(f1, f1, q[1]);
        s[2] += f2; q[2] = fmaf(f2, f2, q[2]);
        s[3] += f3; q[3] = fmaf(f3, f3, q[3]);
        s[4] += f4; q[4] = fmaf(f4, f4, q[4]);
        s[5] += f5; q[5] = fmaf(f5, f5, q[5]);
        s[6] += f6; q[6] = fmaf(f6, f6, q[6]);
        s[7] += f7; q[7] = fmaf(f7, f7, q[7]);
    }
    const int obase = (tid & 7) * 8;
#pragma unroll
    for (int j = 0; j < 8; ++j) {
        atomicAdd(&ls[obase + j], s[j]);
        atomicAdd(&lq[obase + j], q[j]);
    }
    __syncthreads();
    if (tid < 64) {
        atomicAdd(&sums[tid*2+0], ls[tid]);
        atomicAdd(&sums[tid*2+1], lq[tid]);
    }
}

// ============================================================================
// 6) Finalize BN params. Layout: ab[c] = a_c (scale), ab[nch+c] = b_c (shift)
//    so the apply step can use packed v2f math.
// ============================================================================
__global__ void finalize_kernel(const float* __restrict__ sums,
    const float* __restrict__ gamma, const float* __restrict__ beta,
    float* __restrict__ ab, int nch)
{
    int c = threadIdx.x;
    if (c < nch) {
        const float invM = 1.0f / 524288.0f;
        float mu = sums[c*2] * invM;
        float var = sums[c*2+1] * invM - mu * mu;
        float a = gamma[c] / sqrtf(var + 1e-5f);
        ab[c] = a;
        ab[nch + c] = fmaf(-mu, a, beta[c]);
    }
}

// ============================================================================
// 7) Layer 2: g2 = relu(BN1(h1)); h2 = W2(64x64) @ g2. Packed FMAs, halves.
// ============================================================================
__global__ __launch_bounds__(256, 2) void layer2_kernel(const unsigned short* __restrict__ h1,
    const float* __restrict__ ab1, const float* __restrict__ W2,
    unsigned short* __restrict__ h2)
{
    const int col = blockIdx.x * 256 + threadIdx.x;
    const uint4* src = (const uint4*)(h1 + (size_t)col * 64);
    v2f g[32];
    float* gf = (float*)g;
#pragma unroll
    for (int k = 0; k < 8; ++k) {
        uint4 v = src[k];
        gf[8*k+0] = bf2f(v.x & 0xffffu); gf[8*k+1] = bf2f(v.x >> 16);
        gf[8*k+2] = bf2f(v.y & 0xffffu); gf[8*k+3] = bf2f(v.y >> 16);
        gf[8*k+4] = bf2f(v.z & 0xffffu); gf[8*k+5] = bf2f(v.z >> 16);
        gf[8*k+6] = bf2f(v.w & 0xffffu); gf[8*k+7] = bf2f(v.w >> 16);
    }
    const v2f* a2 = (const v2f*)ab1;
    const v2f* b2 = (const v2f*)(ab1 + 64);
#pragma unroll
    for (int k = 0; k < 32; ++k)
        g[k] = relu2(a2[k] * g[k] + b2[k]);               // pk_fma + pk_max
    uint4* dst = (uint4*)(h2 + (size_t)col * 64);
#pragma unroll
    for (int half = 0; half < 2; ++half) {
        float h[32];
#pragma unroll 4
        for (int o16 = 0; o16 < 32; ++o16) {
            const float* w = W2 + ((half*32 + o16) << 6);
            v2f acc; acc.x = 0.f; acc.y = 0.f;
#pragma unroll
            for (int k = 0; k < 32; ++k) {
                v2f wv; wv.x = w[2*k]; wv.y = w[2*k+1];
                acc = wv * g[k] + acc;
            }
            h[o16] = acc.x + acc.y;
        }
#pragma unroll
        for (int k = 0; k < 4; ++k) {
            uint4 v;
            v.x = (unsigned)f2bf(h[8*k+0]) | ((unsigned)f2bf(h[8*k+1]) << 16);
            v.y = (unsigned)f2bf(h[8*k+2]) | ((unsigned)f2bf(h[8*k+3]) << 16);
            v.z = (unsigned)f2bf(h[8*k+4]) | ((unsigned)f2bf(h[8*k+5]) << 16);
            v.w = (unsigned)f2bf(h[8*k+6]) | ((unsigned)f2bf(h[8*k+7]) << 16);
            dst[half*4 + k] = v;
        }
    }
}

// ============================================================================
// 8) Layer 3: g3 = relu(BN2(h2)); h3 = W3(128x64) @ g3; per-(b,s) max/min over
//    n=32 (lanes) + channel stats — all reductions via DPP (no ds ops).
// ============================================================================
__global__ __launch_bounds__(256, 2) void layer3_kernel(const unsigned short* __restrict__ h2,
    const float* __restrict__ ab2, const float* __restrict__ W3,
    float* __restrict__ hmax, float* __restrict__ hmin, float* __restrict__ sums3)
{
    __shared__ float ls[128], lq[128];
    const int tid = threadIdx.x;
    if (tid < 128) { ls[tid] = 0.f; lq[tid] = 0.f; }
    __syncthreads();
    const int col = blockIdx.x * 256 + tid;
    const int q = col >> 5;            // group (b*2048+s); lanes 0-31 / 32-63
    const uint4* src = (const uint4*)(h2 + (size_t)col * 64);
    v2f g[32];
    float* gf = (float*)g;
#pragma unroll
    for (int k = 0; k < 8; ++k) {
        uint4 v = src[k];
        gf[8*k+0] = bf2f(v.x & 0xffffu); gf[8*k+1] = bf2f(v.x >> 16);
        gf[8*k+2] = bf2f(v.y & 0xffffu); gf[8*k+3] = bf2f(v.y >> 16);
        gf[8*k+4] = bf2f(v.z & 0xffffu); gf[8*k+5] = bf2f(v.z >> 16);
        gf[8*k+6] = bf2f(v.w & 0xffffu); gf[8*k+7] = bf2f(v.w >> 16);
    }
    const v2f* a2 = (const v2f*)ab2;
    const v2f* b2 = (const v2f*)(ab2 + 64);
#pragma unroll
    for (int k = 0; k < 32; ++k)
        g[k] = relu2(a2[k] * g[k] + b2[k]);
    const bool leader = ((tid & 31) == 31);
#pragma unroll 2
    for (int o = 0; o < 128; ++o) {
        const float* w = W3 + (o << 6);
        v2f acc; acc.x = 0.f; acc.y = 0.f;
#pragma unroll
        for (int k = 0; k < 32; ++k) {
            v2f wv; wv.x = w[2*k]; wv.y = w[2*k+1];
            acc = wv * g[k] + acc;
        }
        float hv = acc.x + acc.y;
        float sm = hv, sq = hv*hv, mx = hv, mn = hv;
        sm = dpp_add_f32<0x111>(sm); sq = dpp_add_f32<0x111>(sq);
        mx = dpp_max_f32<0x111>(mx); mn = dpp_min_f32<0x111>(mn);
        sm = dpp_add_f32<0x112>(sm); sq = dpp_add_f32<0x112>(sq);
        mx = dpp_max_f32<0x112>(mx); mn = dpp_min_f32<0x112>(mn);
        sm = dpp_add_f32<0x114>(sm); sq = dpp_add_f32<0x114>(sq);
        mx = dpp_max_f32<0x114>(mx); mn = dpp_min_f32<0x114>(mn);
        sm = dpp_add_f32<0x118>(sm); sq = dpp_add_f32<0x118>(sq);
        mx = dpp_max_f32<0x118>(mx); mn = dpp_min_f32<0x118>(mn);
        sm = dpp_add_f32<0x142>(sm); sq = dpp_add_f32<0x142>(sq);
        mx = dpp_max_f32<0x142>(mx); mn = dpp_min_f32<0x142>(mn);
        if (leader) {
            hmax[(size_t)o * 16384 + q] = mx;
            hmin[(size_t)o * 16384 + q] = mn;
            atomicAdd(&ls[o], sm);
            atomicAdd(&lq[o], sq);
        }
    }
    __syncthreads();
    if (tid < 128) {
        atomicAdd(&sums3[tid*2+0], ls[tid]);
        atomicAdd(&sums3[tid*2+1], lq[tid]);
    }
}

// ============================================================================
// 9) Final: feats[b,o,s] = relu(a3*(a3>=0 ? max : min) + c3)
// ============================================================================
__global__ __launch_bounds__(256) void final_kernel(const float* __restrict__ hmax,
    const float* __restrict__ hmin, const float* __restrict__ ab3,
    float* __restrict__ out)
{
    const int t = blockIdx.x * 256 + threadIdx.x;   // (b,o,s), s fastest
    const int s = t & 2047;
    const int o = (t >> 11) & 127;
    const int b = t >> 18;
    const int q = (b << 11) + s;
    float a = ab3[o], c = ab3[128 + o];
    float h = (a >= 0.f) ? hmax[(size_t)o * 16384 + q] : hmin[(size_t)o * 16384 + q];
    out[t] = fmaxf(fmaf(a, h, c), 0.f);
}

// ============================================================================
extern "C" void kernel_launch(void* const* d_in, const int* in_sizes, int n_in,
                              void* d_out, int out_size, void* d_ws, size_t ws_size,
                              hipStream_t stream) {
    (void)in_sizes; (void)n_in; (void)out_size; (void)ws_size;
    const float* xyz      = (const float*)d_in[0];
    const float* features = (const float*)d_in[1];
    const float* W1 = (const float*)d_in[2];
    const float* g1 = (const float*)d_in[3];
    const float* b1 = (const float*)d_in[4];
    const float* W2 = (const float*)d_in[5];
    const float* g2 = (const float*)d_in[6];
    const float* b2 = (const float*)d_in[7];
    const float* W3 = (const float*)d_in[8];
    const float* g3 = (const float*)d_in[9];
    const float* b3 = (const float*)d_in[10];

    char* ws = (char*)d_ws;
    float*          new_xyz = (float*)(ws + 0);                  // 196608 B
    int*            idx     = (int*)(ws + 196608);               // 2097152 B
    float*          ft      = (float*)(ws + 2293760);            // 16777216 B
    unsigned short* h1      = (unsigned short*)(ws + 19070976);  // 67108864 B
    unsigned short* h2      = (unsigned short*)(ws + 86179840);  // 67108864 B
    float*          hmax    = (float*)(ws + 153288704);          // 8388608 B
    float*          hmin    = (float*)(ws + 161677312);          // 8388608 B
    float*          sums    = (float*)(ws + 170065920);          // 2048 B (zeroed)
    float*          ab      = (float*)(ws + 170067968);          // 2048 B
    float* sums1 = sums;        float* ab1 = ab;
    float* sums2 = sums + 128;  float* ab2 = ab + 128;
    float* sums3 = sums + 256;  float* ab3 = ab + 256;

    // sorted point array (float4 x,y,z,idx) lives in h1's space: h1 is only
    // written by layer1 AFTER fps completes (stream order), so no conflict.
    float4* sorted = (float4*)h1;                 // NB*NN*16 = 1 MB

    float* out_newxyz = (float*)d_out;            // B*NS*3 = 49152 floats
    float* out_feats  = (float*)d_out + 49152;    // B*128*NS floats

    hipMemsetAsync(sums, 0, 2048, stream);

    sort_kernel<<<NB, 1024, 0, stream>>>(xyz, sorted);
    fps_kernel<<<NB/2, 1024, 0, stream>>>(xyz, sorted, new_xyz, out_newxyz);
    transpose_kernel<<<dim3(NN/64, NB), 256, 0, stream>>>(features, ft);
    ballquery_kernel<<<(NB*NS)/4, 256, 0, stream>>>(xyz, new_xyz, idx);
    layer1_kernel<<<NCOL/256, 256, 0, stream>>>(xyz, new_xyz, idx, ft, W1, h1);
    stats_kernel<<<1024, 256, 0, stream>>>(h1, sums1);
    finalize_kernel<<<1, 128, 0, stream>>>(sums1, g1, b1, ab1, 64);
    layer2_kernel<<<NCOL/256, 256, 0, stream>>>(h1, ab1, W2, h2);
    stats_kernel<<<1024, 256, 0, stream>>>(h2, sums2);
    finalize_kernel<<<1, 128, 0, stream>>>(sums2, g2, b2, ab2, 64);
    layer3_kernel<<<NCOL/256, 256, 0, stream>>>(h2, ab2, W3, hmax, hmin, sums3);
    finalize_kernel<<<1, 128, 0, stream>>>(sums3, g3, b3, ab3, 128);
    final_kernel<<<(NB*128*NS)/256, 256, 0, stream>>>(hmax, hmin, ab3, out_feats);
}

// Round 6
// 4343.282 us; speedup vs baseline: 1.3029x; 1.3029x over previous
//
#include <hip/hip_runtime.h>
#include <hip/hip_bf16.h>
#include <stdint.h>

#define NB 8
#define NN 8192
#define NC 64
#define NS 2048
#define NK 32
#define NCOL (NB*NS*NK)   // 524288 columns (b,s,n)

typedef float v2f __attribute__((ext_vector_type(2)));

// ---------- bf16 helpers (RNE) ----------
__device__ __forceinline__ unsigned short f2bf(float x) {
    union { float f; unsigned u; } c; c.f = x;
    unsigned r = c.u + 0x7fffu + ((c.u >> 16) & 1u);
    return (unsigned short)(r >> 16);
}
__device__ __forceinline__ float bf2f(unsigned v16) {
    union { float f; unsigned u; } c; c.u = v16 << 16;
    return c.f;
}

// ---------- DPP cross-lane helpers (VALU-speed, no LDS) ----------
// row_shr:n = 0x110|n, row_bcast15 = 0x142, row_bcast31 = 0x143
template<int CTRL>
__device__ __forceinline__ float dpp_add_f32(float x) {   // zero-fill identity
    int o = __builtin_amdgcn_update_dpp(0, __float_as_int(x), CTRL, 0xf, 0xf, true);
    return x + __int_as_float(o);
}
template<int CTRL>
__device__ __forceinline__ float dpp_max_f32(float x) {   // self identity
    int o = __builtin_amdgcn_update_dpp(__float_as_int(x), __float_as_int(x), CTRL, 0xf, 0xf, false);
    return fmaxf(x, __int_as_float(o));
}
template<int CTRL>
__device__ __forceinline__ float dpp_min_f32(float x) {   // self identity
    int o = __builtin_amdgcn_update_dpp(__float_as_int(x), __float_as_int(x), CTRL, 0xf, 0xf, false);
    return fminf(x, __int_as_float(o));
}
template<int CTRL>
__device__ __forceinline__ unsigned dpp_max_u32(unsigned x) {  // self identity
    int o = __builtin_amdgcn_update_dpp((int)x, (int)x, CTRL, 0xf, 0xf, false);
    unsigned ou = (unsigned)o;
    return x > ou ? x : ou;   // v_max_u32
}
template<int CTRL, int RM>
__device__ __forceinline__ unsigned dpp_add_u32(unsigned x) {  // zero-fill, row-masked
    int o = __builtin_amdgcn_update_dpp(0, (int)x, CTRL, RM, 0xf, true);
    return x + (unsigned)o;
}
__device__ __forceinline__ float wave_red_min(float x) {  // full 64-lane min -> all lanes
    x = dpp_min_f32<0x111>(x); x = dpp_min_f32<0x112>(x);
    x = dpp_min_f32<0x114>(x); x = dpp_min_f32<0x118>(x);
    x = dpp_min_f32<0x142>(x); x = dpp_min_f32<0x143>(x);
    return __int_as_float(__builtin_amdgcn_readlane(__float_as_int(x), 63));
}
__device__ __forceinline__ float wave_red_max(float x) {  // full 64-lane max -> all lanes
    x = dpp_max_f32<0x111>(x); x = dpp_max_f32<0x112>(x);
    x = dpp_max_f32<0x114>(x); x = dpp_max_f32<0x118>(x);
    x = dpp_max_f32<0x142>(x); x = dpp_max_f32<0x143>(x);
    return __int_as_float(__builtin_amdgcn_readlane(__float_as_int(x), 63));
}
__device__ __forceinline__ v2f relu2(v2f v) {
    v.x = fmaxf(v.x, 0.f); v.y = fmaxf(v.y, 0.f); return v;
}

// ============================================================================
// 0) Spatial partition: counting sort on top-11 Morton bits (2048 buckets).
//    Any permutation is CORRECT (ordering only affects pruning rate); FPS
//    tie-breaking uses original indices.
// ============================================================================
__device__ __forceinline__ unsigned expand_bits10(unsigned v) {
    v = (v * 0x00010001u) & 0xFF0000FFu;
    v = (v * 0x00000101u) & 0x0F00F00Fu;
    v = (v * 0x00000011u) & 0xC30C30C3u;
    v = (v * 0x00000005u) & 0x49249249u;
    return v;
}
__global__ __launch_bounds__(1024) void sort_kernel(const float* __restrict__ xyz,
    float4* __restrict__ sorted)
{
    __shared__ unsigned cnt[2048];     // bucket counts -> start offsets
    __shared__ unsigned codes[NN];     // bucket id per point (32 KB)
    __shared__ unsigned wsum[16];
    const int b = blockIdx.x;
    const int tid = threadIdx.x;
    const int w = tid >> 6;
    const int lane = tid & 63;
    const float* xb = xyz + (size_t)b * NN * 3;
    cnt[tid] = 0; cnt[tid + 1024] = 0;
    __syncthreads();
    for (int p = tid; p < NN; p += 1024) {
        float x = xb[3*p+0], y = xb[3*p+1], z = xb[3*p+2];
        int qx = (int)(x * 1024.f); qx = qx < 0 ? 0 : (qx > 1023 ? 1023 : qx);
        int qy = (int)(y * 1024.f); qy = qy < 0 ? 0 : (qy > 1023 ? 1023 : qy);
        int qz = (int)(z * 1024.f); qz = qz < 0 ? 0 : (qz > 1023 ? 1023 : qz);
        unsigned m = expand_bits10((unsigned)qx)
                   | (expand_bits10((unsigned)qy) << 1)
                   | (expand_bits10((unsigned)qz) << 2);
        unsigned bk = m >> 19;                 // top 11 of 30 bits
        codes[p] = bk;
        atomicAdd(&cnt[bk], 1u);
    }
    __syncthreads();
    // exclusive scan of 2048 counts: thread t owns pair (2t, 2t+1)
    unsigned c0 = cnt[2*tid], c1 = cnt[2*tid+1];
    unsigned s = c0 + c1;
    unsigned v = s;                            // wave64 inclusive scan (canonical DPP)
    v = dpp_add_u32<0x111, 0xf>(v);
    v = dpp_add_u32<0x112, 0xf>(v);
    v = dpp_add_u32<0x114, 0xf>(v);
    v = dpp_add_u32<0x118, 0xf>(v);
    v = dpp_add_u32<0x142, 0xa>(v);            // bcast15 -> rows 1,3
    v = dpp_add_u32<0x143, 0xc>(v);            // bcast31 -> rows 2,3
    if (lane == 63) wsum[w] = v;
    __syncthreads();
    unsigned wbase = 0;
#pragma unroll
    for (int j = 0; j < 15; ++j) {             // exclusive prefix of wave totals
        unsigned t = wsum[j];
        wbase += (j < w) ? t : 0u;
    }
    unsigned excl = wbase + v - s;             // global exclusive prefix for bucket 2t
    cnt[2*tid]   = excl;                       // each thread touches only its own pair
    cnt[2*tid+1] = excl + c0;
    __syncthreads();
    // scatter
    for (int p = tid; p < NN; p += 1024) {
        unsigned bk = codes[p];
        unsigned pos = atomicAdd(&cnt[bk], 1u);
        float4 o;
        o.x = xb[3*p+0]; o.y = xb[3*p+1]; o.z = xb[3*p+2];
        o.w = __int_as_float(p);
        sorted[(size_t)b * NN + pos] = o;
    }
}

// ============================================================================
// 1) FPS: 8 blocks x 256 threads = 4 waves (ONE wave per SIMD -> no issue
//    contention on the all-wave merge; barrier syncs only 4 waves).
//    Wave ww owns 2048 sorted points (32/lane) as FOUR 512-pt subchunks with
//    independent bbox pruning + cached records -> 16 records per batch.
//    __launch_bounds__(256, 1): VGPR budget >= 256 so the ~190-reg demand
//    (coords+dmin+pidx in registers) does NOT spill (R5 failure: compiler
//    capped at 64 VGPR and spilled to scratch -> 2440 ns/iter).
//    Exact fp32 semantics: contract(off), (dx2+dy2)+dz2, argmax tie = first
//    ORIGINAL index (keys are 8192-idx: order == ~idx order, 0 = none).
//    Winner lane identified by POINT OWNERSHIP (unique); publishes coords
//    into the SoA record. Cross-wave merge: lanes 0-15 read kvki (b64),
//    lanes 16-63 read coord[48] (b32, 2-way bank alias = free); u32 DPP max
//    (non-negative f32 bits == u32 order) -> readlane -> ki-select -> u32
//    DPP -> 3 dynamic readlanes for coords. One barrier per iteration;
//    records double-buffered by parity; pruned subchunks republish cache.
// ============================================================================
#define VMAX6(mv) \
    mv = dpp_max_f32<0x111>(mv); mv = dpp_max_f32<0x112>(mv); \
    mv = dpp_max_f32<0x114>(mv); mv = dpp_max_f32<0x118>(mv); \
    mv = dpp_max_f32<0x142>(mv); mv = dpp_max_f32<0x143>(mv);
#define UMAX6(cv) \
    cv = dpp_max_u32<0x111>(cv); cv = dpp_max_u32<0x112>(cv); \
    cv = dpp_max_u32<0x114>(cv); cv = dpp_max_u32<0x118>(cv); \
    cv = dpp_max_u32<0x142>(cv); cv = dpp_max_u32<0x143>(cv);
#define UPD(M) \
    dx = px[M]-l2x; dy = py[M]-l2y; dz = pz[M]-l2z; \
    d = (dx*dx + dy*dy) + dz*dz; \
    dmin[M].x = fminf(dmin[M].x, d.x); dmin[M].y = fminf(dmin[M].y, d.y);
#define TIE(M) \
    u = (dmin[M].x == vmax) ? (pidx[M] & 0xffffu) : 0u; cand = cand > u ? cand : u; \
    u = (dmin[M].y == vmax) ? (pidx[M] >> 16)     : 0u; cand = cand > u ? cand : u;
#define CSEL(S, M) \
    e = ((pidx[M] & 0xffffu) == cki[S]); iwin[S] = iwin[S] | e; \
    wx[S] = e ? px[M].x : wx[S]; wy[S] = e ? py[M].x : wy[S]; wz[S] = e ? pz[M].x : wz[S]; \
    e = ((pidx[M] >> 16) == cki[S]);     iwin[S] = iwin[S] | e; \
    wx[S] = e ? px[M].y : wx[S]; wy[S] = e ? py[M].y : wy[S]; wz[S] = e ? pz[M].y : wz[S];
#define DO_SUB(S, MA, MB, MC, MD) \
  { \
    float cdx = fmaxf(fmaxf(bnx[S] - lx, lx - bxx[S]), 0.f); \
    float cdy = fmaxf(fmaxf(bny[S] - ly, ly - bxy[S]), 0.f); \
    float cdz = fmaxf(fmaxf(bnz[S] - lz, lz - bxz[S]), 0.f); \
    float lb = (cdx*cdx + cdy*cdy) + cdz*cdz; \
    if (!(lb >= ckv[S])) {                       /* wave-uniform branch */ \
      v2f l2x; l2x.x = lx; l2x.y = lx; \
      v2f l2y; l2y.x = ly; l2y.y = ly; \
      v2f l2z; l2z.x = lz; l2z.y = lz; \
      v2f dx, dy, dz, d; \
      UPD(MA) UPD(MB) UPD(MC) UPD(MD) \
      float t0 = fmaxf(fmaxf(dmin[MA].x, dmin[MA].y), fmaxf(dmin[MB].x, dmin[MB].y)); \
      float t1 = fmaxf(fmaxf(dmin[MC].x, dmin[MC].y), fmaxf(dmin[MD].x, dmin[MD].y)); \
      float mv = fmaxf(t0, t1); \
      VMAX6(mv) \
      const float vmax = __uint_as_float( \
          (unsigned)__builtin_amdgcn_readlane(__float_as_int(mv), 63)); \
      unsigned cand = 0u, u; \
      TIE(MA) TIE(MB) TIE(MC) TIE(MD) \
      UMAX6(cand) \
      cki[S] = (unsigned)__builtin_amdgcn_readlane((int)cand, 63); \
      ckv[S] = vmax; \
      iwin[S] = false;                          /* unique winner by ownership */ \
      bool e; \
      CSEL(S, MA) CSEL(S, MB) CSEL(S, MC) CSEL(S, MD) \
    } \
    if (lane == 0) { \
      uint2 kk2; kk2.x = __float_as_uint(ckv[S]); \
      kk2.y = (cki[S] << 4) | (unsigned)(ww*4 + S); \
      W->kvki[ww*4 + S] = kk2; \
    } \
    if (iwin[S]) { \
      W->coord[ww*4 + S]      = wx[S]; \
      W->coord[16 + ww*4 + S] = wy[S]; \
      W->coord[32 + ww*4 + S] = wz[S]; \
    } \
  }

struct FpsRec { uint2 kvki[16]; float coord[48]; };   // 320 B per parity

__global__ __launch_bounds__(256, 1) void fps_kernel(const float* __restrict__ xyz,
    const float4* __restrict__ sorted,
    float* __restrict__ new_xyz, float* __restrict__ out_newxyz)
{
#pragma clang fp contract(off)
    const int b = blockIdx.x;
    const int tid = threadIdx.x;
    const int ww = tid >> 6;                             // 0..3
    const int lane = tid & 63;

    __shared__ FpsRec s_rec[2];                          // [parity]
    __shared__ float s_hist[NS * 3];                     // 24 KB history

    const float4* sp = sorted + (size_t)b * NN + (size_t)ww * 2048 + lane;
    v2f px[16], py[16], pz[16], dmin[16];
    unsigned pidx[16];                                   // packed (8192-idx): lo=even, hi=odd
    float bnx[4], bny[4], bnz[4], bxx[4], bxy[4], bxz[4];
#pragma unroll
    for (int s = 0; s < 4; ++s) {
        bnx[s] = 1e30f; bny[s] = 1e30f; bnz[s] = 1e30f;
        bxx[s] = -1e30f; bxy[s] = -1e30f; bxz[s] = -1e30f;
    }
#pragma unroll
    for (int m = 0; m < 16; ++m) {
        float4 a = sp[128*m];                            // slot 2m (.x)
        float4 c = sp[128*m + 64];                       // slot 2m+1 (.y)
        px[m].x = a.x; px[m].y = c.x;
        py[m].x = a.y; py[m].y = c.y;
        pz[m].x = a.z; pz[m].y = c.z;
        dmin[m].x = 1e10f; dmin[m].y = 1e10f;
        unsigned ia = (unsigned)__float_as_int(a.w), ic = (unsigned)__float_as_int(c.w);
        pidx[m] = (8192u - ia) | ((8192u - ic) << 16);
        const int g = m >> 2;                            // subchunk id (compile-time)
        bnx[g] = fminf(bnx[g], fminf(a.x, c.x)); bxx[g] = fmaxf(bxx[g], fmaxf(a.x, c.x));
        bny[g] = fminf(bny[g], fminf(a.y, c.y)); bxy[g] = fmaxf(bxy[g], fmaxf(a.y, c.y));
        bnz[g] = fminf(bnz[g], fminf(a.z, c.z)); bxz[g] = fmaxf(bxz[g], fmaxf(a.z, c.z));
    }
#pragma unroll
    for (int s = 0; s < 4; ++s) {
        bnx[s] = wave_red_min(bnx[s]); bny[s] = wave_red_min(bny[s]); bnz[s] = wave_red_min(bnz[s]);
        bxx[s] = wave_red_max(bxx[s]); bxy[s] = wave_red_max(bxy[s]); bxz[s] = wave_red_max(bxz[s]);
    }

    // per-lane record read pointers, both parities
    const int roff = (lane < 16) ? lane * 8 : 128 + (lane - 16) * 4;
    const char* rb0 = (const char*)&s_rec[0] + roff;
    const char* rb1 = (const char*)&s_rec[1] + roff;

    const float* xb = xyz + (size_t)b * NN * 3;
    float lx = xb[0], ly = xb[1], lz = xb[2];            // selection 0 = point 0
    if (tid == 0) { s_hist[0] = lx; s_hist[1] = ly; s_hist[2] = lz; }
    float ckv[4] = {1e30f, 1e30f, 1e30f, 1e30f};         // force first compute
    unsigned cki[4] = {0u, 0u, 0u, 0u};
    bool iwin[4] = {false, false, false, false};
    float wx[4] = {0,0,0,0}, wy[4] = {0,0,0,0}, wz[4] = {0,0,0,0};
    __syncthreads();                                     // hist[0] visible

    for (int i = 1; i < NS; ++i) {
        FpsRec* W = &s_rec[i & 1];
        DO_SUB(0,  0,  1,  2,  3)
        DO_SUB(1,  4,  5,  6,  7)
        DO_SUB(2,  8,  9, 10, 11)
        DO_SUB(3, 12, 13, 14, 15)
        __syncthreads();                                 // the ONLY barrier per iter
        // cross-wave merge (all 4 waves, 1/SIMD -> no issue contention)
        const char* rp = (i & 1) ? rb1 : rb0;
        uint2 kk; kk.x = 0u; kk.y = 0u;
        unsigned rcbits = 0u;
        if (lane < 16) kk = *(const uint2*)rp;
        else rcbits = *(const unsigned*)rp;
        unsigned mkv = (lane < 16) ? kk.x : 0u;          // kv >= 0 -> u32 order == f32
        mkv = dpp_max_u32<0x111>(mkv); mkv = dpp_max_u32<0x112>(mkv);
        mkv = dpp_max_u32<0x114>(mkv); mkv = dpp_max_u32<0x118>(mkv);
        const unsigned gkv = (unsigned)__builtin_amdgcn_readlane((int)mkv, 15);
        unsigned c = (lane < 16 && kk.x == gkv) ? kk.y : 0u;
        c = dpp_max_u32<0x111>(c); c = dpp_max_u32<0x112>(c);
        c = dpp_max_u32<0x114>(c); c = dpp_max_u32<0x118>(c);
        const unsigned kwin = (unsigned)__builtin_amdgcn_readlane((int)c, 15);
        const int sub = (int)(kwin & 15u);               // winning subchunk (uniform)
        lx = __uint_as_float((unsigned)__builtin_amdgcn_readlane((int)rcbits, 16 + sub));
        ly = __uint_as_float((unsigned)__builtin_amdgcn_readlane((int)rcbits, 32 + sub));
        lz = __uint_as_float((unsigned)__builtin_amdgcn_readlane((int)rcbits, 48 + sub));
        if (tid == 0) {
            s_hist[3*i+0] = lx; s_hist[3*i+1] = ly; s_hist[3*i+2] = lz;
        }
    }
    __syncthreads();                                     // last hist write visible
    // coalesced flush of the selected-coordinate history
    float* nw = new_xyz + (size_t)b * NS * 3;
    float* ow = out_newxyz + (size_t)b * NS * 3;
    for (int t = tid; t < NS * 3; t += 256) {
        float v = s_hist[t];
        nw[t] = v; ow[t] = v;
    }
}

// ============================================================================
// 2) Transpose features (B,C,N) -> (B,N,C) for contiguous per-point gathers.
// ============================================================================
__global__ __launch_bounds__(256) void transpose_kernel(const float* __restrict__ f,
    float* __restrict__ ft)
{
    __shared__ float tile[64][65];
    int b = blockIdx.y;
    int p0 = blockIdx.x * 64;
    for (int k = threadIdx.x; k < 64*64; k += 256) {
        int c = k >> 6, p = k & 63;
        tile[c][p] = f[((size_t)b * NC + c) * NN + p0 + p];
    }
    __syncthreads();
    for (int k = threadIdx.x; k < 64*64; k += 256) {
        int p = k >> 6, c = k & 63;
        ft[((size_t)b * NN + p0 + p) * NC + c] = tile[c][p];
    }
}

// ============================================================================
// 3) Ball query: one wave per (b,s) query. First 32 smallest in-ball indices,
//    pad with first. r2 must be float(0.2*0.2) = 0.0399999991 (not 0.2f*0.2f).
// ============================================================================
__global__ __launch_bounds__(256) void ballquery_kernel(const float* __restrict__ xyz,
    const float* __restrict__ new_xyz, int* __restrict__ idx)
{
#pragma clang fp contract(off)
    const int q = blockIdx.x * 4 + (threadIdx.x >> 6);
    const int lane = threadIdx.x & 63;
    const int b = q >> 11;
    const float r2 = (float)(0.2 * 0.2);
    const float* xb = xyz + (size_t)b * NN * 3;
    const float* nx = new_xyz + (size_t)q * 3;
    float qx = nx[0], qy = nx[1], qz = nx[2];
    int cnt = 0, first = -1;
    int* out = idx + (size_t)q * NK;
    for (int base = 0; base < NN; base += 64) {
        int p = base + lane;
        float x = xb[p*3+0], y = xb[p*3+1], z = xb[p*3+2];
        float dx = qx - x, dy = qy - y, dz = qz - z;
        float d2 = (dx*dx + dy*dy) + dz*dz;
        bool in = d2 < r2;
        unsigned long long m = __ballot(in);
        if (m) {
            if (first < 0) first = base + __builtin_ctzll(m);
            if (in) {
                int rank = cnt + __popcll(m & ((1ull << lane) - 1ull));
                if (rank < NK) out[rank] = p;
            }
            cnt += __popcll(m);
            if (cnt >= NK) break;
        }
    }
    for (int k = cnt + lane; k < NK; k += 64) out[k] = first;  // cnt>=1 always
}

// ============================================================================
// 4) Layer 1: h1 = W1(64x67) @ g. v2f packed FMAs; h computed in two halves
//    of 32 outputs to keep VGPR below spill point. h1 bf16.
// ============================================================================
__global__ __launch_bounds__(256, 2) void layer1_kernel(const float* __restrict__ xyz,
    const float* __restrict__ new_xyz, const int* __restrict__ idx,
    const float* __restrict__ ft, const float* __restrict__ W1,
    unsigned short* __restrict__ h1)
{
    const int col = blockIdx.x * 256 + threadIdx.x;
    const int b = col >> 16;
    const int s = (col >> 5) & 2047;
    const int p = idx[col];
    v2f g[34];
    float* gf = (float*)g;
    {
        const float* nx = new_xyz + ((size_t)(b * NS + s)) * 3;
        const float* xp = xyz + ((size_t)(b * NN + p)) * 3;
        gf[0] = xp[0] - nx[0]; gf[1] = xp[1] - nx[1]; gf[2] = xp[2] - nx[2];
    }
    const float4* fp = (const float4*)(ft + ((size_t)(b * NN + p)) * NC);
#pragma unroll
    for (int c4 = 0; c4 < 16; ++c4) {
        float4 v = fp[c4];
        gf[3 + 4*c4 + 0] = v.x; gf[3 + 4*c4 + 1] = v.y;
        gf[3 + 4*c4 + 2] = v.z; gf[3 + 4*c4 + 3] = v.w;
    }
    gf[67] = 0.f;
    uint4* dst = (uint4*)(h1 + (size_t)col * 64);
#pragma unroll
    for (int half = 0; half < 2; ++half) {
        float h[32];
#pragma unroll 4
        for (int o16 = 0; o16 < 32; ++o16) {
            const float* w = W1 + (half*32 + o16) * 67;
            v2f acc; acc.x = 0.f; acc.y = 0.f;
#pragma unroll
            for (int k = 0; k < 33; ++k) {
                v2f wv; wv.x = w[2*k]; wv.y = w[2*k+1];
                acc = wv * g[k] + acc;                    // v_pk_fma_f32
            }
            h[o16] = fmaf(w[66], gf[66], acc.x + acc.y);
        }
#pragma unroll
        for (int k = 0; k < 4; ++k) {
            uint4 v;
            v.x = (unsigned)f2bf(h[8*k+0]) | ((unsigned)f2bf(h[8*k+1]) << 16);
            v.y = (unsigned)f2bf(h[8*k+2]) | ((unsigned)f2bf(h[8*k+3]) << 16);
            v.z = (unsigned)f2bf(h[8*k+4]) | ((unsigned)f2bf(h[8*k+5]) << 16);
            v.w = (unsigned)f2bf(h[8*k+6]) | ((unsigned)f2bf(h[8*k+7]) << 16);
            dst[half*4 + k] = v;
        }
    }
}

// ============================================================================
// 5) Stats pass over a bf16 [col][64] tensor: per-channel sum / sumsq.
// ============================================================================
__global__ __launch_bounds__(256) void stats_kernel(const unsigned short* __restrict__ h,
    float* __restrict__ sums)
{
    __shared__ float ls[64], lq[64];
    const int tid = threadIdx.x;
    if (tid < 64) { ls[tid] = 0.f; lq[tid] = 0.f; }
    __syncthreads();
    float s[8] = {0,0,0,0,0,0,0,0}, q[8] = {0,0,0,0,0,0,0,0};
    const int gt = blockIdx.x * 256 + tid;
    const int G = gridDim.x * 256;            // multiple of 8 -> channel phase fixed
    const uint4* src = (const uint4*)h;
    const int nvec = NCOL * 8;                 // uint4s (8 bf16 each)
    for (int i = gt; i < nvec; i += G) {
        uint4 v = src[i];
        float f0 = bf2f(v.x & 0xffffu), f1 = bf2f(v.x >> 16);
        float f2 = bf2f(v.y & 0xffffu), f3 = bf2f(v.y >> 16);
        float f4 = bf2f(v.z & 0xffffu), f5 = bf2f(v.z >> 16);
        float f6 = bf2f(v.w & 0xffffu), f7 = bf2f(v.w >> 16);
        s[0] += f0; q[0] = fmaf(f0, f0, q[0]);
        s[1] += f1; q[1] = fmaf(f1, f1, q[1]);
        s[2] += f2; q[2] = fmaf(f2, f2, q[2]);
        s[3] += f3; q[3] = fmaf(f3, f3, q[3]);
        s[4] += f4; q[4] = fmaf(f4, f4, q[4]);
        s[5] += f5; q[5] = fmaf(f5, f5, q[5]);
        s[6] += f6; q[6] = fmaf(f6, f6, q[6]);
        s[7] += f7; q[7] = fmaf(f7, f7, q[7]);
    }
    const int obase = (tid & 7) * 8;
#pragma unroll
    for (int j = 0; j < 8; ++j) {
        atomicAdd(&ls[obase + j], s[j]);
        atomicAdd(&lq[obase + j], q[j]);
    }
    __syncthreads();
    if (tid < 64) {
        atomicAdd(&sums[tid*2+0], ls[tid]);
        atomicAdd(&sums[tid*2+1], lq[tid]);
    }
}

// ============================================================================
// 6) Finalize BN params. Layout: ab[c] = a_c (scale), ab[nch+c] = b_c (shift)
//    so the apply step can use packed v2f math.
// ============================================================================
__global__ void finalize_kernel(const float* __restrict__ sums,
    const float* __restrict__ gamma, const float* __restrict__ beta,
    float* __restrict__ ab, int nch)
{
    int c = threadIdx.x;
    if (c < nch) {
        const float invM = 1.0f / 524288.0f;
        float mu = sums[c*2] * invM;
        float var = sums[c*2+1] * invM - mu * mu;
        float a = gamma[c] / sqrtf(var + 1e-5f);
        ab[c] = a;
        ab[nch + c] = fmaf(-mu, a, beta[c]);
    }
}

// ============================================================================
// 7) Layer 2: g2 = relu(BN1(h1)); h2 = W2(64x64) @ g2. Packed FMAs, halves.
// ============================================================================
__global__ __launch_bounds__(256, 2) void layer2_kernel(const unsigned short* __restrict__ h1,
    const float* __restrict__ ab1, const float* __restrict__ W2,
    unsigned short* __restrict__ h2)
{
    const int col = blockIdx.x * 256 + threadIdx.x;
    const uint4* src = (const uint4*)(h1 + (size_t)col * 64);
    v2f g[32];
    float* gf = (float*)g;
#pragma unroll
    for (int k = 0; k < 8; ++k) {
        uint4 v = src[k];
        gf[8*k+0] = bf2f(v.x & 0xffffu); gf[8*k+1] = bf2f(v.x >> 16);
        gf[8*k+2] = bf2f(v.y & 0xffffu); gf[8*k+3] = bf2f(v.y >> 16);
        gf[8*k+4] = bf2f(v.z & 0xffffu); gf[8*k+5] = bf2f(v.z >> 16);
        gf[8*k+6] = bf2f(v.w & 0xffffu); gf[8*k+7] = bf2f(v.w >> 16);
    }
    const v2f* a2 = (const v2f*)ab1;
    const v2f* b2 = (const v2f*)(ab1 + 64);
#pragma unroll
    for (int k = 0; k < 32; ++k)
        g[k] = relu2(a2[k] * g[k] + b2[k]);               // pk_fma + pk_max
    uint4* dst = (uint4*)(h2 + (size_t)col * 64);
#pragma unroll
    for (int half = 0; half < 2; ++half) {
        float h[32];
#pragma unroll 4
        for (int o16 = 0; o16 < 32; ++o16) {
            const float* w = W2 + ((half*32 + o16) << 6);
            v2f acc; acc.x = 0.f; acc.y = 0.f;
#pragma unroll
            for (int k = 0; k < 32; ++k) {
                v2f wv; wv.x = w[2*k]; wv.y = w[2*k+1];
                acc = wv * g[k] + acc;
            }
            h[o16] = acc.x + acc.y;
        }
#pragma unroll
        for (int k = 0; k < 4; ++k) {
            uint4 v;
            v.x = (unsigned)f2bf(h[8*k+0]) | ((unsigned)f2bf(h[8*k+1]) << 16);
            v.y = (unsigned)f2bf(h[8*k+2]) | ((unsigned)f2bf(h[8*k+3]) << 16);
            v.z = (unsigned)f2bf(h[8*k+4]) | ((unsigned)f2bf(h[8*k+5]) << 16);
            v.w = (unsigned)f2bf(h[8*k+6]) | ((unsigned)f2bf(h[8*k+7]) << 16);
            dst[half*4 + k] = v;
        }
    }
}

// ============================================================================
// 8) Layer 3: g3 = relu(BN2(h2)); h3 = W3(128x64) @ g3; per-(b,s) max/min over
//    n=32 (lanes) + channel stats — all reductions via DPP (no ds ops).
// ============================================================================
__global__ __launch_bounds__(256, 2) void layer3_kernel(const unsigned short* __restrict__ h2,
    const float* __restrict__ ab2, const float* __restrict__ W3,
    float* __restrict__ hmax, float* __restrict__ hmin, float* __restrict__ sums3)
{
    __shared__ float ls[128], lq[128];
    const int tid = threadIdx.x;
    if (tid < 128) { ls[tid] = 0.f; lq[tid] = 0.f; }
    __syncthreads();
    const int col = blockIdx.x * 256 + tid;
    const int q = col >> 5;            // group (b*2048+s); lanes 0-31 / 32-63
    const uint4* src = (const uint4*)(h2 + (size_t)col * 64);
    v2f g[32];
    float* gf = (float*)g;
#pragma unroll
    for (int k = 0; k < 8; ++k) {
        uint4 v = src[k];
        gf[8*k+0] = bf2f(v.x & 0xffffu); gf[8*k+1] = bf2f(v.x >> 16);
        gf[8*k+2] = bf2f(v.y & 0xffffu); gf[8*k+3] = bf2f(v.y >> 16);
        gf[8*k+4] = bf2f(v.z & 0xffffu); gf[8*k+5] = bf2f(v.z >> 16);
        gf[8*k+6] = bf2f(v.w & 0xffffu); gf[8*k+7] = bf2f(v.w >> 16);
    }
    const v2f* a2 = (const v2f*)ab2;
    const v2f* b2 = (const v2f*)(ab2 + 64);
#pragma unroll
    for (int k = 0; k < 32; ++k)
        g[k] = relu2(a2[k] * g[k] + b2[k]);
    const bool leader = ((tid & 31) == 31);
#pragma unroll 2
    for (int o = 0; o < 128; ++o) {
        const float* w = W3 + (o << 6);
        v2f acc; acc.x = 0.f; acc.y = 0.f;
#pragma unroll
        for (int k = 0; k < 32; ++k) {
            v2f wv; wv.x = w[2*k]; wv.y = w[2*k+1];
            acc = wv * g[k] + acc;
        }
        float hv = acc.x + acc.y;
        float sm = hv, sq = hv*hv, mx = hv, mn = hv;
        sm = dpp_add_f32<0x111>(sm); sq = dpp_add_f32<0x111>(sq);
        mx = dpp_max_f32<0x111>(mx); mn = dpp_min_f32<0x111>(mn);
        sm = dpp_add_f32<0x112>(sm); sq = dpp_add_f32<0x112>(sq);
        mx = dpp_max_f32<0x112>(mx); mn = dpp_min_f32<0x112>(mn);
        sm = dpp_add_f32<0x114>(sm); sq = dpp_add_f32<0x114>(sq);
        mx = dpp_max_f32<0x114>(mx); mn = dpp_min_f32<0x114>(mn);
        sm = dpp_add_f32<0x118>(sm); sq = dpp_add_f32<0x118>(sq);
        mx = dpp_max_f32<0x118>(mx); mn = dpp_min_f32<0x118>(mn);
        sm = dpp_add_f32<0x142>(sm); sq = dpp_add_f32<0x142>(sq);
        mx = dpp_max_f32<0x142>(mx); mn = dpp_min_f32<0x142>(mn);
        if (leader) {
            hmax[(size_t)o * 16384 + q] = mx;
            hmin[(size_t)o * 16384 + q] = mn;
            atomicAdd(&ls[o], sm);
            atomicAdd(&lq[o], sq);
        }
    }
    __syncthreads();
    if (tid < 128) {
        atomicAdd(&sums3[tid*2+0], ls[tid]);
        atomicAdd(&sums3[tid*2+1], lq[tid]);
    }
}

// ============================================================================
// 9) Final: feats[b,o,s] = relu(a3*(a3>=0 ? max : min) + c3)
// ============================================================================
__global__ __launch_bounds__(256) void final_kernel(const float* __restrict__ hmax,
    const float* __restrict__ hmin, const float* __restrict__ ab3,
    float* __restrict__ out)
{
    const int t = blockIdx.x * 256 + threadIdx.x;   // (b,o,s), s fastest
    const int s = t & 2047;
    const int o = (t >> 11) & 127;
    const int b = t >> 18;
    const int q = (b << 11) + s;
    float a = ab3[o], c = ab3[128 + o];
    float h = (a >= 0.f) ? hmax[(size_t)o * 16384 + q] : hmin[(size_t)o * 16384 + q];
    out[t] = fmaxf(fmaf(a, h, c), 0.f);
}

// ============================================================================
extern "C" void kernel_launch(void* const* d_in, const int* in_sizes, int n_in,
                              void* d_out, int out_size, void* d_ws, size_t ws_size,
                              hipStream_t stream) {
    (void)in_sizes; (void)n_in; (void)out_size; (void)ws_size;
    const float* xyz      = (const float*)d_in[0];
    const float* features = (const float*)d_in[1];
    const float* W1 = (const float*)d_in[2];
    const float* g1 = (const float*)d_in[3];
    const float* b1 = (const float*)d_in[4];
    const float* W2 = (const float*)d_in[5];
    const float* g2 = (const float*)d_in[6];
    const float* b2 = (const float*)d_in[7];
    const float* W3 = (const float*)d_in[8];
    const float* g3 = (const float*)d_in[9];
    const float* b3 = (const float*)d_in[10];

    char* ws = (char*)d_ws;
    float*          new_xyz = (float*)(ws + 0);                  // 196608 B
    int*            idx     = (int*)(ws + 196608);               // 2097152 B
    float*          ft      = (float*)(ws + 2293760);            // 16777216 B
    unsigned short* h1      = (unsigned short*)(ws + 19070976);  // 67108864 B
    unsigned short* h2      = (unsigned short*)(ws + 86179840);  // 67108864 B
    float*          hmax    = (float*)(ws + 153288704);          // 8388608 B
    float*          hmin    = (float*)(ws + 161677312);          // 8388608 B
    float*          sums    = (float*)(ws + 170065920);          // 2048 B (zeroed)
    float*          ab      = (float*)(ws + 170067968);          // 2048 B
    float* sums1 = sums;        float* ab1 = ab;
    float* sums2 = sums + 128;  float* ab2 = ab + 128;
    float* sums3 = sums + 256;  float* ab3 = ab + 256;

    // sorted point array (float4 x,y,z,idx) lives in h1's space: h1 is only
    // written by layer1 AFTER fps completes (stream order), so no conflict.
    float4* sorted = (float4*)h1;                 // NB*NN*16 = 1 MB

    float* out_newxyz = (float*)d_out;            // B*NS*3 = 49152 floats
    float* out_feats  = (float*)d_out + 49152;    // B*128*NS floats

    hipMemsetAsync(sums, 0, 2048, stream);

    sort_kernel<<<NB, 1024, 0, stream>>>(xyz, sorted);
    fps_kernel<<<NB, 256, 0, stream>>>(xyz, sorted, new_xyz, out_newxyz);
    transpose_kernel<<<dim3(NN/64, NB), 256, 0, stream>>>(features, ft);
    ballquery_kernel<<<(NB*NS)/4, 256, 0, stream>>>(xyz, new_xyz, idx);
    layer1_kernel<<<NCOL/256, 256, 0, stream>>>(xyz, new_xyz, idx, ft, W1, h1);
    stats_kernel<<<1024, 256, 0, stream>>>(h1, sums1);
    finalize_kernel<<<1, 128, 0, stream>>>(sums1, g1, b1, ab1, 64);
    layer2_kernel<<<NCOL/256, 256, 0, stream>>>(h1, ab1, W2, h2);
    stats_kernel<<<1024, 256, 0, stream>>>(h2, sums2);
    finalize_kernel<<<1, 128, 0, stream>>>(sums2, g2, b2, ab2, 64);
    layer3_kernel<<<NCOL/256, 256, 0, stream>>>(h2, ab2, W3, hmax, hmin, sums3);
    finalize_kernel<<<1, 128, 0, stream>>>(sums3, g3, b3, ab3, 128);
    final_kernel<<<(NB*128*NS)/256, 256, 0, stream>>>(hmax, hmin, ab3, out_feats);
}

// Round 7
// 2836.276 us; speedup vs baseline: 1.9952x; 1.5313x over previous
//
#include <hip/hip_runtime.h>
#include <hip/hip_bf16.h>
#include <stdint.h>

#define NB 8
#define NN 8192
#define NC 64
#define NS 2048
#define NK 32
#define NCOL (NB*NS*NK)   // 524288 columns (b,s,n)

typedef float v2f __attribute__((ext_vector_type(2)));

// ---------- bf16 helpers (RNE) ----------
__device__ __forceinline__ unsigned short f2bf(float x) {
    union { float f; unsigned u; } c; c.f = x;
    unsigned r = c.u + 0x7fffu + ((c.u >> 16) & 1u);
    return (unsigned short)(r >> 16);
}
__device__ __forceinline__ float bf2f(unsigned v16) {
    union { float f; unsigned u; } c; c.u = v16 << 16;
    return c.f;
}

// ---------- DPP cross-lane helpers (VALU-speed, no LDS) ----------
// row_shr:n = 0x110|n, row_bcast15 = 0x142, row_bcast31 = 0x143
template<int CTRL>
__device__ __forceinline__ float dpp_add_f32(float x) {   // zero-fill identity
    int o = __builtin_amdgcn_update_dpp(0, __float_as_int(x), CTRL, 0xf, 0xf, true);
    return x + __int_as_float(o);
}
template<int CTRL>
__device__ __forceinline__ float dpp_max_f32(float x) {   // self identity
    int o = __builtin_amdgcn_update_dpp(__float_as_int(x), __float_as_int(x), CTRL, 0xf, 0xf, false);
    return fmaxf(x, __int_as_float(o));
}
template<int CTRL>
__device__ __forceinline__ float dpp_min_f32(float x) {   // self identity
    int o = __builtin_amdgcn_update_dpp(__float_as_int(x), __float_as_int(x), CTRL, 0xf, 0xf, false);
    return fminf(x, __int_as_float(o));
}
template<int CTRL>
__device__ __forceinline__ unsigned dpp_max_u32(unsigned x) {  // self identity
    int o = __builtin_amdgcn_update_dpp((int)x, (int)x, CTRL, 0xf, 0xf, false);
    unsigned ou = (unsigned)o;
    return x > ou ? x : ou;   // v_max_u32
}
template<int CTRL, int RM>
__device__ __forceinline__ unsigned dpp_add_u32(unsigned x) {  // zero-fill, row-masked
    int o = __builtin_amdgcn_update_dpp(0, (int)x, CTRL, RM, 0xf, true);
    return x + (unsigned)o;
}
__device__ __forceinline__ float wave_red_min(float x) {  // full 64-lane min -> all lanes
    x = dpp_min_f32<0x111>(x); x = dpp_min_f32<0x112>(x);
    x = dpp_min_f32<0x114>(x); x = dpp_min_f32<0x118>(x);
    x = dpp_min_f32<0x142>(x); x = dpp_min_f32<0x143>(x);
    return __int_as_float(__builtin_amdgcn_readlane(__float_as_int(x), 63));
}
__device__ __forceinline__ float wave_red_max(float x) {  // full 64-lane max -> all lanes
    x = dpp_max_f32<0x111>(x); x = dpp_max_f32<0x112>(x);
    x = dpp_max_f32<0x114>(x); x = dpp_max_f32<0x118>(x);
    x = dpp_max_f32<0x142>(x); x = dpp_max_f32<0x143>(x);
    return __int_as_float(__builtin_amdgcn_readlane(__float_as_int(x), 63));
}
__device__ __forceinline__ v2f relu2(v2f v) {
    v.x = fmaxf(v.x, 0.f); v.y = fmaxf(v.y, 0.f); return v;
}

// ============================================================================
// 0) Spatial partition: counting sort on top-11 Morton bits (2048 buckets).
//    Any permutation is CORRECT (ordering only affects pruning rate); FPS
//    tie-breaking uses original indices.
// ============================================================================
__device__ __forceinline__ unsigned expand_bits10(unsigned v) {
    v = (v * 0x00010001u) & 0xFF0000FFu;
    v = (v * 0x00000101u) & 0x0F00F00Fu;
    v = (v * 0x00000011u) & 0xC30C30C3u;
    v = (v * 0x00000005u) & 0x49249249u;
    return v;
}
__global__ __launch_bounds__(1024) void sort_kernel(const float* __restrict__ xyz,
    float4* __restrict__ sorted)
{
    __shared__ unsigned cnt[2048];     // bucket counts -> start offsets
    __shared__ unsigned codes[NN];     // bucket id per point (32 KB)
    __shared__ unsigned wsum[16];
    const int b = blockIdx.x;
    const int tid = threadIdx.x;
    const int w = tid >> 6;
    const int lane = tid & 63;
    const float* xb = xyz + (size_t)b * NN * 3;
    cnt[tid] = 0; cnt[tid + 1024] = 0;
    __syncthreads();
    for (int p = tid; p < NN; p += 1024) {
        float x = xb[3*p+0], y = xb[3*p+1], z = xb[3*p+2];
        int qx = (int)(x * 1024.f); qx = qx < 0 ? 0 : (qx > 1023 ? 1023 : qx);
        int qy = (int)(y * 1024.f); qy = qy < 0 ? 0 : (qy > 1023 ? 1023 : qy);
        int qz = (int)(z * 1024.f); qz = qz < 0 ? 0 : (qz > 1023 ? 1023 : qz);
        unsigned m = expand_bits10((unsigned)qx)
                   | (expand_bits10((unsigned)qy) << 1)
                   | (expand_bits10((unsigned)qz) << 2);
        unsigned bk = m >> 19;                 // top 11 of 30 bits
        codes[p] = bk;
        atomicAdd(&cnt[bk], 1u);
    }
    __syncthreads();
    // exclusive scan of 2048 counts: thread t owns pair (2t, 2t+1)
    unsigned c0 = cnt[2*tid], c1 = cnt[2*tid+1];
    unsigned s = c0 + c1;
    unsigned v = s;                            // wave64 inclusive scan (canonical DPP)
    v = dpp_add_u32<0x111, 0xf>(v);
    v = dpp_add_u32<0x112, 0xf>(v);
    v = dpp_add_u32<0x114, 0xf>(v);
    v = dpp_add_u32<0x118, 0xf>(v);
    v = dpp_add_u32<0x142, 0xa>(v);            // bcast15 -> rows 1,3
    v = dpp_add_u32<0x143, 0xc>(v);            // bcast31 -> rows 2,3
    if (lane == 63) wsum[w] = v;
    __syncthreads();
    unsigned wbase = 0;
#pragma unroll
    for (int j = 0; j < 15; ++j) {             // exclusive prefix of wave totals
        unsigned t = wsum[j];
        wbase += (j < w) ? t : 0u;
    }
    unsigned excl = wbase + v - s;             // global exclusive prefix for bucket 2t
    cnt[2*tid]   = excl;                       // each thread touches only its own pair
    cnt[2*tid+1] = excl + c0;
    __syncthreads();
    // scatter
    for (int p = tid; p < NN; p += 1024) {
        unsigned bk = codes[p];
        unsigned pos = atomicAdd(&cnt[bk], 1u);
        float4 o;
        o.x = xb[3*p+0]; o.y = xb[3*p+1]; o.z = xb[3*p+2];
        o.w = __int_as_float(p);
        sorted[(size_t)b * NN + pos] = o;
    }
}

// ============================================================================
// 1) FPS — restores the measured-best R1 shape: 8 blocks x 1024 threads =
//    16 waves, wave w owns sorted[512w, 512w+512) (8 pts/lane in regs),
//    per-wave bbox prune, wave0-ONLY merge between two barriers.
//    (Measured: per-iter time scales inversely with wave count — 16 waves
//    697ns vs 4 waves 1800ns — because active subchunks land in different
//    waves and compute in parallel, and co-resident waves hide chain latency.)
//    Changed vs R1 (only the merge internals, each piece proven in R5/R6):
//    - records carry winner COORDS from the owner lane's registers
//      (ownership-unique) -> no 96KB sx/sy/sz tables, no serial coord gather
//      in wave0's critical section;
//    - wave0 merge = split u32 DPP (keys are non-negative f32 bits, so u32
//      order == f32 order) + tie-select + 5 readlanes on the SoA record
//      (lanes 0-15: kvki b64; lanes 16-63: coord b32, <=2-way bank alias).
//    Exact fp32 semantics: contract(off), (dx2+dy2)+dz2, argmax tie = first
//    ORIGINAL index (keys are 8192-idx: order == ~idx order, 0 = none).
//    Records double-buffered by parity; pruned waves republish cache.
// ============================================================================
#define VMAX6(mv) \
    mv = dpp_max_f32<0x111>(mv); mv = dpp_max_f32<0x112>(mv); \
    mv = dpp_max_f32<0x114>(mv); mv = dpp_max_f32<0x118>(mv); \
    mv = dpp_max_f32<0x142>(mv); mv = dpp_max_f32<0x143>(mv);
#define UMAX6(cv) \
    cv = dpp_max_u32<0x111>(cv); cv = dpp_max_u32<0x112>(cv); \
    cv = dpp_max_u32<0x114>(cv); cv = dpp_max_u32<0x118>(cv); \
    cv = dpp_max_u32<0x142>(cv); cv = dpp_max_u32<0x143>(cv);

struct FpsRec { uint2 kvki[16]; float coord[48]; };   // 320 B per parity

__global__ __launch_bounds__(1024) void fps_kernel(const float* __restrict__ xyz,
    const float4* __restrict__ sorted,
    float* __restrict__ new_xyz, float* __restrict__ out_newxyz)
{
#pragma clang fp contract(off)
    const int b = blockIdx.x;
    const int tid = threadIdx.x;
    const int w = tid >> 6;                              // 0..15
    const int lane = tid & 63;

    __shared__ FpsRec s_rec[2];                          // [parity], 640 B
    __shared__ float s_hist[NS * 3];                     // 24 KB history

    const float4* sp = sorted + (size_t)b * NN + (size_t)w * 512 + lane;
    v2f px[4], py[4], pz[4], dmin[4];
    unsigned pidx[4];                                    // packed (8192-idx): lo=even, hi=odd
    float bnx = 1e30f, bny = 1e30f, bnz = 1e30f;
    float bxx = -1e30f, bxy = -1e30f, bxz = -1e30f;
#pragma unroll
    for (int m = 0; m < 4; ++m) {
        float4 a = sp[128*m];                            // slot 2m (.x)
        float4 c = sp[128*m + 64];                       // slot 2m+1 (.y)
        px[m].x = a.x; px[m].y = c.x;
        py[m].x = a.y; py[m].y = c.y;
        pz[m].x = a.z; pz[m].y = c.z;
        dmin[m].x = 1e10f; dmin[m].y = 1e10f;
        unsigned ia = (unsigned)__float_as_int(a.w), ic = (unsigned)__float_as_int(c.w);
        pidx[m] = (8192u - ia) | ((8192u - ic) << 16);
        bnx = fminf(bnx, fminf(a.x, c.x)); bxx = fmaxf(bxx, fmaxf(a.x, c.x));
        bny = fminf(bny, fminf(a.y, c.y)); bxy = fmaxf(bxy, fmaxf(a.y, c.y));
        bnz = fminf(bnz, fminf(a.z, c.z)); bxz = fmaxf(bxz, fmaxf(a.z, c.z));
    }
    bnx = wave_red_min(bnx); bny = wave_red_min(bny); bnz = wave_red_min(bnz);
    bxx = wave_red_max(bxx); bxy = wave_red_max(bxy); bxz = wave_red_max(bxz);

    // wave0's per-lane record read pointers, both parities
    const int roff = (lane < 16) ? lane * 8 : 128 + (lane - 16) * 4;
    const char* rb0 = (const char*)&s_rec[0] + roff;
    const char* rb1 = (const char*)&s_rec[1] + roff;

    const float* xb = xyz + (size_t)b * NN * 3;
    float lx = xb[0], ly = xb[1], lz = xb[2];            // selection 0 = point 0
    if (tid == 0) { s_hist[0] = lx; s_hist[1] = ly; s_hist[2] = lz; }
    float ckv = 1e30f;                                   // force first compute
    unsigned cki = 0u;
    bool iwin = false;
    float wx = 0.f, wy = 0.f, wz = 0.f;                  // cached winner coords (owner lane)
    __syncthreads();                                     // hist[0] visible

    for (int i = 1; i < NS; ++i) {
        FpsRec* W = &s_rec[i & 1];
        // certified fp32 lower bound of d_new for every point in this chunk
        float cdx = fmaxf(fmaxf(bnx - lx, lx - bxx), 0.f);
        float cdy = fmaxf(fmaxf(bny - ly, ly - bxy), 0.f);
        float cdz = fmaxf(fmaxf(bnz - lz, lz - bxz), 0.f);
        float lb = (cdx*cdx + cdy*cdy) + cdz*cdz;
        if (!(lb >= ckv)) {                              // wave-uniform branch
            v2f l2x; l2x.x = lx; l2x.y = lx;
            v2f l2y; l2y.x = ly; l2y.y = ly;
            v2f l2z; l2z.x = lz; l2z.y = lz;
#pragma unroll
            for (int m = 0; m < 4; ++m) {
                v2f dx = px[m] - l2x;
                v2f dy = py[m] - l2y;
                v2f dz = pz[m] - l2z;
                v2f d = (dx*dx + dy*dy) + dz*dz;         // pk mul/add, exact order
                dmin[m].x = fminf(dmin[m].x, d.x);
                dmin[m].y = fminf(dmin[m].y, d.y);
            }
            // lane-local max of 8, then fused-DPP wave max (f32)
            float t0 = fmaxf(fmaxf(dmin[0].x, dmin[0].y), fmaxf(dmin[1].x, dmin[1].y));
            float t1 = fmaxf(fmaxf(dmin[2].x, dmin[2].y), fmaxf(dmin[3].x, dmin[3].y));
            float mv = fmaxf(t0, t1);
            VMAX6(mv)
            const float vmax = __uint_as_float(
                (unsigned)__builtin_amdgcn_readlane(__float_as_int(mv), 63));
            // tie resolve: max (8192-idx) among dm == vmax == first max by orig idx
            unsigned cand = 0u, u;
#pragma unroll
            for (int m = 0; m < 4; ++m) {
                u = (dmin[m].x == vmax) ? (pidx[m] & 0xffffu) : 0u; cand = cand > u ? cand : u;
                u = (dmin[m].y == vmax) ? (pidx[m] >> 16)     : 0u; cand = cand > u ? cand : u;
            }
            UMAX6(cand)
            cki = (unsigned)__builtin_amdgcn_readlane((int)cand, 63);
            ckv = vmax;
            // unique winner lane by point OWNERSHIP (R5/R6-proven)
            iwin = false;
            bool e;
#pragma unroll
            for (int m = 0; m < 4; ++m) {
                e = ((pidx[m] & 0xffffu) == cki); iwin = iwin | e;
                wx = e ? px[m].x : wx; wy = e ? py[m].x : wy; wz = e ? pz[m].x : wz;
                e = ((pidx[m] >> 16) == cki);     iwin = iwin | e;
                wx = e ? px[m].y : wx; wy = e ? py[m].y : wy; wz = e ? pz[m].y : wz;
            }
        }
        if (lane == 0) {                                 // publish (possibly cached) key
            uint2 kk2; kk2.x = __float_as_uint(ckv); kk2.y = (cki << 4) | (unsigned)w;
            W->kvki[w] = kk2;
        }
        if (iwin) {                                      // publish (possibly cached) coords
            W->coord[w]      = wx;
            W->coord[16 + w] = wy;
            W->coord[32 + w] = wz;
        }
        __syncthreads();                                 // barrier 1: records ready
        if (w == 0) {                                    // wave0-only merge (R1 topology)
            const char* rp = (i & 1) ? rb1 : rb0;
            uint2 kk; kk.x = 0u; kk.y = 0u;
            unsigned rcbits = 0u;
            if (lane < 16) kk = *(const uint2*)rp;
            else rcbits = *(const unsigned*)rp;
            unsigned mkv = (lane < 16) ? kk.x : 0u;      // kv >= 0 -> u32 order == f32
            mkv = dpp_max_u32<0x111>(mkv); mkv = dpp_max_u32<0x112>(mkv);
            mkv = dpp_max_u32<0x114>(mkv); mkv = dpp_max_u32<0x118>(mkv);
            const unsigned gkv = (unsigned)__builtin_amdgcn_readlane((int)mkv, 15);
            unsigned c = (lane < 16 && kk.x == gkv) ? kk.y : 0u;
            c = dpp_max_u32<0x111>(c); c = dpp_max_u32<0x112>(c);
            c = dpp_max_u32<0x114>(c); c = dpp_max_u32<0x118>(c);
            const unsigned kwin = (unsigned)__builtin_amdgcn_readlane((int)c, 15);
            const int sub = (int)(kwin & 15u);           // winning wave (uniform)
            float nx = __uint_as_float((unsigned)__builtin_amdgcn_readlane((int)rcbits, 16 + sub));
            float ny = __uint_as_float((unsigned)__builtin_amdgcn_readlane((int)rcbits, 32 + sub));
            float nz = __uint_as_float((unsigned)__builtin_amdgcn_readlane((int)rcbits, 48 + sub));
            if (lane == 0) {
                s_hist[3*i+0] = nx; s_hist[3*i+1] = ny; s_hist[3*i+2] = nz;
            }
        }
        __syncthreads();                                 // barrier 2: winner ready
        lx = s_hist[3*i+0]; ly = s_hist[3*i+1]; lz = s_hist[3*i+2];
    }
    __syncthreads();                                     // last hist write visible
    // coalesced flush of the selected-coordinate history
    float* nw = new_xyz + (size_t)b * NS * 3;
    float* ow = out_newxyz + (size_t)b * NS * 3;
    for (int t = tid; t < NS * 3; t += 1024) {
        float v = s_hist[t];
        nw[t] = v; ow[t] = v;
    }
}

// ============================================================================
// 2) Transpose features (B,C,N) -> (B,N,C) for contiguous per-point gathers.
// ============================================================================
__global__ __launch_bounds__(256) void transpose_kernel(const float* __restrict__ f,
    float* __restrict__ ft)
{
    __shared__ float tile[64][65];
    int b = blockIdx.y;
    int p0 = blockIdx.x * 64;
    for (int k = threadIdx.x; k < 64*64; k += 256) {
        int c = k >> 6, p = k & 63;
        tile[c][p] = f[((size_t)b * NC + c) * NN + p0 + p];
    }
    __syncthreads();
    for (int k = threadIdx.x; k < 64*64; k += 256) {
        int p = k >> 6, c = k & 63;
        ft[((size_t)b * NN + p0 + p) * NC + c] = tile[c][p];
    }
}

// ============================================================================
// 3) Ball query: one wave per (b,s) query. First 32 smallest in-ball indices,
//    pad with first. r2 must be float(0.2*0.2) = 0.0399999991 (not 0.2f*0.2f).
// ============================================================================
__global__ __launch_bounds__(256) void ballquery_kernel(const float* __restrict__ xyz,
    const float* __restrict__ new_xyz, int* __restrict__ idx)
{
#pragma clang fp contract(off)
    const int q = blockIdx.x * 4 + (threadIdx.x >> 6);
    const int lane = threadIdx.x & 63;
    const int b = q >> 11;
    const float r2 = (float)(0.2 * 0.2);
    const float* xb = xyz + (size_t)b * NN * 3;
    const float* nx = new_xyz + (size_t)q * 3;
    float qx = nx[0], qy = nx[1], qz = nx[2];
    int cnt = 0, first = -1;
    int* out = idx + (size_t)q * NK;
    for (int base = 0; base < NN; base += 64) {
        int p = base + lane;
        float x = xb[p*3+0], y = xb[p*3+1], z = xb[p*3+2];
        float dx = qx - x, dy = qy - y, dz = qz - z;
        float d2 = (dx*dx + dy*dy) + dz*dz;
        bool in = d2 < r2;
        unsigned long long m = __ballot(in);
        if (m) {
            if (first < 0) first = base + __builtin_ctzll(m);
            if (in) {
                int rank = cnt + __popcll(m & ((1ull << lane) - 1ull));
                if (rank < NK) out[rank] = p;
            }
            cnt += __popcll(m);
            if (cnt >= NK) break;
        }
    }
    for (int k = cnt + lane; k < NK; k += 64) out[k] = first;  // cnt>=1 always
}

// ============================================================================
// 4) Layer 1: h1 = W1(64x67) @ g. v2f packed FMAs; h computed in two halves
//    of 32 outputs to keep VGPR below spill point. h1 bf16.
// ============================================================================
__global__ __launch_bounds__(256, 2) void layer1_kernel(const float* __restrict__ xyz,
    const float* __restrict__ new_xyz, const int* __restrict__ idx,
    const float* __restrict__ ft, const float* __restrict__ W1,
    unsigned short* __restrict__ h1)
{
    const int col = blockIdx.x * 256 + threadIdx.x;
    const int b = col >> 16;
    const int s = (col >> 5) & 2047;
    const int p = idx[col];
    v2f g[34];
    float* gf = (float*)g;
    {
        const float* nx = new_xyz + ((size_t)(b * NS + s)) * 3;
        const float* xp = xyz + ((size_t)(b * NN + p)) * 3;
        gf[0] = xp[0] - nx[0]; gf[1] = xp[1] - nx[1]; gf[2] = xp[2] - nx[2];
    }
    const float4* fp = (const float4*)(ft + ((size_t)(b * NN + p)) * NC);
#pragma unroll
    for (int c4 = 0; c4 < 16; ++c4) {
        float4 v = fp[c4];
        gf[3 + 4*c4 + 0] = v.x; gf[3 + 4*c4 + 1] = v.y;
        gf[3 + 4*c4 + 2] = v.z; gf[3 + 4*c4 + 3] = v.w;
    }
    gf[67] = 0.f;
    uint4* dst = (uint4*)(h1 + (size_t)col * 64);
#pragma unroll
    for (int half = 0; half < 2; ++half) {
        float h[32];
#pragma unroll 4
        for (int o16 = 0; o16 < 32; ++o16) {
            const float* w = W1 + (half*32 + o16) * 67;
            v2f acc; acc.x = 0.f; acc.y = 0.f;
#pragma unroll
            for (int k = 0; k < 33; ++k) {
                v2f wv; wv.x = w[2*k]; wv.y = w[2*k+1];
                acc = wv * g[k] + acc;                    // v_pk_fma_f32
            }
            h[o16] = fmaf(w[66], gf[66], acc.x + acc.y);
        }
#pragma unroll
        for (int k = 0; k < 4; ++k) {
            uint4 v;
            v.x = (unsigned)f2bf(h[8*k+0]) | ((unsigned)f2bf(h[8*k+1]) << 16);
            v.y = (unsigned)f2bf(h[8*k+2]) | ((unsigned)f2bf(h[8*k+3]) << 16);
            v.z = (unsigned)f2bf(h[8*k+4]) | ((unsigned)f2bf(h[8*k+5]) << 16);
            v.w = (unsigned)f2bf(h[8*k+6]) | ((unsigned)f2bf(h[8*k+7]) << 16);
            dst[half*4 + k] = v;
        }
    }
}

// ============================================================================
// 5) Stats pass over a bf16 [col][64] tensor: per-channel sum / sumsq.
// ============================================================================
__global__ __launch_bounds__(256) void stats_kernel(const unsigned short* __restrict__ h,
    float* __restrict__ sums)
{
    __shared__ float ls[64], lq[64];
    const int tid = threadIdx.x;
    if (tid < 64) { ls[tid] = 0.f; lq[tid] = 0.f; }
    __syncthreads();
    float s[8] = {0,0,0,0,0,0,0,0}, q[8] = {0,0,0,0,0,0,0,0};
    const int gt = blockIdx.x * 256 + tid;
    const int G = gridDim.x * 256;            // multiple of 8 -> channel phase fixed
    const uint4* src = (const uint4*)h;
    const int nvec = NCOL * 8;                 // uint4s (8 bf16 each)
    for (int i = gt; i < nvec; i += G) {
        uint4 v = src[i];
        float f0 = bf2f(v.x & 0xffffu), f1 = bf2f(v.x >> 16);
        float f2 = bf2f(v.y & 0xffffu), f3 = bf2f(v.y >> 16);
        float f4 = bf2f(v.z & 0xffffu), f5 = bf2f(v.z >> 16);
        float f6 = bf2f(v.w & 0xffffu), f7 = bf2f(v.w >> 16);
        s[0] += f0; q[0] = fmaf(f0, f0, q[0]);
        s[1] += f1; q[1] = fmaf(f1, f1, q[1]);
        s[2] += f2; q[2] = fmaf(f2, f2, q[2]);
        s[3] += f3; q[3] = fmaf(f3, f3, q[3]);
        s[4] += f4; q[4] = fmaf(f4, f4, q[4]);
        s[5] += f5; q[5] = fmaf(f5, f5, q[5]);
        s[6] += f6; q[6] = fmaf(f6, f6, q[6]);
        s[7] += f7; q[7] = fmaf(f7, f7, q[7]);
    }
    const int obase = (tid & 7) * 8;
#pragma unroll
    for (int j = 0; j < 8; ++j) {
        atomicAdd(&ls[obase + j], s[j]);
        atomicAdd(&lq[obase + j], q[j]);
    }
    __syncthreads();
    if (tid < 64) {
        atomicAdd(&sums[tid*2+0], ls[tid]);
        atomicAdd(&sums[tid*2+1], lq[tid]);
    }
}

// ============================================================================
// 6) Finalize BN params. Layout: ab[c] = a_c (scale), ab[nch+c] = b_c (shift)
//    so the apply step can use packed v2f math.
// ============================================================================
__global__ void finalize_kernel(const float* __restrict__ sums,
    const float* __restrict__ gamma, const float* __restrict__ beta,
    float* __restrict__ ab, int nch)
{
    int c = threadIdx.x;
    if (c < nch) {
        const float invM = 1.0f / 524288.0f;
        float mu = sums[c*2] * invM;
        float var = sums[c*2+1] * invM - mu * mu;
        float a = gamma[c] / sqrtf(var + 1e-5f);
        ab[c] = a;
        ab[nch + c] = fmaf(-mu, a, beta[c]);
    }
}

// ============================================================================
// 7) Layer 2: g2 = relu(BN1(h1)); h2 = W2(64x64) @ g2. Packed FMAs, halves.
// ============================================================================
__global__ __launch_bounds__(256, 2) void layer2_kernel(const unsigned short* __restrict__ h1,
    const float* __restrict__ ab1, const float* __restrict__ W2,
    unsigned short* __restrict__ h2)
{
    const int col = blockIdx.x * 256 + threadIdx.x;
    const uint4* src = (const uint4*)(h1 + (size_t)col * 64);
    v2f g[32];
    float* gf = (float*)g;
#pragma unroll
    for (int k = 0; k < 8; ++k) {
        uint4 v = src[k];
        gf[8*k+0] = bf2f(v.x & 0xffffu); gf[8*k+1] = bf2f(v.x >> 16);
        gf[8*k+2] = bf2f(v.y & 0xffffu); gf[8*k+3] = bf2f(v.y >> 16);
        gf[8*k+4] = bf2f(v.z & 0xffffu); gf[8*k+5] = bf2f(v.z >> 16);
        gf[8*k+6] = bf2f(v.w & 0xffffu); gf[8*k+7] = bf2f(v.w >> 16);
    }
    const v2f* a2 = (const v2f*)ab1;
    const v2f* b2 = (const v2f*)(ab1 + 64);
#pragma unroll
    for (int k = 0; k < 32; ++k)
        g[k] = relu2(a2[k] * g[k] + b2[k]);               // pk_fma + pk_max
    uint4* dst = (uint4*)(h2 + (size_t)col * 64);
#pragma unroll
    for (int half = 0; half < 2; ++half) {
        float h[32];
#pragma unroll 4
        for (int o16 = 0; o16 < 32; ++o16) {
            const float* w = W2 + ((half*32 + o16) << 6);
            v2f acc; acc.x = 0.f; acc.y = 0.f;
#pragma unroll
            for (int k = 0; k < 32; ++k) {
                v2f wv; wv.x = w[2*k]; wv.y = w[2*k+1];
                acc = wv * g[k] + acc;
            }
            h[o16] = acc.x + acc.y;
        }
#pragma unroll
        for (int k = 0; k < 4; ++k) {
            uint4 v;
            v.x = (unsigned)f2bf(h[8*k+0]) | ((unsigned)f2bf(h[8*k+1]) << 16);
            v.y = (unsigned)f2bf(h[8*k+2]) | ((unsigned)f2bf(h[8*k+3]) << 16);
            v.z = (unsigned)f2bf(h[8*k+4]) | ((unsigned)f2bf(h[8*k+5]) << 16);
            v.w = (unsigned)f2bf(h[8*k+6]) | ((unsigned)f2bf(h[8*k+7]) << 16);
            dst[half*4 + k] = v;
        }
    }
}

// ============================================================================
// 8) Layer 3: g3 = relu(BN2(h2)); h3 = W3(128x64) @ g3; per-(b,s) max/min over
//    n=32 (lanes) + channel stats — all reductions via DPP (no ds ops).
// ============================================================================
__global__ __launch_bounds__(256, 2) void layer3_kernel(const unsigned short* __restrict__ h2,
    const float* __restrict__ ab2, const float* __restrict__ W3,
    float* __restrict__ hmax, float* __restrict__ hmin, float* __restrict__ sums3)
{
    __shared__ float ls[128], lq[128];
    const int tid = threadIdx.x;
    if (tid < 128) { ls[tid] = 0.f; lq[tid] = 0.f; }
    __syncthreads();
    const int col = blockIdx.x * 256 + tid;
    const int q = col >> 5;            // group (b*2048+s); lanes 0-31 / 32-63
    const uint4* src = (const uint4*)(h2 + (size_t)col * 64);
    v2f g[32];
    float* gf = (float*)g;
#pragma unroll
    for (int k = 0; k < 8; ++k) {
        uint4 v = src[k];
        gf[8*k+0] = bf2f(v.x & 0xffffu); gf[8*k+1] = bf2f(v.x >> 16);
        gf[8*k+2] = bf2f(v.y & 0xffffu); gf[8*k+3] = bf2f(v.y >> 16);
        gf[8*k+4] = bf2f(v.z & 0xffffu); gf[8*k+5] = bf2f(v.z >> 16);
        gf[8*k+6] = bf2f(v.w & 0xffffu); gf[8*k+7] = bf2f(v.w >> 16);
    }
    const v2f* a2 = (const v2f*)ab2;
    const v2f* b2 = (const v2f*)(ab2 + 64);
#pragma unroll
    for (int k = 0; k < 32; ++k)
        g[k] = relu2(a2[k] * g[k] + b2[k]);
    const bool leader = ((tid & 31) == 31);
#pragma unroll 2
    for (int o = 0; o < 128; ++o) {
        const float* w = W3 + (o << 6);
        v2f acc; acc.x = 0.f; acc.y = 0.f;
#pragma unroll
        for (int k = 0; k < 32; ++k) {
            v2f wv; wv.x = w[2*k]; wv.y = w[2*k+1];
            acc = wv * g[k] + acc;
        }
        float hv = acc.x + acc.y;
        float sm = hv, sq = hv*hv, mx = hv, mn = hv;
        sm = dpp_add_f32<0x111>(sm); sq = dpp_add_f32<0x111>(sq);
        mx = dpp_max_f32<0x111>(mx); mn = dpp_min_f32<0x111>(mn);
        sm = dpp_add_f32<0x112>(sm); sq = dpp_add_f32<0x112>(sq);
        mx = dpp_max_f32<0x112>(mx); mn = dpp_min_f32<0x112>(mn);
        sm = dpp_add_f32<0x114>(sm); sq = dpp_add_f32<0x114>(sq);
        mx = dpp_max_f32<0x114>(mx); mn = dpp_min_f32<0x114>(mn);
        sm = dpp_add_f32<0x118>(sm); sq = dpp_add_f32<0x118>(sq);
        mx = dpp_max_f32<0x118>(mx); mn = dpp_min_f32<0x118>(mn);
        sm = dpp_add_f32<0x142>(sm); sq = dpp_add_f32<0x142>(sq);
        mx = dpp_max_f32<0x142>(mx); mn = dpp_min_f32<0x142>(mn);
        if (leader) {
            hmax[(size_t)o * 16384 + q] = mx;
            hmin[(size_t)o * 16384 + q] = mn;
            atomicAdd(&ls[o], sm);
            atomicAdd(&lq[o], sq);
        }
    }
    __syncthreads();
    if (tid < 128) {
        atomicAdd(&sums3[tid*2+0], ls[tid]);
        atomicAdd(&sums3[tid*2+1], lq[tid]);
    }
}

// ============================================================================
// 9) Final: feats[b,o,s] = relu(a3*(a3>=0 ? max : min) + c3)
// ============================================================================
__global__ __launch_bounds__(256) void final_kernel(const float* __restrict__ hmax,
    const float* __restrict__ hmin, const float* __restrict__ ab3,
    float* __restrict__ out)
{
    const int t = blockIdx.x * 256 + threadIdx.x;   // (b,o,s), s fastest
    const int s = t & 2047;
    const int o = (t >> 11) & 127;
    const int b = t >> 18;
    const int q = (b << 11) + s;
    float a = ab3[o], c = ab3[128 + o];
    float h = (a >= 0.f) ? hmax[(size_t)o * 16384 + q] : hmin[(size_t)o * 16384 + q];
    out[t] = fmaxf(fmaf(a, h, c), 0.f);
}

// ============================================================================
extern "C" void kernel_launch(void* const* d_in, const int* in_sizes, int n_in,
                              void* d_out, int out_size, void* d_ws, size_t ws_size,
                              hipStream_t stream) {
    (void)in_sizes; (void)n_in; (void)out_size; (void)ws_size;
    const float* xyz      = (const float*)d_in[0];
    const float* features = (const float*)d_in[1];
    const float* W1 = (const float*)d_in[2];
    const float* g1 = (const float*)d_in[3];
    const float* b1 = (const float*)d_in[4];
    const float* W2 = (const float*)d_in[5];
    const float* g2 = (const float*)d_in[6];
    const float* b2 = (const float*)d_in[7];
    const float* W3 = (const float*)d_in[8];
    const float* g3 = (const float*)d_in[9];
    const float* b3 = (const float*)d_in[10];

    char* ws = (char*)d_ws;
    float*          new_xyz = (float*)(ws + 0);                  // 196608 B
    int*            idx     = (int*)(ws + 196608);               // 2097152 B
    float*          ft      = (float*)(ws + 2293760);            // 16777216 B
    unsigned short* h1      = (unsigned short*)(ws + 19070976);  // 67108864 B
    unsigned short* h2      = (unsigned short*)(ws + 86179840);  // 67108864 B
    float*          hmax    = (float*)(ws + 153288704);          // 8388608 B
    float*          hmin    = (float*)(ws + 161677312);          // 8388608 B
    float*          sums    = (float*)(ws + 170065920);          // 2048 B (zeroed)
    float*          ab      = (float*)(ws + 170067968);          // 2048 B
    float* sums1 = sums;        float* ab1 = ab;
    float* sums2 = sums + 128;  float* ab2 = ab + 128;
    float* sums3 = sums + 256;  float* ab3 = ab + 256;

    // sorted point array (float4 x,y,z,idx) lives in h1's space: h1 is only
    // written by layer1 AFTER fps completes (stream order), so no conflict.
    float4* sorted = (float4*)h1;                 // NB*NN*16 = 1 MB

    float* out_newxyz = (float*)d_out;            // B*NS*3 = 49152 floats
    float* out_feats  = (float*)d_out + 49152;    // B*128*NS floats

    hipMemsetAsync(sums, 0, 2048, stream);

    sort_kernel<<<NB, 1024, 0, stream>>>(xyz, sorted);
    fps_kernel<<<NB, 1024, 0, stream>>>(xyz, sorted, new_xyz, out_newxyz);
    transpose_kernel<<<dim3(NN/64, NB), 256, 0, stream>>>(features, ft);
    ballquery_kernel<<<(NB*NS)/4, 256, 0, stream>>>(xyz, new_xyz, idx);
    layer1_kernel<<<NCOL/256, 256, 0, stream>>>(xyz, new_xyz, idx, ft, W1, h1);
    stats_kernel<<<1024, 256, 0, stream>>>(h1, sums1);
    finalize_kernel<<<1, 128, 0, stream>>>(sums1, g1, b1, ab1, 64);
    layer2_kernel<<<NCOL/256, 256, 0, stream>>>(h1, ab1, W2, h2);
    stats_kernel<<<1024, 256, 0, stream>>>(h2, sums2);
    finalize_kernel<<<1, 128, 0, stream>>>(sums2, g2, b2, ab2, 64);
    layer3_kernel<<<NCOL/256, 256, 0, stream>>>(h2, ab2, W3, hmax, hmin, sums3);
    finalize_kernel<<<1, 128, 0, stream>>>(sums3, g3, b3, ab3, 128);
    final_kernel<<<(NB*128*NS)/256, 256, 0, stream>>>(hmax, hmin, ab3, out_feats);
}

// Round 8
// 2112.386 us; speedup vs baseline: 2.6789x; 1.3427x over previous
//
#include <hip/hip_runtime.h>
#include <hip/hip_bf16.h>
#include <stdint.h>

#define NB 8
#define NN 8192
#define NC 64
#define NS 2048
#define NK 32
#define NCOL (NB*NS*NK)   // 524288 columns (b,s,n)

typedef float v2f __attribute__((ext_vector_type(2)));

// ---------- bf16 helpers (RNE) ----------
__device__ __forceinline__ unsigned short f2bf(float x) {
    union { float f; unsigned u; } c; c.f = x;
    unsigned r = c.u + 0x7fffu + ((c.u >> 16) & 1u);
    return (unsigned short)(r >> 16);
}
__device__ __forceinline__ float bf2f(unsigned v16) {
    union { float f; unsigned u; } c; c.u = v16 << 16;
    return c.f;
}

// ---------- DPP cross-lane helpers (VALU-speed, no LDS) ----------
// row_shr:n = 0x110|n, row_bcast15 = 0x142, row_bcast31 = 0x143
template<int CTRL>
__device__ __forceinline__ unsigned long long dpp_max_u64(unsigned long long key) {
    int olo = __builtin_amdgcn_update_dpp(0, (int)(unsigned)key,        CTRL, 0xf, 0xf, true);
    int ohi = __builtin_amdgcn_update_dpp(0, (int)(unsigned)(key >> 32), CTRL, 0xf, 0xf, true);
    unsigned long long ok = ((unsigned long long)(unsigned)ohi << 32) | (unsigned)olo;
    return ok > key ? ok : key;   // zero-fill loses to every real key
}
template<int CTRL>
__device__ __forceinline__ float dpp_add_f32(float x) {   // zero-fill identity
    int o = __builtin_amdgcn_update_dpp(0, __float_as_int(x), CTRL, 0xf, 0xf, true);
    return x + __int_as_float(o);
}
template<int CTRL>
__device__ __forceinline__ float dpp_max_f32(float x) {   // self identity
    int o = __builtin_amdgcn_update_dpp(__float_as_int(x), __float_as_int(x), CTRL, 0xf, 0xf, false);
    return fmaxf(x, __int_as_float(o));
}
template<int CTRL>
__device__ __forceinline__ float dpp_min_f32(float x) {   // self identity
    int o = __builtin_amdgcn_update_dpp(__float_as_int(x), __float_as_int(x), CTRL, 0xf, 0xf, false);
    return fminf(x, __int_as_float(o));
}
template<int CTRL, int RM>
__device__ __forceinline__ unsigned dpp_add_u32(unsigned x) {  // zero-fill, row-masked
    int o = __builtin_amdgcn_update_dpp(0, (int)x, CTRL, RM, 0xf, true);
    return x + (unsigned)o;
}
__device__ __forceinline__ float wave_red_min(float x) {  // full 64-lane min -> all lanes
    x = dpp_min_f32<0x111>(x); x = dpp_min_f32<0x112>(x);
    x = dpp_min_f32<0x114>(x); x = dpp_min_f32<0x118>(x);
    x = dpp_min_f32<0x142>(x); x = dpp_min_f32<0x143>(x);
    return __int_as_float(__builtin_amdgcn_readlane(__float_as_int(x), 63));
}
__device__ __forceinline__ float wave_red_max(float x) {  // full 64-lane max -> all lanes
    x = dpp_max_f32<0x111>(x); x = dpp_max_f32<0x112>(x);
    x = dpp_max_f32<0x114>(x); x = dpp_max_f32<0x118>(x);
    x = dpp_max_f32<0x142>(x); x = dpp_max_f32<0x143>(x);
    return __int_as_float(__builtin_amdgcn_readlane(__float_as_int(x), 63));
}
__device__ __forceinline__ v2f relu2(v2f v) {
    v.x = fmaxf(v.x, 0.f); v.y = fmaxf(v.y, 0.f); return v;
}

// ============================================================================
// 0) Spatial partition: counting sort on top-11 Morton bits (2048 buckets).
//    Any permutation is CORRECT (ordering only affects pruning rate); FPS
//    tie-breaking uses original indices. Proven in R2/R5-R7; ~15us vs
//    bitonic's ~100us.
// ============================================================================
__device__ __forceinline__ unsigned expand_bits10(unsigned v) {
    v = (v * 0x00010001u) & 0xFF0000FFu;
    v = (v * 0x00000101u) & 0x0F00F00Fu;
    v = (v * 0x00000011u) & 0xC30C30C3u;
    v = (v * 0x00000005u) & 0x49249249u;
    return v;
}
__global__ __launch_bounds__(1024) void sort_kernel(const float* __restrict__ xyz,
    float4* __restrict__ sorted)
{
    __shared__ unsigned cnt[2048];     // bucket counts -> start offsets
    __shared__ unsigned codes[NN];     // bucket id per point (32 KB)
    __shared__ unsigned wsum[16];
    const int b = blockIdx.x;
    const int tid = threadIdx.x;
    const int w = tid >> 6;
    const int lane = tid & 63;
    const float* xb = xyz + (size_t)b * NN * 3;
    cnt[tid] = 0; cnt[tid + 1024] = 0;
    __syncthreads();
    for (int p = tid; p < NN; p += 1024) {
        float x = xb[3*p+0], y = xb[3*p+1], z = xb[3*p+2];
        int qx = (int)(x * 1024.f); qx = qx < 0 ? 0 : (qx > 1023 ? 1023 : qx);
        int qy = (int)(y * 1024.f); qy = qy < 0 ? 0 : (qy > 1023 ? 1023 : qy);
        int qz = (int)(z * 1024.f); qz = qz < 0 ? 0 : (qz > 1023 ? 1023 : qz);
        unsigned m = expand_bits10((unsigned)qx)
                   | (expand_bits10((unsigned)qy) << 1)
                   | (expand_bits10((unsigned)qz) << 2);
        unsigned bk = m >> 19;                 // top 11 of 30 bits
        codes[p] = bk;
        atomicAdd(&cnt[bk], 1u);
    }
    __syncthreads();
    // exclusive scan of 2048 counts: thread t owns pair (2t, 2t+1)
    unsigned c0 = cnt[2*tid], c1 = cnt[2*tid+1];
    unsigned s = c0 + c1;
    unsigned v = s;                            // wave64 inclusive scan (canonical DPP)
    v = dpp_add_u32<0x111, 0xf>(v);
    v = dpp_add_u32<0x112, 0xf>(v);
    v = dpp_add_u32<0x114, 0xf>(v);
    v = dpp_add_u32<0x118, 0xf>(v);
    v = dpp_add_u32<0x142, 0xa>(v);            // bcast15 -> rows 1,3
    v = dpp_add_u32<0x143, 0xc>(v);            // bcast31 -> rows 2,3
    if (lane == 63) wsum[w] = v;
    __syncthreads();
    unsigned wbase = 0;
#pragma unroll
    for (int j = 0; j < 15; ++j) {             // exclusive prefix of wave totals
        unsigned t = wsum[j];
        wbase += (j < w) ? t : 0u;
    }
    unsigned excl = wbase + v - s;             // global exclusive prefix for bucket 2t
    cnt[2*tid]   = excl;                       // each thread touches only its own pair
    cnt[2*tid+1] = excl + c0;
    __syncthreads();
    // scatter
    for (int p = tid; p < NN; p += 1024) {
        unsigned bk = codes[p];
        unsigned pos = atomicAdd(&cnt[bk], 1u);
        float4 o;
        o.x = xb[3*p+0]; o.y = xb[3*p+1]; o.z = xb[3*p+2];
        o.w = __int_as_float(p);
        sorted[(size_t)b * NN + pos] = o;
    }
}

// ============================================================================
// 1) FPS — the MEASURED-BEST R1 kernel, restored verbatim (697 ns/iter,
//    1426 us). 8 blocks x 1024 threads = 16 waves; wave w owns sorted
//    [512w, 512w+512) (8 pts/lane in regs) with per-wave bbox pruning.
//    Exact fp32 match: contract(off), (dx2+dy2)+dz2 order, argmax tie = first
//    ORIGINAL index (u64 keys (val_bits<<32)|~orig_idx everywhere).
//    Intra-wave argmax: MONOLITHIC 6-stage u64 DPP chain (no mid-chain
//    readlane serialization — R7's split reduce with two readlanes +
//    ownership CSEL was 1.5x slower). Wave0-only merge between two
//    barriers: 4-stage u64 DPP over 16 keys, coord gather from the 96 KB
//    sx/sy/sz tables (broadcast reads), history written to s_hist and
//    flushed coalesced at the end. Single-buffered s_key[16] is race-free:
//    writes for iter i+1 happen only after barrier-2 of iter i, after
//    wave0's reads completed.
//    Pruning invariant: LB = clamped-bbox dist^2 computed with the SAME
//    rounding order is a certified fp32 lower bound of every d_new in the
//    chunk, so LB >= ckv (cached wave max dmin) => dmin and the wave's
//    cached key provably unchanged -> whole-wave skip (exact).
// ============================================================================
__global__ __launch_bounds__(1024) void fps_kernel(const float* __restrict__ xyz,
    const float4* __restrict__ sorted,
    float* __restrict__ new_xyz, float* __restrict__ out_newxyz)
{
#pragma clang fp contract(off)
    const int b = blockIdx.x;
    const int tid = threadIdx.x;
    const int w = tid >> 6;
    const int lane = tid & 63;
    __shared__ float sx[NN], sy[NN], sz[NN];             // 96 KB, indexed by ORIG idx
    __shared__ float s_hist[NS * 3];                     // 24 KB selected-coord history
    __shared__ unsigned long long s_key[16];
    const float4* sp = sorted + (size_t)b * NN + (size_t)w * 512 + lane;
    v2f px[4], py[4], pz[4], dmin[4];
    unsigned plo[8];                                     // ~orig_idx per point
    float bnx = 1e30f, bny = 1e30f, bnz = 1e30f;
    float bxx = -1e30f, bxy = -1e30f, bxz = -1e30f;
#pragma unroll
    for (int m = 0; m < 4; ++m) {
        float4 a = sp[128*m];                            // point k=2m
        float4 c = sp[128*m + 64];                       // point k=2m+1
        px[m].x = a.x; px[m].y = c.x;
        py[m].x = a.y; py[m].y = c.y;
        pz[m].x = a.z; pz[m].y = c.z;
        dmin[m].x = 1e10f; dmin[m].y = 1e10f;
        int ia = __float_as_int(a.w), ic = __float_as_int(c.w);
        plo[2*m]   = ~(unsigned)ia;
        plo[2*m+1] = ~(unsigned)ic;
        sx[ia] = a.x; sy[ia] = a.y; sz[ia] = a.z;        // scatter by orig idx
        sx[ic] = c.x; sy[ic] = c.y; sz[ic] = c.z;
        bnx = fminf(bnx, fminf(a.x, c.x)); bxx = fmaxf(bxx, fmaxf(a.x, c.x));
        bny = fminf(bny, fminf(a.y, c.y)); bxy = fmaxf(bxy, fmaxf(a.y, c.y));
        bnz = fminf(bnz, fminf(a.z, c.z)); bxz = fmaxf(bxz, fmaxf(a.z, c.z));
    }
    // wave bbox (uniform across the wave after readlane-broadcast)
    bnx = wave_red_min(bnx); bny = wave_red_min(bny); bnz = wave_red_min(bnz);
    bxx = wave_red_max(bxx); bxy = wave_red_max(bxy); bxz = wave_red_max(bxz);

    const float* xb = xyz + (size_t)b * NN * 3;
    float lx = xb[0], ly = xb[1], lz = xb[2];            // selection 0 = point 0
    if (tid == 0) { s_hist[0] = lx; s_hist[1] = ly; s_hist[2] = lz; }
    float ckv = 1e30f;                                   // cached wave max dmin (forces 1st compute)
    unsigned cklo = 0u;                                  // cached tie-winner ~orig_idx
    __syncthreads();                                     // sx/sy/sz + hist[0] visible

    for (int i = 1; i < NS; ++i) {
        // certified fp32 lower bound of d_new for every point in this chunk
        float cdx = fmaxf(fmaxf(bnx - lx, lx - bxx), 0.f);
        float cdy = fmaxf(fmaxf(bny - ly, ly - bxy), 0.f);
        float cdz = fmaxf(fmaxf(bnz - lz, lz - bxz), 0.f);
        float lb = (cdx*cdx + cdy*cdy) + cdz*cdz;
        if (!(lb >= ckv)) {                              // wave-uniform branch
            v2f l2x; l2x.x = lx; l2x.y = lx;
            v2f l2y; l2y.x = ly; l2y.y = ly;
            v2f l2z; l2z.x = lz; l2z.y = lz;
            unsigned long long best = 0ull;
#pragma unroll
            for (int m = 0; m < 4; ++m) {
                v2f dx = px[m] - l2x;
                v2f dy = py[m] - l2y;
                v2f dz = pz[m] - l2z;
                v2f d = (dx*dx + dy*dy) + dz*dz;         // pk mul/add, exact order
                v2f dm;
                dm.x = fminf(dmin[m].x, d.x);
                dm.y = fminf(dmin[m].y, d.y);
                dmin[m] = dm;
                unsigned long long k0 =
                    ((unsigned long long)__float_as_uint(dm.x) << 32) | plo[2*m];
                unsigned long long k1 =
                    ((unsigned long long)__float_as_uint(dm.y) << 32) | plo[2*m+1];
                if (k0 > best) best = k0;
                if (k1 > best) best = k1;
            }
            // MONOLITHIC DPP wave64 max-reduce -> lane 63, broadcast via readlane
            best = dpp_max_u64<0x111>(best);
            best = dpp_max_u64<0x112>(best);
            best = dpp_max_u64<0x114>(best);
            best = dpp_max_u64<0x118>(best);
            best = dpp_max_u64<0x142>(best);
            best = dpp_max_u64<0x143>(best);
            ckv  = __uint_as_float((unsigned)__builtin_amdgcn_readlane((int)(best >> 32), 63));
            cklo = (unsigned)__builtin_amdgcn_readlane((int)(best & 0xffffffffull), 63);
        }
        if (lane == 0)
            s_key[w] = ((unsigned long long)__float_as_uint(ckv) << 32) | cklo;
        __syncthreads();                                 // barrier 1: keys ready
        if (w == 0) {
            unsigned long long k = s_key[lane & 15];     // rows of 16 hold all keys
            k = dpp_max_u64<0x111>(k);
            k = dpp_max_u64<0x112>(k);
            k = dpp_max_u64<0x114>(k);
            k = dpp_max_u64<0x118>(k);                   // lane15 of each row = global max
            int lo15 = __builtin_amdgcn_readlane((int)(k & 0xffffffffull), 15);
            int ix = ~lo15;                              // original point index
            float nx = sx[ix], ny = sy[ix], nz = sz[ix]; // LDS broadcast read
            if (lane == 0) {
                s_hist[3*i+0] = nx; s_hist[3*i+1] = ny; s_hist[3*i+2] = nz;
            }
        }
        __syncthreads();                                 // barrier 2: coords ready
        lx = s_hist[3*i+0]; ly = s_hist[3*i+1]; lz = s_hist[3*i+2];
    }
    __syncthreads();                                     // last hist write visible
    // coalesced flush of the selected-coordinate history
    float* nw = new_xyz + (size_t)b * NS * 3;
    float* ow = out_newxyz + (size_t)b * NS * 3;
    for (int t = tid; t < NS * 3; t += 1024) {
        float v = s_hist[t];
        nw[t] = v; ow[t] = v;
    }
}

// ============================================================================
// 2) Transpose features (B,C,N) -> (B,N,C) for contiguous per-point gathers.
// ============================================================================
__global__ __launch_bounds__(256) void transpose_kernel(const float* __restrict__ f,
    float* __restrict__ ft)
{
    __shared__ float tile[64][65];
    int b = blockIdx.y;
    int p0 = blockIdx.x * 64;
    for (int k = threadIdx.x; k < 64*64; k += 256) {
        int c = k >> 6, p = k & 63;
        tile[c][p] = f[((size_t)b * NC + c) * NN + p0 + p];
    }
    __syncthreads();
    for (int k = threadIdx.x; k < 64*64; k += 256) {
        int p = k >> 6, c = k & 63;
        ft[((size_t)b * NN + p0 + p) * NC + c] = tile[c][p];
    }
}

// ============================================================================
// 3) Ball query: one wave per (b,s) query. First 32 smallest in-ball indices,
//    pad with first. r2 must be float(0.2*0.2) = 0.0399999991 (not 0.2f*0.2f).
// ============================================================================
__global__ __launch_bounds__(256) void ballquery_kernel(const float* __restrict__ xyz,
    const float* __restrict__ new_xyz, int* __restrict__ idx)
{
#pragma clang fp contract(off)
    const int q = blockIdx.x * 4 + (threadIdx.x >> 6);
    const int lane = threadIdx.x & 63;
    const int b = q >> 11;
    const float r2 = (float)(0.2 * 0.2);
    const float* xb = xyz + (size_t)b * NN * 3;
    const float* nx = new_xyz + (size_t)q * 3;
    float qx = nx[0], qy = nx[1], qz = nx[2];
    int cnt = 0, first = -1;
    int* out = idx + (size_t)q * NK;
    for (int base = 0; base < NN; base += 64) {
        int p = base + lane;
        float x = xb[p*3+0], y = xb[p*3+1], z = xb[p*3+2];
        float dx = qx - x, dy = qy - y, dz = qz - z;
        float d2 = (dx*dx + dy*dy) + dz*dz;
        bool in = d2 < r2;
        unsigned long long m = __ballot(in);
        if (m) {
            if (first < 0) first = base + __builtin_ctzll(m);
            if (in) {
                int rank = cnt + __popcll(m & ((1ull << lane) - 1ull));
                if (rank < NK) out[rank] = p;
            }
            cnt += __popcll(m);
            if (cnt >= NK) break;
        }
    }
    for (int k = cnt + lane; k < NK; k += 64) out[k] = first;  // cnt>=1 always
}

// ============================================================================
// 4) Layer 1: h1 = W1(64x67) @ g. v2f packed FMAs; h computed in two halves
//    of 32 outputs to keep VGPR below spill point. h1 bf16.
// ============================================================================
__global__ __launch_bounds__(256, 2) void layer1_kernel(const float* __restrict__ xyz,
    const float* __restrict__ new_xyz, const int* __restrict__ idx,
    const float* __restrict__ ft, const float* __restrict__ W1,
    unsigned short* __restrict__ h1)
{
    const int col = blockIdx.x * 256 + threadIdx.x;
    const int b = col >> 16;
    const int s = (col >> 5) & 2047;
    const int p = idx[col];
    v2f g[34];
    float* gf = (float*)g;
    {
        const float* nx = new_xyz + ((size_t)(b * NS + s)) * 3;
        const float* xp = xyz + ((size_t)(b * NN + p)) * 3;
        gf[0] = xp[0] - nx[0]; gf[1] = xp[1] - nx[1]; gf[2] = xp[2] - nx[2];
    }
    const float4* fp = (const float4*)(ft + ((size_t)(b * NN + p)) * NC);
#pragma unroll
    for (int c4 = 0; c4 < 16; ++c4) {
        float4 v = fp[c4];
        gf[3 + 4*c4 + 0] = v.x; gf[3 + 4*c4 + 1] = v.y;
        gf[3 + 4*c4 + 2] = v.z; gf[3 + 4*c4 + 3] = v.w;
    }
    gf[67] = 0.f;
    uint4* dst = (uint4*)(h1 + (size_t)col * 64);
#pragma unroll
    for (int half = 0; half < 2; ++half) {
        float h[32];
#pragma unroll 4
        for (int o16 = 0; o16 < 32; ++o16) {
            const float* w = W1 + (half*32 + o16) * 67;
            v2f acc; acc.x = 0.f; acc.y = 0.f;
#pragma unroll
            for (int k = 0; k < 33; ++k) {
                v2f wv; wv.x = w[2*k]; wv.y = w[2*k+1];
                acc = wv * g[k] + acc;                    // v_pk_fma_f32
            }
            h[o16] = fmaf(w[66], gf[66], acc.x + acc.y);
        }
#pragma unroll
        for (int k = 0; k < 4; ++k) {
            uint4 v;
            v.x = (unsigned)f2bf(h[8*k+0]) | ((unsigned)f2bf(h[8*k+1]) << 16);
            v.y = (unsigned)f2bf(h[8*k+2]) | ((unsigned)f2bf(h[8*k+3]) << 16);
            v.z = (unsigned)f2bf(h[8*k+4]) | ((unsigned)f2bf(h[8*k+5]) << 16);
            v.w = (unsigned)f2bf(h[8*k+6]) | ((unsigned)f2bf(h[8*k+7]) << 16);
            dst[half*4 + k] = v;
        }
    }
}

// ============================================================================
// 5) Stats pass over a bf16 [col][64] tensor: per-channel sum / sumsq.
// ============================================================================
__global__ __launch_bounds__(256) void stats_kernel(const unsigned short* __restrict__ h,
    float* __restrict__ sums)
{
    __shared__ float ls[64], lq[64];
    const int tid = threadIdx.x;
    if (tid < 64) { ls[tid] = 0.f; lq[tid] = 0.f; }
    __syncthreads();
    float s[8] = {0,0,0,0,0,0,0,0}, q[8] = {0,0,0,0,0,0,0,0};
    const int gt = blockIdx.x * 256 + tid;
    const int G = gridDim.x * 256;            // multiple of 8 -> channel phase fixed
    const uint4* src = (const uint4*)h;
    const int nvec = NCOL * 8;                 // uint4s (8 bf16 each)
    for (int i = gt; i < nvec; i += G) {
        uint4 v = src[i];
        float f0 = bf2f(v.x & 0xffffu), f1 = bf2f(v.x >> 16);
        float f2 = bf2f(v.y & 0xffffu), f3 = bf2f(v.y >> 16);
        float f4 = bf2f(v.z & 0xffffu), f5 = bf2f(v.z >> 16);
        float f6 = bf2f(v.w & 0xffffu), f7 = bf2f(v.w >> 16);
        s[0] += f0; q[0] = fmaf(f0, f0, q[0]);
        s[1] += f1; q[1] = fmaf(f1, f1, q[1]);
        s[2] += f2; q[2] = fmaf(f2, f2, q[2]);
        s[3] += f3; q[3] = fmaf(f3, f3, q[3]);
        s[4] += f4; q[4] = fmaf(f4, f4, q[4]);
        s[5] += f5; q[5] = fmaf(f5, f5, q[5]);
        s[6] += f6; q[6] = fmaf(f6, f6, q[6]);
        s[7] += f7; q[7] = fmaf(f7, f7, q[7]);
    }
    const int obase = (tid & 7) * 8;
#pragma unroll
    for (int j = 0; j < 8; ++j) {
        atomicAdd(&ls[obase + j], s[j]);
        atomicAdd(&lq[obase + j], q[j]);
    }
    __syncthreads();
    if (tid < 64) {
        atomicAdd(&sums[tid*2+0], ls[tid]);
        atomicAdd(&sums[tid*2+1], lq[tid]);
    }
}

// ============================================================================
// 6) Finalize BN params. Layout: ab[c] = a_c (scale), ab[nch+c] = b_c (shift)
//    so the apply step can use packed v2f math.
// ============================================================================
__global__ void finalize_kernel(const float* __restrict__ sums,
    const float* __restrict__ gamma, const float* __restrict__ beta,
    float* __restrict__ ab, int nch)
{
    int c = threadIdx.x;
    if (c < nch) {
        const float invM = 1.0f / 524288.0f;
        float mu = sums[c*2] * invM;
        float var = sums[c*2+1] * invM - mu * mu;
        float a = gamma[c] / sqrtf(var + 1e-5f);
        ab[c] = a;
        ab[nch + c] = fmaf(-mu, a, beta[c]);
    }
}

// ============================================================================
// 7) Layer 2: g2 = relu(BN1(h1)); h2 = W2(64x64) @ g2. Packed FMAs, halves.
// ============================================================================
__global__ __launch_bounds__(256, 2) void layer2_kernel(const unsigned short* __restrict__ h1,
    const float* __restrict__ ab1, const float* __restrict__ W2,
    unsigned short* __restrict__ h2)
{
    const int col = blockIdx.x * 256 + threadIdx.x;
    const uint4* src = (const uint4*)(h1 + (size_t)col * 64);
    v2f g[32];
    float* gf = (float*)g;
#pragma unroll
    for (int k = 0; k < 8; ++k) {
        uint4 v = src[k];
        gf[8*k+0] = bf2f(v.x & 0xffffu); gf[8*k+1] = bf2f(v.x >> 16);
        gf[8*k+2] = bf2f(v.y & 0xffffu); gf[8*k+3] = bf2f(v.y >> 16);
        gf[8*k+4] = bf2f(v.z & 0xffffu); gf[8*k+5] = bf2f(v.z >> 16);
        gf[8*k+6] = bf2f(v.w & 0xffffu); gf[8*k+7] = bf2f(v.w >> 16);
    }
    const v2f* a2 = (const v2f*)ab1;
    const v2f* b2 = (const v2f*)(ab1 + 64);
#pragma unroll
    for (int k = 0; k < 32; ++k)
        g[k] = relu2(a2[k] * g[k] + b2[k]);               // pk_fma + pk_max
    uint4* dst = (uint4*)(h2 + (size_t)col * 64);
#pragma unroll
    for (int half = 0; half < 2; ++half) {
        float h[32];
#pragma unroll 4
        for (int o16 = 0; o16 < 32; ++o16) {
            const float* w = W2 + ((half*32 + o16) << 6);
            v2f acc; acc.x = 0.f; acc.y = 0.f;
#pragma unroll
            for (int k = 0; k < 32; ++k) {
                v2f wv; wv.x = w[2*k]; wv.y = w[2*k+1];
                acc = wv * g[k] + acc;
            }
            h[o16] = acc.x + acc.y;
        }
#pragma unroll
        for (int k = 0; k < 4; ++k) {
            uint4 v;
            v.x = (unsigned)f2bf(h[8*k+0]) | ((unsigned)f2bf(h[8*k+1]) << 16);
            v.y = (unsigned)f2bf(h[8*k+2]) | ((unsigned)f2bf(h[8*k+3]) << 16);
            v.z = (unsigned)f2bf(h[8*k+4]) | ((unsigned)f2bf(h[8*k+5]) << 16);
            v.w = (unsigned)f2bf(h[8*k+6]) | ((unsigned)f2bf(h[8*k+7]) << 16);
            dst[half*4 + k] = v;
        }
    }
}

// ============================================================================
// 8) Layer 3: g3 = relu(BN2(h2)); h3 = W3(128x64) @ g3; per-(b,s) max/min over
//    n=32 (lanes) + channel stats — all reductions via DPP (no ds ops).
// ============================================================================
__global__ __launch_bounds__(256, 2) void layer3_kernel(const unsigned short* __restrict__ h2,
    const float* __restrict__ ab2, const float* __restrict__ W3,
    float* __restrict__ hmax, float* __restrict__ hmin, float* __restrict__ sums3)
{
    __shared__ float ls[128], lq[128];
    const int tid = threadIdx.x;
    if (tid < 128) { ls[tid] = 0.f; lq[tid] = 0.f; }
    __syncthreads();
    const int col = blockIdx.x * 256 + tid;
    const int q = col >> 5;            // group (b*2048+s); lanes 0-31 / 32-63
    const uint4* src = (const uint4*)(h2 + (size_t)col * 64);
    v2f g[32];
    float* gf = (float*)g;
#pragma unroll
    for (int k = 0; k < 8; ++k) {
        uint4 v = src[k];
        gf[8*k+0] = bf2f(v.x & 0xffffu); gf[8*k+1] = bf2f(v.x >> 16);
        gf[8*k+2] = bf2f(v.y & 0xffffu); gf[8*k+3] = bf2f(v.y >> 16);
        gf[8*k+4] = bf2f(v.z & 0xffffu); gf[8*k+5] = bf2f(v.z >> 16);
        gf[8*k+6] = bf2f(v.w & 0xffffu); gf[8*k+7] = bf2f(v.w >> 16);
    }
    const v2f* a2 = (const v2f*)ab2;
    const v2f* b2 = (const v2f*)(ab2 + 64);
#pragma unroll
    for (int k = 0; k < 32; ++k)
        g[k] = relu2(a2[k] * g[k] + b2[k]);
    const bool leader = ((tid & 31) == 31);
#pragma unroll 2
    for (int o = 0; o < 128; ++o) {
        const float* w = W3 + (o << 6);
        v2f acc; acc.x = 0.f; acc.y = 0.f;
#pragma unroll
        for (int k = 0; k < 32; ++k) {
            v2f wv; wv.x = w[2*k]; wv.y = w[2*k+1];
            acc = wv * g[k] + acc;
        }
        float hv = acc.x + acc.y;
        float sm = hv, sq = hv*hv, mx = hv, mn = hv;
        sm = dpp_add_f32<0x111>(sm); sq = dpp_add_f32<0x111>(sq);
        mx = dpp_max_f32<0x111>(mx); mn = dpp_min_f32<0x111>(mn);
        sm = dpp_add_f32<0x112>(sm); sq = dpp_add_f32<0x112>(sq);
        mx = dpp_max_f32<0x112>(mx); mn = dpp_min_f32<0x112>(mn);
        sm = dpp_add_f32<0x114>(sm); sq = dpp_add_f32<0x114>(sq);
        mx = dpp_max_f32<0x114>(mx); mn = dpp_min_f32<0x114>(mn);
        sm = dpp_add_f32<0x118>(sm); sq = dpp_add_f32<0x118>(sq);
        mx = dpp_max_f32<0x118>(mx); mn = dpp_min_f32<0x118>(mn);
        sm = dpp_add_f32<0x142>(sm); sq = dpp_add_f32<0x142>(sq);
        mx = dpp_max_f32<0x142>(mx); mn = dpp_min_f32<0x142>(mn);
        if (leader) {
            hmax[(size_t)o * 16384 + q] = mx;
            hmin[(size_t)o * 16384 + q] = mn;
            atomicAdd(&ls[o], sm);
            atomicAdd(&lq[o], sq);
        }
    }
    __syncthreads();
    if (tid < 128) {
        atomicAdd(&sums3[tid*2+0], ls[tid]);
        atomicAdd(&sums3[tid*2+1], lq[tid]);
    }
}

// ============================================================================
// 9) Final: feats[b,o,s] = relu(a3*(a3>=0 ? max : min) + c3)
// ============================================================================
__global__ __launch_bounds__(256) void final_kernel(const float* __restrict__ hmax,
    const float* __restrict__ hmin, const float* __restrict__ ab3,
    float* __restrict__ out)
{
    const int t = blockIdx.x * 256 + threadIdx.x;   // (b,o,s), s fastest
    const int s = t & 2047;
    const int o = (t >> 11) & 127;
    const int b = t >> 18;
    const int q = (b << 11) + s;
    float a = ab3[o], c = ab3[128 + o];
    float h = (a >= 0.f) ? hmax[(size_t)o * 16384 + q] : hmin[(size_t)o * 16384 + q];
    out[t] = fmaxf(fmaf(a, h, c), 0.f);
}

// ============================================================================
extern "C" void kernel_launch(void* const* d_in, const int* in_sizes, int n_in,
                              void* d_out, int out_size, void* d_ws, size_t ws_size,
                              hipStream_t stream) {
    (void)in_sizes; (void)n_in; (void)out_size; (void)ws_size;
    const float* xyz      = (const float*)d_in[0];
    const float* features = (const float*)d_in[1];
    const float* W1 = (const float*)d_in[2];
    const float* g1 = (const float*)d_in[3];
    const float* b1 = (const float*)d_in[4];
    const float* W2 = (const float*)d_in[5];
    const float* g2 = (const float*)d_in[6];
    const float* b2 = (const float*)d_in[7];
    const float* W3 = (const float*)d_in[8];
    const float* g3 = (const float*)d_in[9];
    const float* b3 = (const float*)d_in[10];

    char* ws = (char*)d_ws;
    float*          new_xyz = (float*)(ws + 0);                  // 196608 B
    int*            idx     = (int*)(ws + 196608);               // 2097152 B
    float*          ft      = (float*)(ws + 2293760);            // 16777216 B
    unsigned short* h1      = (unsigned short*)(ws + 19070976);  // 67108864 B
    unsigned short* h2      = (unsigned short*)(ws + 86179840);  // 67108864 B
    float*          hmax    = (float*)(ws + 153288704);          // 8388608 B
    float*          hmin    = (float*)(ws + 161677312);          // 8388608 B
    float*          sums    = (float*)(ws + 170065920);          // 2048 B (zeroed)
    float*          ab      = (float*)(ws + 170067968);          // 2048 B
    float* sums1 = sums;        float* ab1 = ab;
    float* sums2 = sums + 128;  float* ab2 = ab + 128;
    float* sums3 = sums + 256;  float* ab3 = ab + 256;

    // sorted point array (float4 x,y,z,idx) lives in h1's space: h1 is only
    // written by layer1 AFTER fps completes (stream order), so no conflict.
    float4* sorted = (float4*)h1;                 // NB*NN*16 = 1 MB

    float* out_newxyz = (float*)d_out;            // B*NS*3 = 49152 floats
    float* out_feats  = (float*)d_out + 49152;    // B*128*NS floats

    hipMemsetAsync(sums, 0, 2048, stream);

    sort_kernel<<<NB, 1024, 0, stream>>>(xyz, sorted);
    fps_kernel<<<NB, 1024, 0, stream>>>(xyz, sorted, new_xyz, out_newxyz);
    transpose_kernel<<<dim3(NN/64, NB), 256, 0, stream>>>(features, ft);
    ballquery_kernel<<<(NB*NS)/4, 256, 0, stream>>>(xyz, new_xyz, idx);
    layer1_kernel<<<NCOL/256, 256, 0, stream>>>(xyz, new_xyz, idx, ft, W1, h1);
    stats_kernel<<<1024, 256, 0, stream>>>(h1, sums1);
    finalize_kernel<<<1, 128, 0, stream>>>(sums1, g1, b1, ab1, 64);
    layer2_kernel<<<NCOL/256, 256, 0, stream>>>(h1, ab1, W2, h2);
    stats_kernel<<<1024, 256, 0, stream>>>(h2, sums2);
    finalize_kernel<<<1, 128, 0, stream>>>(sums2, g2, b2, ab2, 64);
    layer3_kernel<<<NCOL/256, 256, 0, stream>>>(h2, ab2, W3, hmax, hmin, sums3);
    finalize_kernel<<<1, 128, 0, stream>>>(sums3, g3, b3, ab3, 128);
    final_kernel<<<(NB*128*NS)/256, 256, 0, stream>>>(hmax, hmin, ab3, out_feats);
}

// Round 9
// 2039.352 us; speedup vs baseline: 2.7748x; 1.0358x over previous
//
#include <hip/hip_runtime.h>
#include <hip/hip_bf16.h>
#include <stdint.h>

#define NB 8
#define NN 8192
#define NC 64
#define NS 2048
#define NK 32
#define NCOL (NB*NS*NK)   // 524288 columns (b,s,n)

typedef float v2f __attribute__((ext_vector_type(2)));

// ---------- bf16 helpers (RNE) ----------
__device__ __forceinline__ unsigned short f2bf(float x) {
    union { float f; unsigned u; } c; c.f = x;
    unsigned r = c.u + 0x7fffu + ((c.u >> 16) & 1u);
    return (unsigned short)(r >> 16);
}
__device__ __forceinline__ float bf2f(unsigned v16) {
    union { float f; unsigned u; } c; c.u = v16 << 16;
    return c.f;
}

// ---------- DPP cross-lane helpers (VALU-speed, no LDS) ----------
// row_shr:n = 0x110|n, row_bcast15 = 0x142, row_bcast31 = 0x143
template<int CTRL>
__device__ __forceinline__ unsigned long long dpp_max_u64(unsigned long long key) {
    int olo = __builtin_amdgcn_update_dpp(0, (int)(unsigned)key,        CTRL, 0xf, 0xf, true);
    int ohi = __builtin_amdgcn_update_dpp(0, (int)(unsigned)(key >> 32), CTRL, 0xf, 0xf, true);
    unsigned long long ok = ((unsigned long long)(unsigned)ohi << 32) | (unsigned)olo;
    return ok > key ? ok : key;   // zero-fill loses to every real key
}
template<int CTRL>
__device__ __forceinline__ float dpp_add_f32(float x) {   // zero-fill identity
    int o = __builtin_amdgcn_update_dpp(0, __float_as_int(x), CTRL, 0xf, 0xf, true);
    return x + __int_as_float(o);
}
template<int CTRL>
__device__ __forceinline__ float dpp_max_f32(float x) {   // self identity
    int o = __builtin_amdgcn_update_dpp(__float_as_int(x), __float_as_int(x), CTRL, 0xf, 0xf, false);
    return fmaxf(x, __int_as_float(o));
}
template<int CTRL>
__device__ __forceinline__ float dpp_min_f32(float x) {   // self identity
    int o = __builtin_amdgcn_update_dpp(__float_as_int(x), __float_as_int(x), CTRL, 0xf, 0xf, false);
    return fminf(x, __int_as_float(o));
}
template<int CTRL, int RM>
__device__ __forceinline__ unsigned dpp_add_u32(unsigned x) {  // zero-fill, row-masked
    int o = __builtin_amdgcn_update_dpp(0, (int)x, CTRL, RM, 0xf, true);
    return x + (unsigned)o;
}
__device__ __forceinline__ float wave_red_min(float x) {  // full 64-lane min -> all lanes
    x = dpp_min_f32<0x111>(x); x = dpp_min_f32<0x112>(x);
    x = dpp_min_f32<0x114>(x); x = dpp_min_f32<0x118>(x);
    x = dpp_min_f32<0x142>(x); x = dpp_min_f32<0x143>(x);
    return __int_as_float(__builtin_amdgcn_readlane(__float_as_int(x), 63));
}
__device__ __forceinline__ float wave_red_max(float x) {  // full 64-lane max -> all lanes
    x = dpp_max_f32<0x111>(x); x = dpp_max_f32<0x112>(x);
    x = dpp_max_f32<0x114>(x); x = dpp_max_f32<0x118>(x);
    x = dpp_max_f32<0x142>(x); x = dpp_max_f32<0x143>(x);
    return __int_as_float(__builtin_amdgcn_readlane(__float_as_int(x), 63));
}
__device__ __forceinline__ v2f relu2(v2f v) {
    v.x = fmaxf(v.x, 0.f); v.y = fmaxf(v.y, 0.f); return v;
}

// ============================================================================
// 0) Spatial partition: counting sort on top-11 Morton bits (2048 buckets).
//    Any permutation is CORRECT (ordering only affects pruning rate); FPS
//    tie-breaking uses original indices. Proven in R2/R5-R8.
// ============================================================================
__device__ __forceinline__ unsigned expand_bits10(unsigned v) {
    v = (v * 0x00010001u) & 0xFF0000FFu;
    v = (v * 0x00000101u) & 0x0F00F00Fu;
    v = (v * 0x00000011u) & 0xC30C30C3u;
    v = (v * 0x00000005u) & 0x49249249u;
    return v;
}
__global__ __launch_bounds__(1024) void sort_kernel(const float* __restrict__ xyz,
    float4* __restrict__ sorted)
{
    __shared__ unsigned cnt[2048];     // bucket counts -> start offsets
    __shared__ unsigned codes[NN];     // bucket id per point (32 KB)
    __shared__ unsigned wsum[16];
    const int b = blockIdx.x;
    const int tid = threadIdx.x;
    const int w = tid >> 6;
    const int lane = tid & 63;
    const float* xb = xyz + (size_t)b * NN * 3;
    cnt[tid] = 0; cnt[tid + 1024] = 0;
    __syncthreads();
    for (int p = tid; p < NN; p += 1024) {
        float x = xb[3*p+0], y = xb[3*p+1], z = xb[3*p+2];
        int qx = (int)(x * 1024.f); qx = qx < 0 ? 0 : (qx > 1023 ? 1023 : qx);
        int qy = (int)(y * 1024.f); qy = qy < 0 ? 0 : (qy > 1023 ? 1023 : qy);
        int qz = (int)(z * 1024.f); qz = qz < 0 ? 0 : (qz > 1023 ? 1023 : qz);
        unsigned m = expand_bits10((unsigned)qx)
                   | (expand_bits10((unsigned)qy) << 1)
                   | (expand_bits10((unsigned)qz) << 2);
        unsigned bk = m >> 19;                 // top 11 of 30 bits
        codes[p] = bk;
        atomicAdd(&cnt[bk], 1u);
    }
    __syncthreads();
    // exclusive scan of 2048 counts: thread t owns pair (2t, 2t+1)
    unsigned c0 = cnt[2*tid], c1 = cnt[2*tid+1];
    unsigned s = c0 + c1;
    unsigned v = s;                            // wave64 inclusive scan (canonical DPP)
    v = dpp_add_u32<0x111, 0xf>(v);
    v = dpp_add_u32<0x112, 0xf>(v);
    v = dpp_add_u32<0x114, 0xf>(v);
    v = dpp_add_u32<0x118, 0xf>(v);
    v = dpp_add_u32<0x142, 0xa>(v);            // bcast15 -> rows 1,3
    v = dpp_add_u32<0x143, 0xc>(v);            // bcast31 -> rows 2,3
    if (lane == 63) wsum[w] = v;
    __syncthreads();
    unsigned wbase = 0;
#pragma unroll
    for (int j = 0; j < 15; ++j) {             // exclusive prefix of wave totals
        unsigned t = wsum[j];
        wbase += (j < w) ? t : 0u;
    }
    unsigned excl = wbase + v - s;             // global exclusive prefix for bucket 2t
    cnt[2*tid]   = excl;                       // each thread touches only its own pair
    cnt[2*tid+1] = excl + c0;
    __syncthreads();
    // scatter
    for (int p = tid; p < NN; p += 1024) {
        unsigned bk = codes[p];
        unsigned pos = atomicAdd(&cnt[bk], 1u);
        float4 o;
        o.x = xb[3*p+0]; o.y = xb[3*p+1]; o.z = xb[3*p+2];
        o.w = __int_as_float(p);
        sorted[(size_t)b * NN + pos] = o;
    }
}

// ============================================================================
// 1) FPS — R8 skeleton (16 waves x 512-pt chunks, bbox prune, monolithic
//    6-stage u64 DPP intra-wave reduce) with the cross-wave merge replaced
//    by a single LDS u64 atomicMax and ONE barrier per iteration.
//    Per iter: [reset future slot] -> LB/compute -> lane0 atomicMax(key)
//    -> barrier -> ALL threads read winning key (b64 broadcast) -> ix =
//    ~lo32 -> sx/sy/sz gather (broadcast). Removes barrier-2, wave0's
//    serial 4-stage u64 DPP merge, and the s_hist write->read roundtrip.
//    Bit-exact: atomic max over the same 16 u64 keys, same tie order
//    ((dmin_bits<<32)|~orig_idx; dmin>=0 so u64 order == (f32,~idx) order).
//    3-slot rotation safety (one barrier/iter):
//      iter i: reset slot[(i+1)%3], atomicMax slot[i%3], read slot[i%3].
//      - reset vs its last readers: slot[(i+1)%3]==slot[(i-2)%3] was read
//        between barrier(i-2) and barrier(i-1); reset happens after
//        barrier(i-1). Ordered.
//      - reset vs its next writers: writes to that slot happen at iter i+1
//        after barrier(i). Ordered.
//      - read vs next reset: readers of slot[i%3] finish before
//        barrier(i+1); next reset at iter i+2 after barrier(i+1). Ordered.
//    Pruning invariant unchanged: LB = clamped-bbox dist^2 in the same
//    rounding order certifies whole-wave skip (exact).
// ============================================================================
__global__ __launch_bounds__(1024) void fps_kernel(const float* __restrict__ xyz,
    const float4* __restrict__ sorted,
    float* __restrict__ new_xyz, float* __restrict__ out_newxyz)
{
#pragma clang fp contract(off)
    const int b = blockIdx.x;
    const int tid = threadIdx.x;
    const int w = tid >> 6;
    const int lane = tid & 63;
    __shared__ float sx[NN], sy[NN], sz[NN];             // 96 KB, indexed by ORIG idx
    __shared__ float s_hist[NS * 3];                     // 24 KB selected-coord history
    __shared__ unsigned long long s_slot[3];             // rotating merge slots
    const float4* sp = sorted + (size_t)b * NN + (size_t)w * 512 + lane;
    v2f px[4], py[4], pz[4], dmin[4];
    unsigned plo[8];                                     // ~orig_idx per point
    float bnx = 1e30f, bny = 1e30f, bnz = 1e30f;
    float bxx = -1e30f, bxy = -1e30f, bxz = -1e30f;
#pragma unroll
    for (int m = 0; m < 4; ++m) {
        float4 a = sp[128*m];                            // point k=2m
        float4 c = sp[128*m + 64];                       // point k=2m+1
        px[m].x = a.x; px[m].y = c.x;
        py[m].x = a.y; py[m].y = c.y;
        pz[m].x = a.z; pz[m].y = c.z;
        dmin[m].x = 1e10f; dmin[m].y = 1e10f;
        int ia = __float_as_int(a.w), ic = __float_as_int(c.w);
        plo[2*m]   = ~(unsigned)ia;
        plo[2*m+1] = ~(unsigned)ic;
        sx[ia] = a.x; sy[ia] = a.y; sz[ia] = a.z;        // scatter by orig idx
        sx[ic] = c.x; sy[ic] = c.y; sz[ic] = c.z;
        bnx = fminf(bnx, fminf(a.x, c.x)); bxx = fmaxf(bxx, fmaxf(a.x, c.x));
        bny = fminf(bny, fminf(a.y, c.y)); bxy = fmaxf(bxy, fmaxf(a.y, c.y));
        bnz = fminf(bnz, fminf(a.z, c.z)); bxz = fmaxf(bxz, fmaxf(a.z, c.z));
    }
    // wave bbox (uniform across the wave after readlane-broadcast)
    bnx = wave_red_min(bnx); bny = wave_red_min(bny); bnz = wave_red_min(bnz);
    bxx = wave_red_max(bxx); bxy = wave_red_max(bxy); bxz = wave_red_max(bxz);

    const float* xb = xyz + (size_t)b * NN * 3;
    float lx = xb[0], ly = xb[1], lz = xb[2];            // selection 0 = point 0
    if (tid == 0) {
        s_hist[0] = lx; s_hist[1] = ly; s_hist[2] = lz;
        s_slot[0] = 0ull; s_slot[1] = 0ull; s_slot[2] = 0ull;
    }
    float ckv = 1e30f;                                   // cached wave max dmin (forces 1st compute)
    unsigned cklo = 0u;                                  // cached tie-winner ~orig_idx
    __syncthreads();                                     // sx/sy/sz + slots + hist[0] visible

    int cur = 1, nxt = 2;                                // cur = i%3, nxt = (i+1)%3 at i=1
    for (int i = 1; i < NS; ++i) {
        if (tid == 0) s_slot[nxt] = 0ull;                // reset future slot (safe window)
        // certified fp32 lower bound of d_new for every point in this chunk
        float cdx = fmaxf(fmaxf(bnx - lx, lx - bxx), 0.f);
        float cdy = fmaxf(fmaxf(bny - ly, ly - bxy), 0.f);
        float cdz = fmaxf(fmaxf(bnz - lz, lz - bxz), 0.f);
        float lb = (cdx*cdx + cdy*cdy) + cdz*cdz;
        if (!(lb >= ckv)) {                              // wave-uniform branch
            v2f l2x; l2x.x = lx; l2x.y = lx;
            v2f l2y; l2y.x = ly; l2y.y = ly;
            v2f l2z; l2z.x = lz; l2z.y = lz;
            unsigned long long best = 0ull;
#pragma unroll
            for (int m = 0; m < 4; ++m) {
                v2f dx = px[m] - l2x;
                v2f dy = py[m] - l2y;
                v2f dz = pz[m] - l2z;
                v2f d = (dx*dx + dy*dy) + dz*dz;         // pk mul/add, exact order
                v2f dm;
                dm.x = fminf(dmin[m].x, d.x);
                dm.y = fminf(dmin[m].y, d.y);
                dmin[m] = dm;
                unsigned long long k0 =
                    ((unsigned long long)__float_as_uint(dm.x) << 32) | plo[2*m];
                unsigned long long k1 =
                    ((unsigned long long)__float_as_uint(dm.y) << 32) | plo[2*m+1];
                if (k0 > best) best = k0;
                if (k1 > best) best = k1;
            }
            // MONOLITHIC DPP wave64 max-reduce -> lane 63, broadcast via readlane
            best = dpp_max_u64<0x111>(best);
            best = dpp_max_u64<0x112>(best);
            best = dpp_max_u64<0x114>(best);
            best = dpp_max_u64<0x118>(best);
            best = dpp_max_u64<0x142>(best);
            best = dpp_max_u64<0x143>(best);
            ckv  = __uint_as_float((unsigned)__builtin_amdgcn_readlane((int)(best >> 32), 63));
            cklo = (unsigned)__builtin_amdgcn_readlane((int)(best & 0xffffffffull), 63);
        }
        if (lane == 0)
            atomicMax(&s_slot[cur],
                      ((unsigned long long)__float_as_uint(ckv) << 32) | cklo);
        __syncthreads();                                 // the ONLY barrier per iter
        const unsigned long long k = s_slot[cur];        // b64 broadcast read
        const int ix = ~(int)(unsigned)(k & 0xffffffffull);  // original point index
        lx = sx[ix]; ly = sy[ix]; lz = sz[ix];           // LDS broadcast gather
        if (tid == 0) {
            s_hist[3*i+0] = lx; s_hist[3*i+1] = ly; s_hist[3*i+2] = lz;
        }
        cur = nxt;                                       // rotate slot indices
        nxt = nxt + 1; if (nxt == 3) nxt = 0;
    }
    __syncthreads();                                     // last hist write visible
    // coalesced flush of the selected-coordinate history
    float* nw = new_xyz + (size_t)b * NS * 3;
    float* ow = out_newxyz + (size_t)b * NS * 3;
    for (int t = tid; t < NS * 3; t += 1024) {
        float v = s_hist[t];
        nw[t] = v; ow[t] = v;
    }
}

// ============================================================================
// 2) Transpose features (B,C,N) -> (B,N,C) for contiguous per-point gathers.
// ============================================================================
__global__ __launch_bounds__(256) void transpose_kernel(const float* __restrict__ f,
    float* __restrict__ ft)
{
    __shared__ float tile[64][65];
    int b = blockIdx.y;
    int p0 = blockIdx.x * 64;
    for (int k = threadIdx.x; k < 64*64; k += 256) {
        int c = k >> 6, p = k & 63;
        tile[c][p] = f[((size_t)b * NC + c) * NN + p0 + p];
    }
    __syncthreads();
    for (int k = threadIdx.x; k < 64*64; k += 256) {
        int p = k >> 6, c = k & 63;
        ft[((size_t)b * NN + p0 + p) * NC + c] = tile[c][p];
    }
}

// ============================================================================
// 3) Ball query: one wave per (b,s) query. First 32 smallest in-ball indices,
//    pad with first. r2 must be float(0.2*0.2) = 0.0399999991 (not 0.2f*0.2f).
// ============================================================================
__global__ __launch_bounds__(256) void ballquery_kernel(const float* __restrict__ xyz,
    const float* __restrict__ new_xyz, int* __restrict__ idx)
{
#pragma clang fp contract(off)
    const int q = blockIdx.x * 4 + (threadIdx.x >> 6);
    const int lane = threadIdx.x & 63;
    const int b = q >> 11;
    const float r2 = (float)(0.2 * 0.2);
    const float* xb = xyz + (size_t)b * NN * 3;
    const float* nx = new_xyz + (size_t)q * 3;
    float qx = nx[0], qy = nx[1], qz = nx[2];
    int cnt = 0, first = -1;
    int* out = idx + (size_t)q * NK;
    for (int base = 0; base < NN; base += 64) {
        int p = base + lane;
        float x = xb[p*3+0], y = xb[p*3+1], z = xb[p*3+2];
        float dx = qx - x, dy = qy - y, dz = qz - z;
        float d2 = (dx*dx + dy*dy) + dz*dz;
        bool in = d2 < r2;
        unsigned long long m = __ballot(in);
        if (m) {
            if (first < 0) first = base + __builtin_ctzll(m);
            if (in) {
                int rank = cnt + __popcll(m & ((1ull << lane) - 1ull));
                if (rank < NK) out[rank] = p;
            }
            cnt += __popcll(m);
            if (cnt >= NK) break;
        }
    }
    for (int k = cnt + lane; k < NK; k += 64) out[k] = first;  // cnt>=1 always
}

// ============================================================================
// 4) Layer 1: h1 = W1(64x67) @ g. v2f packed FMAs; h computed in two halves
//    of 32 outputs to keep VGPR below spill point. h1 bf16.
// ============================================================================
__global__ __launch_bounds__(256, 2) void layer1_kernel(const float* __restrict__ xyz,
    const float* __restrict__ new_xyz, const int* __restrict__ idx,
    const float* __restrict__ ft, const float* __restrict__ W1,
    unsigned short* __restrict__ h1)
{
    const int col = blockIdx.x * 256 + threadIdx.x;
    const int b = col >> 16;
    const int s = (col >> 5) & 2047;
    const int p = idx[col];
    v2f g[34];
    float* gf = (float*)g;
    {
        const float* nx = new_xyz + ((size_t)(b * NS + s)) * 3;
        const float* xp = xyz + ((size_t)(b * NN + p)) * 3;
        gf[0] = xp[0] - nx[0]; gf[1] = xp[1] - nx[1]; gf[2] = xp[2] - nx[2];
    }
    const float4* fp = (const float4*)(ft + ((size_t)(b * NN + p)) * NC);
#pragma unroll
    for (int c4 = 0; c4 < 16; ++c4) {
        float4 v = fp[c4];
        gf[3 + 4*c4 + 0] = v.x; gf[3 + 4*c4 + 1] = v.y;
        gf[3 + 4*c4 + 2] = v.z; gf[3 + 4*c4 + 3] = v.w;
    }
    gf[67] = 0.f;
    uint4* dst = (uint4*)(h1 + (size_t)col * 64);
#pragma unroll
    for (int half = 0; half < 2; ++half) {
        float h[32];
#pragma unroll 4
        for (int o16 = 0; o16 < 32; ++o16) {
            const float* w = W1 + (half*32 + o16) * 67;
            v2f acc; acc.x = 0.f; acc.y = 0.f;
#pragma unroll
            for (int k = 0; k < 33; ++k) {
                v2f wv; wv.x = w[2*k]; wv.y = w[2*k+1];
                acc = wv * g[k] + acc;                    // v_pk_fma_f32
            }
            h[o16] = fmaf(w[66], gf[66], acc.x + acc.y);
        }
#pragma unroll
        for (int k = 0; k < 4; ++k) {
            uint4 v;
            v.x = (unsigned)f2bf(h[8*k+0]) | ((unsigned)f2bf(h[8*k+1]) << 16);
            v.y = (unsigned)f2bf(h[8*k+2]) | ((unsigned)f2bf(h[8*k+3]) << 16);
            v.z = (unsigned)f2bf(h[8*k+4]) | ((unsigned)f2bf(h[8*k+5]) << 16);
            v.w = (unsigned)f2bf(h[8*k+6]) | ((unsigned)f2bf(h[8*k+7]) << 16);
            dst[half*4 + k] = v;
        }
    }
}

// ============================================================================
// 5) Stats pass over a bf16 [col][64] tensor: per-channel sum / sumsq.
// ============================================================================
__global__ __launch_bounds__(256) void stats_kernel(const unsigned short* __restrict__ h,
    float* __restrict__ sums)
{
    __shared__ float ls[64], lq[64];
    const int tid = threadIdx.x;
    if (tid < 64) { ls[tid] = 0.f; lq[tid] = 0.f; }
    __syncthreads();
    float s[8] = {0,0,0,0,0,0,0,0}, q[8] = {0,0,0,0,0,0,0,0};
    const int gt = blockIdx.x * 256 + tid;
    const int G = gridDim.x * 256;            // multiple of 8 -> channel phase fixed
    const uint4* src = (const uint4*)h;
    const int nvec = NCOL * 8;                 // uint4s (8 bf16 each)
    for (int i = gt; i < nvec; i += G) {
        uint4 v = src[i];
        float f0 = bf2f(v.x & 0xffffu), f1 = bf2f(v.x >> 16);
        float f2 = bf2f(v.y & 0xffffu), f3 = bf2f(v.y >> 16);
        float f4 = bf2f(v.z & 0xffffu), f5 = bf2f(v.z >> 16);
        float f6 = bf2f(v.w & 0xffffu), f7 = bf2f(v.w >> 16);
        s[0] += f0; q[0] = fmaf(f0, f0, q[0]);
        s[1] += f1; q[1] = fmaf(f1, f1, q[1]);
        s[2] += f2; q[2] = fmaf(f2, f2, q[2]);
        s[3] += f3; q[3] = fmaf(f3, f3, q[3]);
        s[4] += f4; q[4] = fmaf(f4, f4, q[4]);
        s[5] += f5; q[5] = fmaf(f5, f5, q[5]);
        s[6] += f6; q[6] = fmaf(f6, f6, q[6]);
        s[7] += f7; q[7] = fmaf(f7, f7, q[7]);
    }
    const int obase = (tid & 7) * 8;
#pragma unroll
    for (int j = 0; j < 8; ++j) {
        atomicAdd(&ls[obase + j], s[j]);
        atomicAdd(&lq[obase + j], q[j]);
    }
    __syncthreads();
    if (tid < 64) {
        atomicAdd(&sums[tid*2+0], ls[tid]);
        atomicAdd(&sums[tid*2+1], lq[tid]);
    }
}

// ============================================================================
// 6) Finalize BN params. Layout: ab[c] = a_c (scale), ab[nch+c] = b_c (shift)
//    so the apply step can use packed v2f math.
// ============================================================================
__global__ void finalize_kernel(const float* __restrict__ sums,
    const float* __restrict__ gamma, const float* __restrict__ beta,
    float* __restrict__ ab, int nch)
{
    int c = threadIdx.x;
    if (c < nch) {
        const float invM = 1.0f / 524288.0f;
        float mu = sums[c*2] * invM;
        float var = sums[c*2+1] * invM - mu * mu;
        float a = gamma[c] / sqrtf(var + 1e-5f);
        ab[c] = a;
        ab[nch + c] = fmaf(-mu, a, beta[c]);
    }
}

// ============================================================================
// 7) Layer 2: g2 = relu(BN1(h1)); h2 = W2(64x64) @ g2. Packed FMAs, halves.
// ============================================================================
__global__ __launch_bounds__(256, 2) void layer2_kernel(const unsigned short* __restrict__ h1,
    const float* __restrict__ ab1, const float* __restrict__ W2,
    unsigned short* __restrict__ h2)
{
    const int col = blockIdx.x * 256 + threadIdx.x;
    const uint4* src = (const uint4*)(h1 + (size_t)col * 64);
    v2f g[32];
    float* gf = (float*)g;
#pragma unroll
    for (int k = 0; k < 8; ++k) {
        uint4 v = src[k];
        gf[8*k+0] = bf2f(v.x & 0xffffu); gf[8*k+1] = bf2f(v.x >> 16);
        gf[8*k+2] = bf2f(v.y & 0xffffu); gf[8*k+3] = bf2f(v.y >> 16);
        gf[8*k+4] = bf2f(v.z & 0xffffu); gf[8*k+5] = bf2f(v.z >> 16);
        gf[8*k+6] = bf2f(v.w & 0xffffu); gf[8*k+7] = bf2f(v.w >> 16);
    }
    const v2f* a2 = (const v2f*)ab1;
    const v2f* b2 = (const v2f*)(ab1 + 64);
#pragma unroll
    for (int k = 0; k < 32; ++k)
        g[k] = relu2(a2[k] * g[k] + b2[k]);               // pk_fma + pk_max
    uint4* dst = (uint4*)(h2 + (size_t)col * 64);
#pragma unroll
    for (int half = 0; half < 2; ++half) {
        float h[32];
#pragma unroll 4
        for (int o16 = 0; o16 < 32; ++o16) {
            const float* w = W2 + ((half*32 + o16) << 6);
            v2f acc; acc.x = 0.f; acc.y = 0.f;
#pragma unroll
            for (int k = 0; k < 32; ++k) {
                v2f wv; wv.x = w[2*k]; wv.y = w[2*k+1];
                acc = wv * g[k] + acc;
            }
            h[o16] = acc.x + acc.y;
        }
#pragma unroll
        for (int k = 0; k < 4; ++k) {
            uint4 v;
            v.x = (unsigned)f2bf(h[8*k+0]) | ((unsigned)f2bf(h[8*k+1]) << 16);
            v.y = (unsigned)f2bf(h[8*k+2]) | ((unsigned)f2bf(h[8*k+3]) << 16);
            v.z = (unsigned)f2bf(h[8*k+4]) | ((unsigned)f2bf(h[8*k+5]) << 16);
            v.w = (unsigned)f2bf(h[8*k+6]) | ((unsigned)f2bf(h[8*k+7]) << 16);
            dst[half*4 + k] = v;
        }
    }
}

// ============================================================================
// 8) Layer 3: g3 = relu(BN2(h2)); h3 = W3(128x64) @ g3; per-(b,s) max/min over
//    n=32 (lanes) + channel stats — all reductions via DPP (no ds ops).
// ============================================================================
__global__ __launch_bounds__(256, 2) void layer3_kernel(const unsigned short* __restrict__ h2,
    const float* __restrict__ ab2, const float* __restrict__ W3,
    float* __restrict__ hmax, float* __restrict__ hmin, float* __restrict__ sums3)
{
    __shared__ float ls[128], lq[128];
    const int tid = threadIdx.x;
    if (tid < 128) { ls[tid] = 0.f; lq[tid] = 0.f; }
    __syncthreads();
    const int col = blockIdx.x * 256 + tid;
    const int q = col >> 5;            // group (b*2048+s); lanes 0-31 / 32-63
    const uint4* src = (const uint4*)(h2 + (size_t)col * 64);
    v2f g[32];
    float* gf = (float*)g;
#pragma unroll
    for (int k = 0; k < 8; ++k) {
        uint4 v = src[k];
        gf[8*k+0] = bf2f(v.x & 0xffffu); gf[8*k+1] = bf2f(v.x >> 16);
        gf[8*k+2] = bf2f(v.y & 0xffffu); gf[8*k+3] = bf2f(v.y >> 16);
        gf[8*k+4] = bf2f(v.z & 0xffffu); gf[8*k+5] = bf2f(v.z >> 16);
        gf[8*k+6] = bf2f(v.w & 0xffffu); gf[8*k+7] = bf2f(v.w >> 16);
    }
    const v2f* a2 = (const v2f*)ab2;
    const v2f* b2 = (const v2f*)(ab2 + 64);
#pragma unroll
    for (int k = 0; k < 32; ++k)
        g[k] = relu2(a2[k] * g[k] + b2[k]);
    const bool leader = ((tid & 31) == 31);
#pragma unroll 2
    for (int o = 0; o < 128; ++o) {
        const float* w = W3 + (o << 6);
        v2f acc; acc.x = 0.f; acc.y = 0.f;
#pragma unroll
        for (int k = 0; k < 32; ++k) {
            v2f wv; wv.x = w[2*k]; wv.y = w[2*k+1];
            acc = wv * g[k] + acc;
        }
        float hv = acc.x + acc.y;
        float sm = hv, sq = hv*hv, mx = hv, mn = hv;
        sm = dpp_add_f32<0x111>(sm); sq = dpp_add_f32<0x111>(sq);
        mx = dpp_max_f32<0x111>(mx); mn = dpp_min_f32<0x111>(mn);
        sm = dpp_add_f32<0x112>(sm); sq = dpp_add_f32<0x112>(sq);
        mx = dpp_max_f32<0x112>(mx); mn = dpp_min_f32<0x112>(mn);
        sm = dpp_add_f32<0x114>(sm); sq = dpp_add_f32<0x114>(sq);
        mx = dpp_max_f32<0x114>(mx); mn = dpp_min_f32<0x114>(mn);
        sm = dpp_add_f32<0x118>(sm); sq = dpp_add_f32<0x118>(sq);
        mx = dpp_max_f32<0x118>(mx); mn = dpp_min_f32<0x118>(mn);
        sm = dpp_add_f32<0x142>(sm); sq = dpp_add_f32<0x142>(sq);
        mx = dpp_max_f32<0x142>(mx); mn = dpp_min_f32<0x142>(mn);
        if (leader) {
            hmax[(size_t)o * 16384 + q] = mx;
            hmin[(size_t)o * 16384 + q] = mn;
            atomicAdd(&ls[o], sm);
            atomicAdd(&lq[o], sq);
        }
    }
    __syncthreads();
    if (tid < 128) {
        atomicAdd(&sums3[tid*2+0], ls[tid]);
        atomicAdd(&sums3[tid*2+1], lq[tid]);
    }
}

// ============================================================================
// 9) Final: feats[b,o,s] = relu(a3*(a3>=0 ? max : min) + c3)
// ============================================================================
__global__ __launch_bounds__(256) void final_kernel(const float* __restrict__ hmax,
    const float* __restrict__ hmin, const float* __restrict__ ab3,
    float* __restrict__ out)
{
    const int t = blockIdx.x * 256 + threadIdx.x;   // (b,o,s), s fastest
    const int s = t & 2047;
    const int o = (t >> 11) & 127;
    const int b = t >> 18;
    const int q = (b << 11) + s;
    float a = ab3[o], c = ab3[128 + o];
    float h = (a >= 0.f) ? hmax[(size_t)o * 16384 + q] : hmin[(size_t)o * 16384 + q];
    out[t] = fmaxf(fmaf(a, h, c), 0.f);
}

// ============================================================================
extern "C" void kernel_launch(void* const* d_in, const int* in_sizes, int n_in,
                              void* d_out, int out_size, void* d_ws, size_t ws_size,
                              hipStream_t stream) {
    (void)in_sizes; (void)n_in; (void)out_size; (void)ws_size;
    const float* xyz      = (const float*)d_in[0];
    const float* features = (const float*)d_in[1];
    const float* W1 = (const float*)d_in[2];
    const float* g1 = (const float*)d_in[3];
    const float* b1 = (const float*)d_in[4];
    const float* W2 = (const float*)d_in[5];
    const float* g2 = (const float*)d_in[6];
    const float* b2 = (const float*)d_in[7];
    const float* W3 = (const float*)d_in[8];
    const float* g3 = (const float*)d_in[9];
    const float* b3 = (const float*)d_in[10];

    char* ws = (char*)d_ws;
    float*          new_xyz = (float*)(ws + 0);                  // 196608 B
    int*            idx     = (int*)(ws + 196608);               // 2097152 B
    float*          ft      = (float*)(ws + 2293760);            // 16777216 B
    unsigned short* h1      = (unsigned short*)(ws + 19070976);  // 67108864 B
    unsigned short* h2      = (unsigned short*)(ws + 86179840);  // 67108864 B
    float*          hmax    = (float*)(ws + 153288704);          // 8388608 B
    float*          hmin    = (float*)(ws + 161677312);          // 8388608 B
    float*          sums    = (float*)(ws + 170065920);          // 2048 B (zeroed)
    float*          ab      = (float*)(ws + 170067968);          // 2048 B
    float* sums1 = sums;        float* ab1 = ab;
    float* sums2 = sums + 128;  float* ab2 = ab + 128;
    float* sums3 = sums + 256;  float* ab3 = ab + 256;

    // sorted point array (float4 x,y,z,idx) lives in h1's space: h1 is only
    // written by layer1 AFTER fps completes (stream order), so no conflict.
    float4* sorted = (float4*)h1;                 // NB*NN*16 = 1 MB

    float* out_newxyz = (float*)d_out;            // B*NS*3 = 49152 floats
    float* out_feats  = (float*)d_out + 49152;    // B*128*NS floats

    hipMemsetAsync(sums, 0, 2048, stream);

    sort_kernel<<<NB, 1024, 0, stream>>>(xyz, sorted);
    fps_kernel<<<NB, 1024, 0, stream>>>(xyz, sorted, new_xyz, out_newxyz);
    transpose_kernel<<<dim3(NN/64, NB), 256, 0, stream>>>(features, ft);
    ballquery_kernel<<<(NB*NS)/4, 256, 0, stream>>>(xyz, new_xyz, idx);
    layer1_kernel<<<NCOL/256, 256, 0, stream>>>(xyz, new_xyz, idx, ft, W1, h1);
    stats_kernel<<<1024, 256, 0, stream>>>(h1, sums1);
    finalize_kernel<<<1, 128, 0, stream>>>(sums1, g1, b1, ab1, 64);
    layer2_kernel<<<NCOL/256, 256, 0, stream>>>(h1, ab1, W2, h2);
    stats_kernel<<<1024, 256, 0, stream>>>(h2, sums2);
    finalize_kernel<<<1, 128, 0, stream>>>(sums2, g2, b2, ab2, 64);
    layer3_kernel<<<NCOL/256, 256, 0, stream>>>(h2, ab2, W3, hmax, hmin, sums3);
    finalize_kernel<<<1, 128, 0, stream>>>(sums3, g3, b3, ab3, 128);
    final_kernel<<<(NB*128*NS)/256, 256, 0, stream>>>(hmax, hmin, ab3, out_feats);
}

// Round 10
// 2029.394 us; speedup vs baseline: 2.7884x; 1.0049x over previous
//
#include <hip/hip_runtime.h>
#include <hip/hip_bf16.h>
#include <stdint.h>

#define NB 8
#define NN 8192
#define NC 64
#define NS 2048
#define NK 32
#define NCOL (NB*NS*NK)   // 524288 columns (b,s,n)

typedef float v2f __attribute__((ext_vector_type(2)));
typedef __attribute__((ext_vector_type(8))) short bf16x8;   // 8 bf16 (4 VGPRs)
typedef __attribute__((ext_vector_type(4))) float f32x4;    // MFMA acc

// ---------- bf16 helpers (RNE) ----------
__device__ __forceinline__ unsigned short f2bf(float x) {
    union { float f; unsigned u; } c; c.f = x;
    unsigned r = c.u + 0x7fffu + ((c.u >> 16) & 1u);
    return (unsigned short)(r >> 16);
}
__device__ __forceinline__ float bf2f(unsigned v16) {
    union { float f; unsigned u; } c; c.u = v16 << 16;
    return c.f;
}

// ---------- DPP cross-lane helpers (VALU-speed, no LDS) ----------
// row_shr:n = 0x110|n, row_bcast15 = 0x142, row_bcast31 = 0x143
template<int CTRL>
__device__ __forceinline__ unsigned long long dpp_max_u64(unsigned long long key) {
    int olo = __builtin_amdgcn_update_dpp(0, (int)(unsigned)key,        CTRL, 0xf, 0xf, true);
    int ohi = __builtin_amdgcn_update_dpp(0, (int)(unsigned)(key >> 32), CTRL, 0xf, 0xf, true);
    unsigned long long ok = ((unsigned long long)(unsigned)ohi << 32) | (unsigned)olo;
    return ok > key ? ok : key;   // zero-fill loses to every real key
}
template<int CTRL>
__device__ __forceinline__ float dpp_add_f32(float x) {   // zero-fill identity
    int o = __builtin_amdgcn_update_dpp(0, __float_as_int(x), CTRL, 0xf, 0xf, true);
    return x + __int_as_float(o);
}
template<int CTRL>
__device__ __forceinline__ float dpp_max_f32(float x) {   // self identity
    int o = __builtin_amdgcn_update_dpp(__float_as_int(x), __float_as_int(x), CTRL, 0xf, 0xf, false);
    return fmaxf(x, __int_as_float(o));
}
template<int CTRL>
__device__ __forceinline__ float dpp_min_f32(float x) {   // self identity
    int o = __builtin_amdgcn_update_dpp(__float_as_int(x), __float_as_int(x), CTRL, 0xf, 0xf, false);
    return fminf(x, __int_as_float(o));
}
template<int CTRL, int RM>
__device__ __forceinline__ unsigned dpp_add_u32(unsigned x) {  // zero-fill, row-masked
    int o = __builtin_amdgcn_update_dpp(0, (int)x, CTRL, RM, 0xf, true);
    return x + (unsigned)o;
}
__device__ __forceinline__ float wave_red_min(float x) {  // full 64-lane min -> all lanes
    x = dpp_min_f32<0x111>(x); x = dpp_min_f32<0x112>(x);
    x = dpp_min_f32<0x114>(x); x = dpp_min_f32<0x118>(x);
    x = dpp_min_f32<0x142>(x); x = dpp_min_f32<0x143>(x);
    return __int_as_float(__builtin_amdgcn_readlane(__float_as_int(x), 63));
}
__device__ __forceinline__ float wave_red_max(float x) {  // full 64-lane max -> all lanes
    x = dpp_max_f32<0x111>(x); x = dpp_max_f32<0x112>(x);
    x = dpp_max_f32<0x114>(x); x = dpp_max_f32<0x118>(x);
    x = dpp_max_f32<0x142>(x); x = dpp_max_f32<0x143>(x);
    return __int_as_float(__builtin_amdgcn_readlane(__float_as_int(x), 63));
}
__device__ __forceinline__ v2f relu2(v2f v) {
    v.x = fmaxf(v.x, 0.f); v.y = fmaxf(v.y, 0.f); return v;
}

// ============================================================================
// 0) Spatial partition: counting sort on top-11 Morton bits (2048 buckets).
//    Any permutation is CORRECT (ordering only affects pruning rate); FPS
//    tie-breaking uses original indices. Proven in R2/R5-R9.
// ============================================================================
__device__ __forceinline__ unsigned expand_bits10(unsigned v) {
    v = (v * 0x00010001u) & 0xFF0000FFu;
    v = (v * 0x00000101u) & 0x0F00F00Fu;
    v = (v * 0x00000011u) & 0xC30C30C3u;
    v = (v * 0x00000005u) & 0x49249249u;
    return v;
}
__global__ __launch_bounds__(1024) void sort_kernel(const float* __restrict__ xyz,
    float4* __restrict__ sorted)
{
    __shared__ unsigned cnt[2048];     // bucket counts -> start offsets
    __shared__ unsigned codes[NN];     // bucket id per point (32 KB)
    __shared__ unsigned wsum[16];
    const int b = blockIdx.x;
    const int tid = threadIdx.x;
    const int w = tid >> 6;
    const int lane = tid & 63;
    const float* xb = xyz + (size_t)b * NN * 3;
    cnt[tid] = 0; cnt[tid + 1024] = 0;
    __syncthreads();
    for (int p = tid; p < NN; p += 1024) {
        float x = xb[3*p+0], y = xb[3*p+1], z = xb[3*p+2];
        int qx = (int)(x * 1024.f); qx = qx < 0 ? 0 : (qx > 1023 ? 1023 : qx);
        int qy = (int)(y * 1024.f); qy = qy < 0 ? 0 : (qy > 1023 ? 1023 : qy);
        int qz = (int)(z * 1024.f); qz = qz < 0 ? 0 : (qz > 1023 ? 1023 : qz);
        unsigned m = expand_bits10((unsigned)qx)
                   | (expand_bits10((unsigned)qy) << 1)
                   | (expand_bits10((unsigned)qz) << 2);
        unsigned bk = m >> 19;                 // top 11 of 30 bits
        codes[p] = bk;
        atomicAdd(&cnt[bk], 1u);
    }
    __syncthreads();
    // exclusive scan of 2048 counts: thread t owns pair (2t, 2t+1)
    unsigned c0 = cnt[2*tid], c1 = cnt[2*tid+1];
    unsigned s = c0 + c1;
    unsigned v = s;                            // wave64 inclusive scan (canonical DPP)
    v = dpp_add_u32<0x111, 0xf>(v);
    v = dpp_add_u32<0x112, 0xf>(v);
    v = dpp_add_u32<0x114, 0xf>(v);
    v = dpp_add_u32<0x118, 0xf>(v);
    v = dpp_add_u32<0x142, 0xa>(v);            // bcast15 -> rows 1,3
    v = dpp_add_u32<0x143, 0xc>(v);            // bcast31 -> rows 2,3
    if (lane == 63) wsum[w] = v;
    __syncthreads();
    unsigned wbase = 0;
#pragma unroll
    for (int j = 0; j < 15; ++j) {             // exclusive prefix of wave totals
        unsigned t = wsum[j];
        wbase += (j < w) ? t : 0u;
    }
    unsigned excl = wbase + v - s;             // global exclusive prefix for bucket 2t
    cnt[2*tid]   = excl;                       // each thread touches only its own pair
    cnt[2*tid+1] = excl + c0;
    __syncthreads();
    // scatter
    for (int p = tid; p < NN; p += 1024) {
        unsigned bk = codes[p];
        unsigned pos = atomicAdd(&cnt[bk], 1u);
        float4 o;
        o.x = xb[3*p+0]; o.y = xb[3*p+1]; o.z = xb[3*p+2];
        o.w = __int_as_float(p);
        sorted[(size_t)b * NN + pos] = o;
    }
}

// ============================================================================
// 1) FPS — R9 structure (16 waves x 512-pt chunks, bbox prune, monolithic
//    u64 DPP reduce, LDS atomicMax merge, ONE barrier/iter), with the
//    atomic path shortened: lane63 owns the cached key register and issues
//    atomicMax directly from the DPP result (no readlane/pack gating the
//    atomic); only the HIGH word is broadcast (1 readlane, for the prune
//    branch), in parallel with the atomic. Semantics identical to R9.
//    Bit-exact: same u64 key order ((dmin_bits<<32)|~orig_idx).
//    3-slot rotation safety unchanged (see R9 proof).
// ============================================================================
__global__ __launch_bounds__(1024) void fps_kernel(const float* __restrict__ xyz,
    const float4* __restrict__ sorted,
    float* __restrict__ new_xyz, float* __restrict__ out_newxyz)
{
#pragma clang fp contract(off)
    const int b = blockIdx.x;
    const int tid = threadIdx.x;
    const int w = tid >> 6;
    const int lane = tid & 63;
    __shared__ float sx[NN], sy[NN], sz[NN];             // 96 KB, indexed by ORIG idx
    __shared__ float s_hist[NS * 3];                     // 24 KB selected-coord history
    __shared__ unsigned long long s_slot[3];             // rotating merge slots
    const float4* sp = sorted + (size_t)b * NN + (size_t)w * 512 + lane;
    v2f px[4], py[4], pz[4], dmin[4];
    unsigned plo[8];                                     // ~orig_idx per point
    float bnx = 1e30f, bny = 1e30f, bnz = 1e30f;
    float bxx = -1e30f, bxy = -1e30f, bxz = -1e30f;
#pragma unroll
    for (int m = 0; m < 4; ++m) {
        float4 a = sp[128*m];                            // point k=2m
        float4 c = sp[128*m + 64];                       // point k=2m+1
        px[m].x = a.x; px[m].y = c.x;
        py[m].x = a.y; py[m].y = c.y;
        pz[m].x = a.z; pz[m].y = c.z;
        dmin[m].x = 1e10f; dmin[m].y = 1e10f;
        int ia = __float_as_int(a.w), ic = __float_as_int(c.w);
        plo[2*m]   = ~(unsigned)ia;
        plo[2*m+1] = ~(unsigned)ic;
        sx[ia] = a.x; sy[ia] = a.y; sz[ia] = a.z;        // scatter by orig idx
        sx[ic] = c.x; sy[ic] = c.y; sz[ic] = c.z;
        bnx = fminf(bnx, fminf(a.x, c.x)); bxx = fmaxf(bxx, fmaxf(a.x, c.x));
        bny = fminf(bny, fminf(a.y, c.y)); bxy = fmaxf(bxy, fmaxf(a.y, c.y));
        bnz = fminf(bnz, fminf(a.z, c.z)); bxz = fmaxf(bxz, fmaxf(a.z, c.z));
    }
    // wave bbox (uniform across the wave after readlane-broadcast)
    bnx = wave_red_min(bnx); bny = wave_red_min(bny); bnz = wave_red_min(bnz);
    bxx = wave_red_max(bxx); bxy = wave_red_max(bxy); bxz = wave_red_max(bxz);

    const float* xb = xyz + (size_t)b * NN * 3;
    float lx = xb[0], ly = xb[1], lz = xb[2];            // selection 0 = point 0
    if (tid == 0) {
        s_hist[0] = lx; s_hist[1] = ly; s_hist[2] = lz;
        s_slot[0] = 0ull; s_slot[1] = 0ull; s_slot[2] = 0ull;
    }
    float ckv = 1e30f;                                   // cached wave max dmin (forces 1st compute)
    unsigned long long kc = 0ull;                        // cached key (valid at lane 63)
    __syncthreads();                                     // sx/sy/sz + slots + hist[0] visible

    int cur = 1, nxt = 2;                                // cur = i%3, nxt = (i+1)%3 at i=1
    for (int i = 1; i < NS; ++i) {
        if (tid == 0) s_slot[nxt] = 0ull;                // reset future slot (safe window)
        // certified fp32 lower bound of d_new for every point in this chunk
        float cdx = fmaxf(fmaxf(bnx - lx, lx - bxx), 0.f);
        float cdy = fmaxf(fmaxf(bny - ly, ly - bxy), 0.f);
        float cdz = fmaxf(fmaxf(bnz - lz, lz - bxz), 0.f);
        float lb = (cdx*cdx + cdy*cdy) + cdz*cdz;
        if (!(lb >= ckv)) {                              // wave-uniform branch
            v2f l2x; l2x.x = lx; l2x.y = lx;
            v2f l2y; l2y.x = ly; l2y.y = ly;
            v2f l2z; l2z.x = lz; l2z.y = lz;
            unsigned long long best = 0ull;
#pragma unroll
            for (int m = 0; m < 4; ++m) {
                v2f dx = px[m] - l2x;
                v2f dy = py[m] - l2y;
                v2f dz = pz[m] - l2z;
                v2f d = (dx*dx + dy*dy) + dz*dz;         // pk mul/add, exact order
                v2f dm;
                dm.x = fminf(dmin[m].x, d.x);
                dm.y = fminf(dmin[m].y, d.y);
                dmin[m] = dm;
                unsigned long long k0 =
                    ((unsigned long long)__float_as_uint(dm.x) << 32) | plo[2*m];
                unsigned long long k1 =
                    ((unsigned long long)__float_as_uint(dm.y) << 32) | plo[2*m+1];
                if (k0 > best) best = k0;
                if (k1 > best) best = k1;
            }
            // MONOLITHIC DPP wave64 max-reduce -> lane 63
            best = dpp_max_u64<0x111>(best);
            best = dpp_max_u64<0x112>(best);
            best = dpp_max_u64<0x114>(best);
            best = dpp_max_u64<0x118>(best);
            best = dpp_max_u64<0x142>(best);
            best = dpp_max_u64<0x143>(best);
            kc = best;                                   // lane63 holds the wave key
            // broadcast ONLY the value word for the prune branch (off atomic path)
            ckv = __uint_as_float((unsigned)__builtin_amdgcn_readlane((int)(best >> 32), 63));
        }
        if (lane == 63)
            atomicMax(&s_slot[cur], kc);                 // straight from DPP result
        __syncthreads();                                 // the ONLY barrier per iter
        const unsigned long long k = s_slot[cur];        // b64 broadcast read
        const int ix = ~(int)(unsigned)(k & 0xffffffffull);  // original point index
        lx = sx[ix]; ly = sy[ix]; lz = sz[ix];           // LDS broadcast gather
        if (tid == 0) {
            s_hist[3*i+0] = lx; s_hist[3*i+1] = ly; s_hist[3*i+2] = lz;
        }
        cur = nxt;                                       // rotate slot indices
        nxt = nxt + 1; if (nxt == 3) nxt = 0;
    }
    __syncthreads();                                     // last hist write visible
    // coalesced flush of the selected-coordinate history
    float* nw = new_xyz + (size_t)b * NS * 3;
    float* ow = out_newxyz + (size_t)b * NS * 3;
    for (int t = tid; t < NS * 3; t += 1024) {
        float v = s_hist[t];
        nw[t] = v; ow[t] = v;
    }
}

// ============================================================================
// 2) Transpose features (B,C,N) -> (B,N,C) for contiguous per-point gathers.
// ============================================================================
__global__ __launch_bounds__(256) void transpose_kernel(const float* __restrict__ f,
    float* __restrict__ ft)
{
    __shared__ float tile[64][65];
    int b = blockIdx.y;
    int p0 = blockIdx.x * 64;
    for (int k = threadIdx.x; k < 64*64; k += 256) {
        int c = k >> 6, p = k & 63;
        tile[c][p] = f[((size_t)b * NC + c) * NN + p0 + p];
    }
    __syncthreads();
    for (int k = threadIdx.x; k < 64*64; k += 256) {
        int p = k >> 6, c = k & 63;
        ft[((size_t)b * NN + p0 + p) * NC + c] = tile[c][p];
    }
}

// ============================================================================
// 3) Ball query: one wave per (b,s) query. First 32 smallest in-ball indices,
//    pad with first. r2 must be float(0.2*0.2) = 0.0399999991 (not 0.2f*0.2f).
// ============================================================================
__global__ __launch_bounds__(256) void ballquery_kernel(const float* __restrict__ xyz,
    const float* __restrict__ new_xyz, int* __restrict__ idx)
{
#pragma clang fp contract(off)
    const int q = blockIdx.x * 4 + (threadIdx.x >> 6);
    const int lane = threadIdx.x & 63;
    const int b = q >> 11;
    const float r2 = (float)(0.2 * 0.2);
    const float* xb = xyz + (size_t)b * NN * 3;
    const float* nx = new_xyz + (size_t)q * 3;
    float qx = nx[0], qy = nx[1], qz = nx[2];
    int cnt = 0, first = -1;
    int* out = idx + (size_t)q * NK;
    for (int base = 0; base < NN; base += 64) {
        int p = base + lane;
        float x = xb[p*3+0], y = xb[p*3+1], z = xb[p*3+2];
        float dx = qx - x, dy = qy - y, dz = qz - z;
        float d2 = (dx*dx + dy*dy) + dz*dz;
        bool in = d2 < r2;
        unsigned long long m = __ballot(in);
        if (m) {
            if (first < 0) first = base + __builtin_ctzll(m);
            if (in) {
                int rank = cnt + __popcll(m & ((1ull << lane) - 1ull));
                if (rank < NK) out[rank] = p;
            }
            cnt += __popcll(m);
            if (cnt >= NK) break;
        }
    }
    for (int k = cnt + lane; k < NK; k += 64) out[k] = first;  // cnt>=1 always
}

// ============================================================================
// 4) Layer 1: h1 = W1(64x67) @ g. v2f packed FMAs; h computed in two halves
//    of 32 outputs to keep VGPR below spill point. h1 bf16.
// ============================================================================
__global__ __launch_bounds__(256, 2) void layer1_kernel(const float* __restrict__ xyz,
    const float* __restrict__ new_xyz, const int* __restrict__ idx,
    const float* __restrict__ ft, const float* __restrict__ W1,
    unsigned short* __restrict__ h1)
{
    const int col = blockIdx.x * 256 + threadIdx.x;
    const int b = col >> 16;
    const int s = (col >> 5) & 2047;
    const int p = idx[col];
    v2f g[34];
    float* gf = (float*)g;
    {
        const float* nx = new_xyz + ((size_t)(b * NS + s)) * 3;
        const float* xp = xyz + ((size_t)(b * NN + p)) * 3;
        gf[0] = xp[0] - nx[0]; gf[1] = xp[1] - nx[1]; gf[2] = xp[2] - nx[2];
    }
    const float4* fp = (const float4*)(ft + ((size_t)(b * NN + p)) * NC);
#pragma unroll
    for (int c4 = 0; c4 < 16; ++c4) {
        float4 v = fp[c4];
        gf[3 + 4*c4 + 0] = v.x; gf[3 + 4*c4 + 1] = v.y;
        gf[3 + 4*c4 + 2] = v.z; gf[3 + 4*c4 + 3] = v.w;
    }
    gf[67] = 0.f;
    uint4* dst = (uint4*)(h1 + (size_t)col * 64);
#pragma unroll
    for (int half = 0; half < 2; ++half) {
        float h[32];
#pragma unroll 4
        for (int o16 = 0; o16 < 32; ++o16) {
            const float* w = W1 + (half*32 + o16) * 67;
            v2f acc; acc.x = 0.f; acc.y = 0.f;
#pragma unroll
            for (int k = 0; k < 33; ++k) {
                v2f wv; wv.x = w[2*k]; wv.y = w[2*k+1];
                acc = wv * g[k] + acc;                    // v_pk_fma_f32
            }
            h[o16] = fmaf(w[66], gf[66], acc.x + acc.y);
        }
#pragma unroll
        for (int k = 0; k < 4; ++k) {
            uint4 v;
            v.x = (unsigned)f2bf(h[8*k+0]) | ((unsigned)f2bf(h[8*k+1]) << 16);
            v.y = (unsigned)f2bf(h[8*k+2]) | ((unsigned)f2bf(h[8*k+3]) << 16);
            v.z = (unsigned)f2bf(h[8*k+4]) | ((unsigned)f2bf(h[8*k+5]) << 16);
            v.w = (unsigned)f2bf(h[8*k+6]) | ((unsigned)f2bf(h[8*k+7]) << 16);
            dst[half*4 + k] = v;
        }
    }
}

// ============================================================================
// 5) Stats pass over a bf16 [col][64] tensor: per-channel sum / sumsq.
// ============================================================================
__global__ __launch_bounds__(256) void stats_kernel(const unsigned short* __restrict__ h,
    float* __restrict__ sums)
{
    __shared__ float ls[64], lq[64];
    const int tid = threadIdx.x;
    if (tid < 64) { ls[tid] = 0.f; lq[tid] = 0.f; }
    __syncthreads();
    float s[8] = {0,0,0,0,0,0,0,0}, q[8] = {0,0,0,0,0,0,0,0};
    const int gt = blockIdx.x * 256 + tid;
    const int G = gridDim.x * 256;            // multiple of 8 -> channel phase fixed
    const uint4* src = (const uint4*)h;
    const int nvec = NCOL * 8;                 // uint4s (8 bf16 each)
    for (int i = gt; i < nvec; i += G) {
        uint4 v = src[i];
        float f0 = bf2f(v.x & 0xffffu), f1 = bf2f(v.x >> 16);
        float f2 = bf2f(v.y & 0xffffu), f3 = bf2f(v.y >> 16);
        float f4 = bf2f(v.z & 0xffffu), f5 = bf2f(v.z >> 16);
        float f6 = bf2f(v.w & 0xffffu), f7 = bf2f(v.w >> 16);
        s[0] += f0; q[0] = fmaf(f0, f0, q[0]);
        s[1] += f1; q[1] = fmaf(f1, f1, q[1]);
        s[2] += f2; q[2] = fmaf(f2, f2, q[2]);
        s[3] += f3; q[3] = fmaf(f3, f3, q[3]);
        s[4] += f4; q[4] = fmaf(f4, f4, q[4]);
        s[5] += f5; q[5] = fmaf(f5, f5, q[5]);
        s[6] += f6; q[6] = fmaf(f6, f6, q[6]);
        s[7] += f7; q[7] = fmaf(f7, f7, q[7]);
    }
    const int obase = (tid & 7) * 8;
#pragma unroll
    for (int j = 0; j < 8; ++j) {
        atomicAdd(&ls[obase + j], s[j]);
        atomicAdd(&lq[obase + j], q[j]);
    }
    __syncthreads();
    if (tid < 64) {
        atomicAdd(&sums[tid*2+0], ls[tid]);
        atomicAdd(&sums[tid*2+1], lq[tid]);
    }
}

// ============================================================================
// 6) Finalize BN params. Layout: ab[c] = a_c (scale), ab[nch+c] = b_c (shift)
//    so the apply step can use packed v2f math.
// ============================================================================
__global__ void finalize_kernel(const float* __restrict__ sums,
    const float* __restrict__ gamma, const float* __restrict__ beta,
    float* __restrict__ ab, int nch)
{
    int c = threadIdx.x;
    if (c < nch) {
        const float invM = 1.0f / 524288.0f;
        float mu = sums[c*2] * invM;
        float var = sums[c*2+1] * invM - mu * mu;
        float a = gamma[c] / sqrtf(var + 1e-5f);
        ab[c] = a;
        ab[nch + c] = fmaf(-mu, a, beta[c]);
    }
}

// ============================================================================
// 7) Layer 2: g2 = relu(BN1(h1)); h2 = W2(64x64) @ g2. Packed FMAs, halves.
// ============================================================================
__global__ __launch_bounds__(256, 2) void layer2_kernel(const unsigned short* __restrict__ h1,
    const float* __restrict__ ab1, const float* __restrict__ W2,
    unsigned short* __restrict__ h2)
{
    const int col = blockIdx.x * 256 + threadIdx.x;
    const uint4* src = (const uint4*)(h1 + (size_t)col * 64);
    v2f g[32];
    float* gf = (float*)g;
#pragma unroll
    for (int k = 0; k < 8; ++k) {
        uint4 v = src[k];
        gf[8*k+0] = bf2f(v.x & 0xffffu); gf[8*k+1] = bf2f(v.x >> 16);
        gf[8*k+2] = bf2f(v.y & 0xffffu); gf[8*k+3] = bf2f(v.y >> 16);
        gf[8*k+4] = bf2f(v.z & 0xffffu); gf[8*k+5] = bf2f(v.z >> 16);
        gf[8*k+6] = bf2f(v.w & 0xffffu); gf[8*k+7] = bf2f(v.w >> 16);
    }
    const v2f* a2 = (const v2f*)ab1;
    const v2f* b2 = (const v2f*)(ab1 + 64);
#pragma unroll
    for (int k = 0; k < 32; ++k)
        g[k] = relu2(a2[k] * g[k] + b2[k]);               // pk_fma + pk_max
    uint4* dst = (uint4*)(h2 + (size_t)col * 64);
#pragma unroll
    for (int half = 0; half < 2; ++half) {
        float h[32];
#pragma unroll 4
        for (int o16 = 0; o16 < 32; ++o16) {
            const float* w = W2 + ((half*32 + o16) << 6);
            v2f acc; acc.x = 0.f; acc.y = 0.f;
#pragma unroll
            for (int k = 0; k < 32; ++k) {
                v2f wv; wv.x = w[2*k]; wv.y = w[2*k+1];
                acc = wv * g[k] + acc;
            }
            h[o16] = acc.x + acc.y;
        }
#pragma unroll
        for (int k = 0; k < 4; ++k) {
            uint4 v;
            v.x = (unsigned)f2bf(h[8*k+0]) | ((unsigned)f2bf(h[8*k+1]) << 16);
            v.y = (unsigned)f2bf(h[8*k+2]) | ((unsigned)f2bf(h[8*k+3]) << 16);
            v.z = (unsigned)f2bf(h[8*k+4]) | ((unsigned)f2bf(h[8*k+5]) << 16);
            v.w = (unsigned)f2bf(h[8*k+6]) | ((unsigned)f2bf(h[8*k+7]) << 16);
            dst[half*4 + k] = v;
        }
    }
}

// ============================================================================
// 8) Layer 3 via MFMA (bf16 in, f32 acc): h3 = W3(128x64) @ relu(BN2(h2)).
//    Tiles: D[16 out][16 col] via mfma_f32_16x16x32_bf16, K=64 in 2 steps.
//    Fragment layouts (m89-verified D; A/B per AMD lab-notes convention):
//      A[m][k]: m = lane&15, k = (lane>>4)*8 + j   (8 bf16 / lane)
//      B[k][n]: n = lane&15, k = (lane>>4)*8 + j
//      D[m][n]: n = lane&15, m = (lane>>4)*4 + reg (4 f32 / lane)
//    One wave owns one (b,s)-group (32 cols = 2 tiles, held simultaneously
//    so group max/min combine in-register -> hmax/hmin layout unchanged).
//    B built per-lane from ONE uint4 load of h2 (8 contiguous bf16 at
//    k = kh*32 + rg*8) + BN(ab2)+relu + f2bf. A (W3) converted on the fly
//    (32 KB, L1/L2-hot). Channel sums: per-lane f32 accumulators
//    [rt][reg] over its cols, 4-stage row-local DPP add at the end ->
//    lane15 of each 16-lane row -> LDS atomics -> global (proven pattern).
//    grid 2048 x 256 (4 waves/block, 8192 waves, 2 groups/wave = 16384).
// ============================================================================
__global__ __launch_bounds__(256, 2) void layer3_kernel(const unsigned short* __restrict__ h2,
    const float* __restrict__ ab2, const float* __restrict__ W3,
    float* __restrict__ hmax, float* __restrict__ hmin, float* __restrict__ sums3)
{
    __shared__ float ls[128], lq[128];
    const int tid = threadIdx.x;
    if (tid < 128) { ls[tid] = 0.f; lq[tid] = 0.f; }
    __syncthreads();
    const int lane = tid & 63;
    const int col0 = lane & 15;                          // n (col in tile) / m (row of A)
    const int rg   = lane >> 4;                          // k-group (input frags), row-group (D)
    const int wglob = blockIdx.x * 4 + (tid >> 6);       // 0..8191

    float sums[32], sqs[32];                             // [rt][reg]
#pragma unroll
    for (int t = 0; t < 32; ++t) { sums[t] = 0.f; sqs[t] = 0.f; }

    for (int g = wglob * 2; g < wglob * 2 + 2; ++g) {    // 2 (b,s)-groups per wave
        // ---- build B fragments for both 16-col tiles of this group ----
        bf16x8 Bf[2][2];                                 // [tile][kh]
#pragma unroll
        for (int t = 0; t < 2; ++t) {
            const int col = g * 32 + t * 16 + col0;
            const unsigned short* hp = h2 + (size_t)col * 64 + rg * 8;
#pragma unroll
            for (int kh = 0; kh < 2; ++kh) {
                uint4 hv = *(const uint4*)(hp + kh * 32);
                const float* ap = ab2 + kh * 32 + rg * 8;
                float4 a0 = *(const float4*)ap;
                float4 a1 = *(const float4*)(ap + 4);
                float4 b0 = *(const float4*)(ap + 64);
                float4 b1 = *(const float4*)(ap + 68);
                bf16x8 f;
                f[0] = (short)f2bf(fmaxf(fmaf(a0.x, bf2f(hv.x & 0xffffu), b0.x), 0.f));
                f[1] = (short)f2bf(fmaxf(fmaf(a0.y, bf2f(hv.x >> 16),     b0.y), 0.f));
                f[2] = (short)f2bf(fmaxf(fmaf(a0.z, bf2f(hv.y & 0xffffu), b0.z), 0.f));
                f[3] = (short)f2bf(fmaxf(fmaf(a0.w, bf2f(hv.y >> 16),     b0.w), 0.f));
                f[4] = (short)f2bf(fmaxf(fmaf(a1.x, bf2f(hv.z & 0xffffu), b1.x), 0.f));
                f[5] = (short)f2bf(fmaxf(fmaf(a1.y, bf2f(hv.z >> 16),     b1.y), 0.f));
                f[6] = (short)f2bf(fmaxf(fmaf(a1.z, bf2f(hv.w & 0xffffu), b1.z), 0.f));
                f[7] = (short)f2bf(fmaxf(fmaf(a1.w, bf2f(hv.w >> 16),     b1.w), 0.f));
                Bf[t][kh] = f;
            }
        }
        // ---- 8 row-tiles of 16 output channels ----
#pragma unroll
        for (int rt = 0; rt < 8; ++rt) {
            f32x4 acc0 = {0.f, 0.f, 0.f, 0.f};
            f32x4 acc1 = {0.f, 0.f, 0.f, 0.f};
#pragma unroll
            for (int kh = 0; kh < 2; ++kh) {
                const float* wp = W3 + (size_t)(rt * 16 + col0) * 64 + kh * 32 + rg * 8;
                float4 w0 = *(const float4*)wp;
                float4 w1 = *(const float4*)(wp + 4);
                bf16x8 Af;
                Af[0] = (short)f2bf(w0.x); Af[1] = (short)f2bf(w0.y);
                Af[2] = (short)f2bf(w0.z); Af[3] = (short)f2bf(w0.w);
                Af[4] = (short)f2bf(w1.x); Af[5] = (short)f2bf(w1.y);
                Af[6] = (short)f2bf(w1.z); Af[7] = (short)f2bf(w1.w);
                acc0 = __builtin_amdgcn_mfma_f32_16x16x32_bf16(Af, Bf[0][kh], acc0, 0, 0, 0);
                acc1 = __builtin_amdgcn_mfma_f32_16x16x32_bf16(Af, Bf[1][kh], acc1, 0, 0, 0);
            }
#pragma unroll
            for (int r = 0; r < 4; ++r) {
                float v0 = acc0[r], v1 = acc1[r];
                sums[rt*4 + r] += v0 + v1;
                sqs[rt*4 + r]  = fmaf(v0, v0, fmaf(v1, v1, sqs[rt*4 + r]));
                float mx = fmaxf(v0, v1);
                float mn = fminf(v0, v1);
                mx = dpp_max_f32<0x111>(mx); mn = dpp_min_f32<0x111>(mn);
                mx = dpp_max_f32<0x112>(mx); mn = dpp_min_f32<0x112>(mn);
                mx = dpp_max_f32<0x114>(mx); mn = dpp_min_f32<0x114>(mn);
                mx = dpp_max_f32<0x118>(mx); mn = dpp_min_f32<0x118>(mn);
                if (col0 == 15) {                        // lane15 of each 16-lane row
                    const int o = rt * 16 + rg * 4 + r;
                    hmax[(size_t)o * 16384 + g] = mx;
                    hmin[(size_t)o * 16384 + g] = mn;
                }
            }
        }
    }
    // ---- channel sums: reduce over cols (16-lane rows), then LDS -> global
#pragma unroll
    for (int t = 0; t < 32; ++t) {
        float sm = sums[t], sq = sqs[t];
        sm = dpp_add_f32<0x111>(sm); sq = dpp_add_f32<0x111>(sq);
        sm = dpp_add_f32<0x112>(sm); sq = dpp_add_f32<0x112>(sq);
        sm = dpp_add_f32<0x114>(sm); sq = dpp_add_f32<0x114>(sq);
        sm = dpp_add_f32<0x118>(sm); sq = dpp_add_f32<0x118>(sq);
        if (col0 == 15) {
            const int o = (t >> 2) * 16 + rg * 4 + (t & 3);
            atomicAdd(&ls[o], sm);
            atomicAdd(&lq[o], sq);
        }
    }
    __syncthreads();
    if (tid < 128) {
        atomicAdd(&sums3[tid*2+0], ls[tid]);
        atomicAdd(&sums3[tid*2+1], lq[tid]);
    }
}

// ============================================================================
// 9) Final: feats[b,o,s] = relu(a3*(a3>=0 ? max : min) + c3)
// ============================================================================
__global__ __launch_bounds__(256) void final_kernel(const float* __restrict__ hmax,
    const float* __restrict__ hmin, const float* __restrict__ ab3,
    float* __restrict__ out)
{
    const int t = blockIdx.x * 256 + threadIdx.x;   // (b,o,s), s fastest
    const int s = t & 2047;
    const int o = (t >> 11) & 127;
    const int b = t >> 18;
    const int q = (b << 11) + s;
    float a = ab3[o], c = ab3[128 + o];
    float h = (a >= 0.f) ? hmax[(size_t)o * 16384 + q] : hmin[(size_t)o * 16384 + q];
    out[t] = fmaxf(fmaf(a, h, c), 0.f);
}

// ============================================================================
extern "C" void kernel_launch(void* const* d_in, const int* in_sizes, int n_in,
                              void* d_out, int out_size, void* d_ws, size_t ws_size,
                              hipStream_t stream) {
    (void)in_sizes; (void)n_in; (void)out_size; (void)ws_size;
    const float* xyz      = (const float*)d_in[0];
    const float* features = (const float*)d_in[1];
    const float* W1 = (const float*)d_in[2];
    const float* g1 = (const float*)d_in[3];
    const float* b1 = (const float*)d_in[4];
    const float* W2 = (const float*)d_in[5];
    const float* g2 = (const float*)d_in[6];
    const float* b2 = (const float*)d_in[7];
    const float* W3 = (const float*)d_in[8];
    const float* g3 = (const float*)d_in[9];
    const float* b3 = (const float*)d_in[10];

    char* ws = (char*)d_ws;
    float*          new_xyz = (float*)(ws + 0);                  // 196608 B
    int*            idx     = (int*)(ws + 196608);               // 2097152 B
    float*          ft      = (float*)(ws + 2293760);            // 16777216 B
    unsigned short* h1      = (unsigned short*)(ws + 19070976);  // 67108864 B
    unsigned short* h2      = (unsigned short*)(ws + 86179840);  // 67108864 B
    float*          hmax    = (float*)(ws + 153288704);          // 8388608 B
    float*          hmin    = (float*)(ws + 161677312);          // 8388608 B
    float*          sums    = (float*)(ws + 170065920);          // 2048 B (zeroed)
    float*          ab      = (float*)(ws + 170067968);          // 2048 B
    float* sums1 = sums;        float* ab1 = ab;
    float* sums2 = sums + 128;  float* ab2 = ab + 128;
    float* sums3 = sums + 256;  float* ab3 = ab + 256;

    // sorted point array (float4 x,y,z,idx) lives in h1's space: h1 is only
    // written by layer1 AFTER fps completes (stream order), so no conflict.
    float4* sorted = (float4*)h1;                 // NB*NN*16 = 1 MB

    float* out_newxyz = (float*)d_out;            // B*NS*3 = 49152 floats
    float* out_feats  = (float*)d_out + 49152;    // B*128*NS floats

    hipMemsetAsync(sums, 0, 2048, stream);

    sort_kernel<<<NB, 1024, 0, stream>>>(xyz, sorted);
    fps_kernel<<<NB, 1024, 0, stream>>>(xyz, sorted, new_xyz, out_newxyz);
    transpose_kernel<<<dim3(NN/64, NB), 256, 0, stream>>>(features, ft);
    ballquery_kernel<<<(NB*NS)/4, 256, 0, stream>>>(xyz, new_xyz, idx);
    layer1_kernel<<<NCOL/256, 256, 0, stream>>>(xyz, new_xyz, idx, ft, W1, h1);
    stats_kernel<<<1024, 256, 0, stream>>>(h1, sums1);
    finalize_kernel<<<1, 128, 0, stream>>>(sums1, g1, b1, ab1, 64);
    layer2_kernel<<<NCOL/256, 256, 0, stream>>>(h1, ab1, W2, h2);
    stats_kernel<<<1024, 256, 0, stream>>>(h2, sums2);
    finalize_kernel<<<1, 128, 0, stream>>>(sums2, g2, b2, ab2, 64);
    layer3_kernel<<<NCOL/256, 256, 0, stream>>>(h2, ab2, W3, hmax, hmin, sums3);
    finalize_kernel<<<1, 128, 0, stream>>>(sums3, g3, b3, ab3, 128);
    final_kernel<<<(NB*128*NS)/256, 256, 0, stream>>>(hmax, hmin, ab3, out_feats);
}

// Round 11
// 1887.718 us; speedup vs baseline: 2.9977x; 1.0751x over previous
//
#include <hip/hip_runtime.h>
#include <hip/hip_bf16.h>
#include <stdint.h>

#define NB 8
#define NN 8192
#define NC 64
#define NS 2048
#define NK 32
#define NCOL (NB*NS*NK)   // 524288 columns (b,s,n)

typedef float v2f __attribute__((ext_vector_type(2)));
typedef __attribute__((ext_vector_type(8))) short bf16x8;   // 8 bf16 (4 VGPRs)
typedef __attribute__((ext_vector_type(4))) float f32x4;    // MFMA acc

// ---------- bf16 helpers (RNE) ----------
__device__ __forceinline__ unsigned short f2bf(float x) {
    union { float f; unsigned u; } c; c.f = x;
    unsigned r = c.u + 0x7fffu + ((c.u >> 16) & 1u);
    return (unsigned short)(r >> 16);
}
__device__ __forceinline__ float bf2f(unsigned v16) {
    union { float f; unsigned u; } c; c.u = v16 << 16;
    return c.f;
}

// ---------- DPP cross-lane helpers (VALU-speed, no LDS) ----------
// row_shr:n = 0x110|n, row_bcast15 = 0x142, row_bcast31 = 0x143
template<int CTRL>
__device__ __forceinline__ unsigned long long dpp_max_u64(unsigned long long key) {
    int olo = __builtin_amdgcn_update_dpp(0, (int)(unsigned)key,        CTRL, 0xf, 0xf, true);
    int ohi = __builtin_amdgcn_update_dpp(0, (int)(unsigned)(key >> 32), CTRL, 0xf, 0xf, true);
    unsigned long long ok = ((unsigned long long)(unsigned)ohi << 32) | (unsigned)olo;
    return ok > key ? ok : key;   // zero-fill loses to every real key
}
template<int CTRL>
__device__ __forceinline__ float dpp_add_f32(float x) {   // zero-fill identity
    int o = __builtin_amdgcn_update_dpp(0, __float_as_int(x), CTRL, 0xf, 0xf, true);
    return x + __int_as_float(o);
}
template<int CTRL>
__device__ __forceinline__ float dpp_max_f32(float x) {   // self identity
    int o = __builtin_amdgcn_update_dpp(__float_as_int(x), __float_as_int(x), CTRL, 0xf, 0xf, false);
    return fmaxf(x, __int_as_float(o));
}
template<int CTRL>
__device__ __forceinline__ float dpp_min_f32(float x) {   // self identity
    int o = __builtin_amdgcn_update_dpp(__float_as_int(x), __float_as_int(x), CTRL, 0xf, 0xf, false);
    return fminf(x, __int_as_float(o));
}
template<int CTRL, int RM>
__device__ __forceinline__ unsigned dpp_add_u32(unsigned x) {  // zero-fill, row-masked
    int o = __builtin_amdgcn_update_dpp(0, (int)x, CTRL, RM, 0xf, true);
    return x + (unsigned)o;
}
__device__ __forceinline__ float wave_red_min(float x) {  // full 64-lane min -> all lanes
    x = dpp_min_f32<0x111>(x); x = dpp_min_f32<0x112>(x);
    x = dpp_min_f32<0x114>(x); x = dpp_min_f32<0x118>(x);
    x = dpp_min_f32<0x142>(x); x = dpp_min_f32<0x143>(x);
    return __int_as_float(__builtin_amdgcn_readlane(__float_as_int(x), 63));
}
__device__ __forceinline__ float wave_red_max(float x) {  // full 64-lane max -> all lanes
    x = dpp_max_f32<0x111>(x); x = dpp_max_f32<0x112>(x);
    x = dpp_max_f32<0x114>(x); x = dpp_max_f32<0x118>(x);
    x = dpp_max_f32<0x142>(x); x = dpp_max_f32<0x143>(x);
    return __int_as_float(__builtin_amdgcn_readlane(__float_as_int(x), 63));
}
__device__ __forceinline__ v2f relu2(v2f v) {
    v.x = fmaxf(v.x, 0.f); v.y = fmaxf(v.y, 0.f); return v;
}

// ============================================================================
// 0) Spatial partition: counting sort on top-11 Morton bits (2048 buckets).
//    Any permutation is CORRECT (ordering only affects pruning rate); FPS
//    tie-breaking uses original indices. Proven in R2/R5-R10.
// ============================================================================
__device__ __forceinline__ unsigned expand_bits10(unsigned v) {
    v = (v * 0x00010001u) & 0xFF0000FFu;
    v = (v * 0x00000101u) & 0x0F00F00Fu;
    v = (v * 0x00000011u) & 0xC30C30C3u;
    v = (v * 0x00000005u) & 0x49249249u;
    return v;
}
__global__ __launch_bounds__(1024) void sort_kernel(const float* __restrict__ xyz,
    float4* __restrict__ sorted)
{
    __shared__ unsigned cnt[2048];     // bucket counts -> start offsets
    __shared__ unsigned codes[NN];     // bucket id per point (32 KB)
    __shared__ unsigned wsum[16];
    const int b = blockIdx.x;
    const int tid = threadIdx.x;
    const int w = tid >> 6;
    const int lane = tid & 63;
    const float* xb = xyz + (size_t)b * NN * 3;
    cnt[tid] = 0; cnt[tid + 1024] = 0;
    __syncthreads();
    for (int p = tid; p < NN; p += 1024) {
        float x = xb[3*p+0], y = xb[3*p+1], z = xb[3*p+2];
        int qx = (int)(x * 1024.f); qx = qx < 0 ? 0 : (qx > 1023 ? 1023 : qx);
        int qy = (int)(y * 1024.f); qy = qy < 0 ? 0 : (qy > 1023 ? 1023 : qy);
        int qz = (int)(z * 1024.f); qz = qz < 0 ? 0 : (qz > 1023 ? 1023 : qz);
        unsigned m = expand_bits10((unsigned)qx)
                   | (expand_bits10((unsigned)qy) << 1)
                   | (expand_bits10((unsigned)qz) << 2);
        unsigned bk = m >> 19;                 // top 11 of 30 bits
        codes[p] = bk;
        atomicAdd(&cnt[bk], 1u);
    }
    __syncthreads();
    // exclusive scan of 2048 counts: thread t owns pair (2t, 2t+1)
    unsigned c0 = cnt[2*tid], c1 = cnt[2*tid+1];
    unsigned s = c0 + c1;
    unsigned v = s;                            // wave64 inclusive scan (canonical DPP)
    v = dpp_add_u32<0x111, 0xf>(v);
    v = dpp_add_u32<0x112, 0xf>(v);
    v = dpp_add_u32<0x114, 0xf>(v);
    v = dpp_add_u32<0x118, 0xf>(v);
    v = dpp_add_u32<0x142, 0xa>(v);            // bcast15 -> rows 1,3
    v = dpp_add_u32<0x143, 0xc>(v);            // bcast31 -> rows 2,3
    if (lane == 63) wsum[w] = v;
    __syncthreads();
    unsigned wbase = 0;
#pragma unroll
    for (int j = 0; j < 15; ++j) {             // exclusive prefix of wave totals
        unsigned t = wsum[j];
        wbase += (j < w) ? t : 0u;
    }
    unsigned excl = wbase + v - s;             // global exclusive prefix for bucket 2t
    cnt[2*tid]   = excl;                       // each thread touches only its own pair
    cnt[2*tid+1] = excl + c0;
    __syncthreads();
    // scatter
    for (int p = tid; p < NN; p += 1024) {
        unsigned bk = codes[p];
        unsigned pos = atomicAdd(&cnt[bk], 1u);
        float4 o;
        o.x = xb[3*p+0]; o.y = xb[3*p+1]; o.z = xb[3*p+2];
        o.w = __int_as_float(p);
        sorted[(size_t)b * NN + pos] = o;
    }
}

// ============================================================================
// 1) FPS — R9 version VERBATIM (measured 1341 us; R10's lane63-VGPR atomic
//    variant regressed to 1464 — the lane0 SGPR-packed atomic overlaps the
//    scalar pack with the vector pipe and is the proven-fastest form).
//    16 waves x 512-pt chunks, bbox prune, monolithic u64 DPP reduce, LDS
//    atomicMax merge, ONE barrier per iteration.
//    Bit-exact: atomic max over the same 16 u64 keys, same tie order
//    ((dmin_bits<<32)|~orig_idx; dmin>=0 so u64 order == (f32,~idx) order).
//    3-slot rotation safety (one barrier/iter):
//      iter i: reset slot[(i+1)%3], atomicMax slot[i%3], read slot[i%3].
//      Reset/write/read of any slot are separated by >=1 barrier (R9 proof).
//    Pruning invariant: LB = clamped-bbox dist^2 in the same rounding order
//    certifies whole-wave skip (exact).
// ============================================================================
__global__ __launch_bounds__(1024) void fps_kernel(const float* __restrict__ xyz,
    const float4* __restrict__ sorted,
    float* __restrict__ new_xyz, float* __restrict__ out_newxyz)
{
#pragma clang fp contract(off)
    const int b = blockIdx.x;
    const int tid = threadIdx.x;
    const int w = tid >> 6;
    const int lane = tid & 63;
    __shared__ float sx[NN], sy[NN], sz[NN];             // 96 KB, indexed by ORIG idx
    __shared__ float s_hist[NS * 3];                     // 24 KB selected-coord history
    __shared__ unsigned long long s_slot[3];             // rotating merge slots
    const float4* sp = sorted + (size_t)b * NN + (size_t)w * 512 + lane;
    v2f px[4], py[4], pz[4], dmin[4];
    unsigned plo[8];                                     // ~orig_idx per point
    float bnx = 1e30f, bny = 1e30f, bnz = 1e30f;
    float bxx = -1e30f, bxy = -1e30f, bxz = -1e30f;
#pragma unroll
    for (int m = 0; m < 4; ++m) {
        float4 a = sp[128*m];                            // point k=2m
        float4 c = sp[128*m + 64];                       // point k=2m+1
        px[m].x = a.x; px[m].y = c.x;
        py[m].x = a.y; py[m].y = c.y;
        pz[m].x = a.z; pz[m].y = c.z;
        dmin[m].x = 1e10f; dmin[m].y = 1e10f;
        int ia = __float_as_int(a.w), ic = __float_as_int(c.w);
        plo[2*m]   = ~(unsigned)ia;
        plo[2*m+1] = ~(unsigned)ic;
        sx[ia] = a.x; sy[ia] = a.y; sz[ia] = a.z;        // scatter by orig idx
        sx[ic] = c.x; sy[ic] = c.y; sz[ic] = c.z;
        bnx = fminf(bnx, fminf(a.x, c.x)); bxx = fmaxf(bxx, fmaxf(a.x, c.x));
        bny = fminf(bny, fminf(a.y, c.y)); bxy = fmaxf(bxy, fmaxf(a.y, c.y));
        bnz = fminf(bnz, fminf(a.z, c.z)); bxz = fmaxf(bxz, fmaxf(a.z, c.z));
    }
    // wave bbox (uniform across the wave after readlane-broadcast)
    bnx = wave_red_min(bnx); bny = wave_red_min(bny); bnz = wave_red_min(bnz);
    bxx = wave_red_max(bxx); bxy = wave_red_max(bxy); bxz = wave_red_max(bxz);

    const float* xb = xyz + (size_t)b * NN * 3;
    float lx = xb[0], ly = xb[1], lz = xb[2];            // selection 0 = point 0
    if (tid == 0) {
        s_hist[0] = lx; s_hist[1] = ly; s_hist[2] = lz;
        s_slot[0] = 0ull; s_slot[1] = 0ull; s_slot[2] = 0ull;
    }
    float ckv = 1e30f;                                   // cached wave max dmin (forces 1st compute)
    unsigned cklo = 0u;                                  // cached tie-winner ~orig_idx
    __syncthreads();                                     // sx/sy/sz + slots + hist[0] visible

    int cur = 1, nxt = 2;                                // cur = i%3, nxt = (i+1)%3 at i=1
    for (int i = 1; i < NS; ++i) {
        if (tid == 0) s_slot[nxt] = 0ull;                // reset future slot (safe window)
        // certified fp32 lower bound of d_new for every point in this chunk
        float cdx = fmaxf(fmaxf(bnx - lx, lx - bxx), 0.f);
        float cdy = fmaxf(fmaxf(bny - ly, ly - bxy), 0.f);
        float cdz = fmaxf(fmaxf(bnz - lz, lz - bxz), 0.f);
        float lb = (cdx*cdx + cdy*cdy) + cdz*cdz;
        if (!(lb >= ckv)) {                              // wave-uniform branch
            v2f l2x; l2x.x = lx; l2x.y = lx;
            v2f l2y; l2y.x = ly; l2y.y = ly;
            v2f l2z; l2z.x = lz; l2z.y = lz;
            unsigned long long best = 0ull;
#pragma unroll
            for (int m = 0; m < 4; ++m) {
                v2f dx = px[m] - l2x;
                v2f dy = py[m] - l2y;
                v2f dz = pz[m] - l2z;
                v2f d = (dx*dx + dy*dy) + dz*dz;         // pk mul/add, exact order
                v2f dm;
                dm.x = fminf(dmin[m].x, d.x);
                dm.y = fminf(dmin[m].y, d.y);
                dmin[m] = dm;
                unsigned long long k0 =
                    ((unsigned long long)__float_as_uint(dm.x) << 32) | plo[2*m];
                unsigned long long k1 =
                    ((unsigned long long)__float_as_uint(dm.y) << 32) | plo[2*m+1];
                if (k0 > best) best = k0;
                if (k1 > best) best = k1;
            }
            // MONOLITHIC DPP wave64 max-reduce -> lane 63, broadcast via readlane
            best = dpp_max_u64<0x111>(best);
            best = dpp_max_u64<0x112>(best);
            best = dpp_max_u64<0x114>(best);
            best = dpp_max_u64<0x118>(best);
            best = dpp_max_u64<0x142>(best);
            best = dpp_max_u64<0x143>(best);
            ckv  = __uint_as_float((unsigned)__builtin_amdgcn_readlane((int)(best >> 32), 63));
            cklo = (unsigned)__builtin_amdgcn_readlane((int)(best & 0xffffffffull), 63);
        }
        if (lane == 0)
            atomicMax(&s_slot[cur],
                      ((unsigned long long)__float_as_uint(ckv) << 32) | cklo);
        __syncthreads();                                 // the ONLY barrier per iter
        const unsigned long long k = s_slot[cur];        // b64 broadcast read
        const int ix = ~(int)(unsigned)(k & 0xffffffffull);  // original point index
        lx = sx[ix]; ly = sy[ix]; lz = sz[ix];           // LDS broadcast gather
        if (tid == 0) {
            s_hist[3*i+0] = lx; s_hist[3*i+1] = ly; s_hist[3*i+2] = lz;
        }
        cur = nxt;                                       // rotate slot indices
        nxt = nxt + 1; if (nxt == 3) nxt = 0;
    }
    __syncthreads();                                     // last hist write visible
    // coalesced flush of the selected-coordinate history
    float* nw = new_xyz + (size_t)b * NS * 3;
    float* ow = out_newxyz + (size_t)b * NS * 3;
    for (int t = tid; t < NS * 3; t += 1024) {
        float v = s_hist[t];
        nw[t] = v; ow[t] = v;
    }
}

// ============================================================================
// 2) Transpose features (B,C,N) -> (B,N,C) for contiguous per-point gathers.
// ============================================================================
__global__ __launch_bounds__(256) void transpose_kernel(const float* __restrict__ f,
    float* __restrict__ ft)
{
    __shared__ float tile[64][65];
    int b = blockIdx.y;
    int p0 = blockIdx.x * 64;
    for (int k = threadIdx.x; k < 64*64; k += 256) {
        int c = k >> 6, p = k & 63;
        tile[c][p] = f[((size_t)b * NC + c) * NN + p0 + p];
    }
    __syncthreads();
    for (int k = threadIdx.x; k < 64*64; k += 256) {
        int p = k >> 6, c = k & 63;
        ft[((size_t)b * NN + p0 + p) * NC + c] = tile[c][p];
    }
}

// ============================================================================
// 3) Ball query: one wave per (b,s) query. First 32 smallest in-ball indices,
//    pad with first. r2 must be float(0.2*0.2) = 0.0399999991 (not 0.2f*0.2f).
// ============================================================================
__global__ __launch_bounds__(256) void ballquery_kernel(const float* __restrict__ xyz,
    const float* __restrict__ new_xyz, int* __restrict__ idx)
{
#pragma clang fp contract(off)
    const int q = blockIdx.x * 4 + (threadIdx.x >> 6);
    const int lane = threadIdx.x & 63;
    const int b = q >> 11;
    const float r2 = (float)(0.2 * 0.2);
    const float* xb = xyz + (size_t)b * NN * 3;
    const float* nx = new_xyz + (size_t)q * 3;
    float qx = nx[0], qy = nx[1], qz = nx[2];
    int cnt = 0, first = -1;
    int* out = idx + (size_t)q * NK;
    for (int base = 0; base < NN; base += 64) {
        int p = base + lane;
        float x = xb[p*3+0], y = xb[p*3+1], z = xb[p*3+2];
        float dx = qx - x, dy = qy - y, dz = qz - z;
        float d2 = (dx*dx + dy*dy) + dz*dz;
        bool in = d2 < r2;
        unsigned long long m = __ballot(in);
        if (m) {
            if (first < 0) first = base + __builtin_ctzll(m);
            if (in) {
                int rank = cnt + __popcll(m & ((1ull << lane) - 1ull));
                if (rank < NK) out[rank] = p;
            }
            cnt += __popcll(m);
            if (cnt >= NK) break;
        }
    }
    for (int k = cnt + lane; k < NK; k += 64) out[k] = first;  // cnt>=1 always
}

// ============================================================================
// 4) Layer 1: h1 = W1(64x67) @ g. v2f packed FMAs; h computed in two halves
//    of 32 outputs to keep VGPR below spill point. h1 bf16.
// ============================================================================
__global__ __launch_bounds__(256, 2) void layer1_kernel(const float* __restrict__ xyz,
    const float* __restrict__ new_xyz, const int* __restrict__ idx,
    const float* __restrict__ ft, const float* __restrict__ W1,
    unsigned short* __restrict__ h1)
{
    const int col = blockIdx.x * 256 + threadIdx.x;
    const int b = col >> 16;
    const int s = (col >> 5) & 2047;
    const int p = idx[col];
    v2f g[34];
    float* gf = (float*)g;
    {
        const float* nx = new_xyz + ((size_t)(b * NS + s)) * 3;
        const float* xp = xyz + ((size_t)(b * NN + p)) * 3;
        gf[0] = xp[0] - nx[0]; gf[1] = xp[1] - nx[1]; gf[2] = xp[2] - nx[2];
    }
    const float4* fp = (const float4*)(ft + ((size_t)(b * NN + p)) * NC);
#pragma unroll
    for (int c4 = 0; c4 < 16; ++c4) {
        float4 v = fp[c4];
        gf[3 + 4*c4 + 0] = v.x; gf[3 + 4*c4 + 1] = v.y;
        gf[3 + 4*c4 + 2] = v.z; gf[3 + 4*c4 + 3] = v.w;
    }
    gf[67] = 0.f;
    uint4* dst = (uint4*)(h1 + (size_t)col * 64);
#pragma unroll
    for (int half = 0; half < 2; ++half) {
        float h[32];
#pragma unroll 4
        for (int o16 = 0; o16 < 32; ++o16) {
            const float* w = W1 + (half*32 + o16) * 67;
            v2f acc; acc.x = 0.f; acc.y = 0.f;
#pragma unroll
            for (int k = 0; k < 33; ++k) {
                v2f wv; wv.x = w[2*k]; wv.y = w[2*k+1];
                acc = wv * g[k] + acc;                    // v_pk_fma_f32
            }
            h[o16] = fmaf(w[66], gf[66], acc.x + acc.y);
        }
#pragma unroll
        for (int k = 0; k < 4; ++k) {
            uint4 v;
            v.x = (unsigned)f2bf(h[8*k+0]) | ((unsigned)f2bf(h[8*k+1]) << 16);
            v.y = (unsigned)f2bf(h[8*k+2]) | ((unsigned)f2bf(h[8*k+3]) << 16);
            v.z = (unsigned)f2bf(h[8*k+4]) | ((unsigned)f2bf(h[8*k+5]) << 16);
            v.w = (unsigned)f2bf(h[8*k+6]) | ((unsigned)f2bf(h[8*k+7]) << 16);
            dst[half*4 + k] = v;
        }
    }
}

// ============================================================================
// 5) Stats pass over a bf16 [col][64] tensor: per-channel sum / sumsq.
// ============================================================================
__global__ __launch_bounds__(256) void stats_kernel(const unsigned short* __restrict__ h,
    float* __restrict__ sums)
{
    __shared__ float ls[64], lq[64];
    const int tid = threadIdx.x;
    if (tid < 64) { ls[tid] = 0.f; lq[tid] = 0.f; }
    __syncthreads();
    float s[8] = {0,0,0,0,0,0,0,0}, q[8] = {0,0,0,0,0,0,0,0};
    const int gt = blockIdx.x * 256 + tid;
    const int G = gridDim.x * 256;            // multiple of 8 -> channel phase fixed
    const uint4* src = (const uint4*)h;
    const int nvec = NCOL * 8;                 // uint4s (8 bf16 each)
    for (int i = gt; i < nvec; i += G) {
        uint4 v = src[i];
        float f0 = bf2f(v.x & 0xffffu), f1 = bf2f(v.x >> 16);
        float f2 = bf2f(v.y & 0xffffu), f3 = bf2f(v.y >> 16);
        float f4 = bf2f(v.z & 0xffffu), f5 = bf2f(v.z >> 16);
        float f6 = bf2f(v.w & 0xffffu), f7 = bf2f(v.w >> 16);
        s[0] += f0; q[0] = fmaf(f0, f0, q[0]);
        s[1] += f1; q[1] = fmaf(f1, f1, q[1]);
        s[2] += f2; q[2] = fmaf(f2, f2, q[2]);
        s[3] += f3; q[3] = fmaf(f3, f3, q[3]);
        s[4] += f4; q[4] = fmaf(f4, f4, q[4]);
        s[5] += f5; q[5] = fmaf(f5, f5, q[5]);
        s[6] += f6; q[6] = fmaf(f6, f6, q[6]);
        s[7] += f7; q[7] = fmaf(f7, f7, q[7]);
    }
    const int obase = (tid & 7) * 8;
#pragma unroll
    for (int j = 0; j < 8; ++j) {
        atomicAdd(&ls[obase + j], s[j]);
        atomicAdd(&lq[obase + j], q[j]);
    }
    __syncthreads();
    if (tid < 64) {
        atomicAdd(&sums[tid*2+0], ls[tid]);
        atomicAdd(&sums[tid*2+1], lq[tid]);
    }
}

// ============================================================================
// 6) Finalize BN params. Layout: ab[c] = a_c (scale), ab[nch+c] = b_c (shift)
//    so the apply step can use packed v2f math.
// ============================================================================
__global__ void finalize_kernel(const float* __restrict__ sums,
    const float* __restrict__ gamma, const float* __restrict__ beta,
    float* __restrict__ ab, int nch)
{
    int c = threadIdx.x;
    if (c < nch) {
        const float invM = 1.0f / 524288.0f;
        float mu = sums[c*2] * invM;
        float var = sums[c*2+1] * invM - mu * mu;
        float a = gamma[c] / sqrtf(var + 1e-5f);
        ab[c] = a;
        ab[nch + c] = fmaf(-mu, a, beta[c]);
    }
}

// ============================================================================
// 7) Layer 2: g2 = relu(BN1(h1)); h2 = W2(64x64) @ g2. Packed FMAs, halves.
// ============================================================================
__global__ __launch_bounds__(256, 2) void layer2_kernel(const unsigned short* __restrict__ h1,
    const float* __restrict__ ab1, const float* __restrict__ W2,
    unsigned short* __restrict__ h2)
{
    const int col = blockIdx.x * 256 + threadIdx.x;
    const uint4* src = (const uint4*)(h1 + (size_t)col * 64);
    v2f g[32];
    float* gf = (float*)g;
#pragma unroll
    for (int k = 0; k < 8; ++k) {
        uint4 v = src[k];
        gf[8*k+0] = bf2f(v.x & 0xffffu); gf[8*k+1] = bf2f(v.x >> 16);
        gf[8*k+2] = bf2f(v.y & 0xffffu); gf[8*k+3] = bf2f(v.y >> 16);
        gf[8*k+4] = bf2f(v.z & 0xffffu); gf[8*k+5] = bf2f(v.z >> 16);
        gf[8*k+6] = bf2f(v.w & 0xffffu); gf[8*k+7] = bf2f(v.w >> 16);
    }
    const v2f* a2 = (const v2f*)ab1;
    const v2f* b2 = (const v2f*)(ab1 + 64);
#pragma unroll
    for (int k = 0; k < 32; ++k)
        g[k] = relu2(a2[k] * g[k] + b2[k]);               // pk_fma + pk_max
    uint4* dst = (uint4*)(h2 + (size_t)col * 64);
#pragma unroll
    for (int half = 0; half < 2; ++half) {
        float h[32];
#pragma unroll 4
        for (int o16 = 0; o16 < 32; ++o16) {
            const float* w = W2 + ((half*32 + o16) << 6);
            v2f acc; acc.x = 0.f; acc.y = 0.f;
#pragma unroll
            for (int k = 0; k < 32; ++k) {
                v2f wv; wv.x = w[2*k]; wv.y = w[2*k+1];
                acc = wv * g[k] + acc;
            }
            h[o16] = acc.x + acc.y;
        }
#pragma unroll
        for (int k = 0; k < 4; ++k) {
            uint4 v;
            v.x = (unsigned)f2bf(h[8*k+0]) | ((unsigned)f2bf(h[8*k+1]) << 16);
            v.y = (unsigned)f2bf(h[8*k+2]) | ((unsigned)f2bf(h[8*k+3]) << 16);
            v.z = (unsigned)f2bf(h[8*k+4]) | ((unsigned)f2bf(h[8*k+5]) << 16);
            v.w = (unsigned)f2bf(h[8*k+6]) | ((unsigned)f2bf(h[8*k+7]) << 16);
            dst[half*4 + k] = v;
        }
    }
}

// ============================================================================
// 8) Layer 3 via MFMA (bf16 in, f32 acc): h3 = W3(128x64) @ relu(BN2(h2)).
//    R10 version (proven: tail 698 -> 565 us, absmax 0.046875 < threshold).
//    Tiles: D[16 out][16 col] via mfma_f32_16x16x32_bf16, K=64 in 2 steps.
//    Fragment layouts (m89-verified D; A/B per AMD lab-notes convention):
//      A[m][k]: m = lane&15, k = (lane>>4)*8 + j   (8 bf16 / lane)
//      B[k][n]: n = lane&15, k = (lane>>4)*8 + j
//      D[m][n]: n = lane&15, m = (lane>>4)*4 + reg (4 f32 / lane)
//    One wave owns one (b,s)-group (32 cols = 2 tiles held simultaneously
//    -> group max/min combine in-register -> hmax/hmin layout unchanged).
// ============================================================================
__global__ __launch_bounds__(256, 2) void layer3_kernel(const unsigned short* __restrict__ h2,
    const float* __restrict__ ab2, const float* __restrict__ W3,
    float* __restrict__ hmax, float* __restrict__ hmin, float* __restrict__ sums3)
{
    __shared__ float ls[128], lq[128];
    const int tid = threadIdx.x;
    if (tid < 128) { ls[tid] = 0.f; lq[tid] = 0.f; }
    __syncthreads();
    const int lane = tid & 63;
    const int col0 = lane & 15;                          // n (col in tile) / m (row of A)
    const int rg   = lane >> 4;                          // k-group (input frags), row-group (D)
    const int wglob = blockIdx.x * 4 + (tid >> 6);       // 0..8191

    float sums[32], sqs[32];                             // [rt][reg]
#pragma unroll
    for (int t = 0; t < 32; ++t) { sums[t] = 0.f; sqs[t] = 0.f; }

    for (int g = wglob * 2; g < wglob * 2 + 2; ++g) {    // 2 (b,s)-groups per wave
        // ---- build B fragments for both 16-col tiles of this group ----
        bf16x8 Bf[2][2];                                 // [tile][kh]
#pragma unroll
        for (int t = 0; t < 2; ++t) {
            const int col = g * 32 + t * 16 + col0;
            const unsigned short* hp = h2 + (size_t)col * 64 + rg * 8;
#pragma unroll
            for (int kh = 0; kh < 2; ++kh) {
                uint4 hv = *(const uint4*)(hp + kh * 32);
                const float* ap = ab2 + kh * 32 + rg * 8;
                float4 a0 = *(const float4*)ap;
                float4 a1 = *(const float4*)(ap + 4);
                float4 b0 = *(const float4*)(ap + 64);
                float4 b1 = *(const float4*)(ap + 68);
                bf16x8 f;
                f[0] = (short)f2bf(fmaxf(fmaf(a0.x, bf2f(hv.x & 0xffffu), b0.x), 0.f));
                f[1] = (short)f2bf(fmaxf(fmaf(a0.y, bf2f(hv.x >> 16),     b0.y), 0.f));
                f[2] = (short)f2bf(fmaxf(fmaf(a0.z, bf2f(hv.y & 0xffffu), b0.z), 0.f));
                f[3] = (short)f2bf(fmaxf(fmaf(a0.w, bf2f(hv.y >> 16),     b0.w), 0.f));
                f[4] = (short)f2bf(fmaxf(fmaf(a1.x, bf2f(hv.z & 0xffffu), b1.x), 0.f));
                f[5] = (short)f2bf(fmaxf(fmaf(a1.y, bf2f(hv.z >> 16),     b1.y), 0.f));
                f[6] = (short)f2bf(fmaxf(fmaf(a1.z, bf2f(hv.w & 0xffffu), b1.z), 0.f));
                f[7] = (short)f2bf(fmaxf(fmaf(a1.w, bf2f(hv.w >> 16),     b1.w), 0.f));
                Bf[t][kh] = f;
            }
        }
        // ---- 8 row-tiles of 16 output channels ----
#pragma unroll
        for (int rt = 0; rt < 8; ++rt) {
            f32x4 acc0 = {0.f, 0.f, 0.f, 0.f};
            f32x4 acc1 = {0.f, 0.f, 0.f, 0.f};
#pragma unroll
            for (int kh = 0; kh < 2; ++kh) {
                const float* wp = W3 + (size_t)(rt * 16 + col0) * 64 + kh * 32 + rg * 8;
                float4 w0 = *(const float4*)wp;
                float4 w1 = *(const float4*)(wp + 4);
                bf16x8 Af;
                Af[0] = (short)f2bf(w0.x); Af[1] = (short)f2bf(w0.y);
                Af[2] = (short)f2bf(w0.z); Af[3] = (short)f2bf(w0.w);
                Af[4] = (short)f2bf(w1.x); Af[5] = (short)f2bf(w1.y);
                Af[6] = (short)f2bf(w1.z); Af[7] = (short)f2bf(w1.w);
                acc0 = __builtin_amdgcn_mfma_f32_16x16x32_bf16(Af, Bf[0][kh], acc0, 0, 0, 0);
                acc1 = __builtin_amdgcn_mfma_f32_16x16x32_bf16(Af, Bf[1][kh], acc1, 0, 0, 0);
            }
#pragma unroll
            for (int r = 0; r < 4; ++r) {
                float v0 = acc0[r], v1 = acc1[r];
                sums[rt*4 + r] += v0 + v1;
                sqs[rt*4 + r]  = fmaf(v0, v0, fmaf(v1, v1, sqs[rt*4 + r]));
                float mx = fmaxf(v0, v1);
                float mn = fminf(v0, v1);
                mx = dpp_max_f32<0x111>(mx); mn = dpp_min_f32<0x111>(mn);
                mx = dpp_max_f32<0x112>(mx); mn = dpp_min_f32<0x112>(mn);
                mx = dpp_max_f32<0x114>(mx); mn = dpp_min_f32<0x114>(mn);
                mx = dpp_max_f32<0x118>(mx); mn = dpp_min_f32<0x118>(mn);
                if (col0 == 15) {                        // lane15 of each 16-lane row
                    const int o = rt * 16 + rg * 4 + r;
                    hmax[(size_t)o * 16384 + g] = mx;
                    hmin[(size_t)o * 16384 + g] = mn;
                }
            }
        }
    }
    // ---- channel sums: reduce over cols (16-lane rows), then LDS -> global
#pragma unroll
    for (int t = 0; t < 32; ++t) {
        float sm = sums[t], sq = sqs[t];
        sm = dpp_add_f32<0x111>(sm); sq = dpp_add_f32<0x111>(sq);
        sm = dpp_add_f32<0x112>(sm); sq = dpp_add_f32<0x112>(sq);
        sm = dpp_add_f32<0x114>(sm); sq = dpp_add_f32<0x114>(sq);
        sm = dpp_add_f32<0x118>(sm); sq = dpp_add_f32<0x118>(sq);
        if (col0 == 15) {
            const int o = (t >> 2) * 16 + rg * 4 + (t & 3);
            atomicAdd(&ls[o], sm);
            atomicAdd(&lq[o], sq);
        }
    }
    __syncthreads();
    if (tid < 128) {
        atomicAdd(&sums3[tid*2+0], ls[tid]);
        atomicAdd(&sums3[tid*2+1], lq[tid]);
    }
}

// ============================================================================
// 9) Final: feats[b,o,s] = relu(a3*(a3>=0 ? max : min) + c3)
// ============================================================================
__global__ __launch_bounds__(256) void final_kernel(const float* __restrict__ hmax,
    const float* __restrict__ hmin, const float* __restrict__ ab3,
    float* __restrict__ out)
{
    const int t = blockIdx.x * 256 + threadIdx.x;   // (b,o,s), s fastest
    const int s = t & 2047;
    const int o = (t >> 11) & 127;
    const int b = t >> 18;
    const int q = (b << 11) + s;
    float a = ab3[o], c = ab3[128 + o];
    float h = (a >= 0.f) ? hmax[(size_t)o * 16384 + q] : hmin[(size_t)o * 16384 + q];
    out[t] = fmaxf(fmaf(a, h, c), 0.f);
}

// ============================================================================
extern "C" void kernel_launch(void* const* d_in, const int* in_sizes, int n_in,
                              void* d_out, int out_size, void* d_ws, size_t ws_size,
                              hipStream_t stream) {
    (void)in_sizes; (void)n_in; (void)out_size; (void)ws_size;
    const float* xyz      = (const float*)d_in[0];
    const float* features = (const float*)d_in[1];
    const float* W1 = (const float*)d_in[2];
    const float* g1 = (const float*)d_in[3];
    const float* b1 = (const float*)d_in[4];
    const float* W2 = (const float*)d_in[5];
    const float* g2 = (const float*)d_in[6];
    const float* b2 = (const float*)d_in[7];
    const float* W3 = (const float*)d_in[8];
    const float* g3 = (const float*)d_in[9];
    const float* b3 = (const float*)d_in[10];

    char* ws = (char*)d_ws;
    float*          new_xyz = (float*)(ws + 0);                  // 196608 B
    int*            idx     = (int*)(ws + 196608);               // 2097152 B
    float*          ft      = (float*)(ws + 2293760);            // 16777216 B
    unsigned short* h1      = (unsigned short*)(ws + 19070976);  // 67108864 B
    unsigned short* h2      = (unsigned short*)(ws + 86179840);  // 67108864 B
    float*          hmax    = (float*)(ws + 153288704);          // 8388608 B
    float*          hmin    = (float*)(ws + 161677312);          // 8388608 B
    float*          sums    = (float*)(ws + 170065920);          // 2048 B (zeroed)
    float*          ab      = (float*)(ws + 170067968);          // 2048 B
    float* sums1 = sums;        float* ab1 = ab;
    float* sums2 = sums + 128;  float* ab2 = ab + 128;
    float* sums3 = sums + 256;  float* ab3 = ab + 256;

    // sorted point array (float4 x,y,z,idx) lives in h1's space: h1 is only
    // written by layer1 AFTER fps completes (stream order), so no conflict.
    float4* sorted = (float4*)h1;                 // NB*NN*16 = 1 MB

    float* out_newxyz = (float*)d_out;            // B*NS*3 = 49152 floats
    float* out_feats  = (float*)d_out + 49152;    // B*128*NS floats

    hipMemsetAsync(sums, 0, 2048, stream);

    sort_kernel<<<NB, 1024, 0, stream>>>(xyz, sorted);
    fps_kernel<<<NB, 1024, 0, stream>>>(xyz, sorted, new_xyz, out_newxyz);
    transpose_kernel<<<dim3(NN/64, NB), 256, 0, stream>>>(features, ft);
    ballquery_kernel<<<(NB*NS)/4, 256, 0, stream>>>(xyz, new_xyz, idx);
    layer1_kernel<<<NCOL/256, 256, 0, stream>>>(xyz, new_xyz, idx, ft, W1, h1);
    stats_kernel<<<1024, 256, 0, stream>>>(h1, sums1);
    finalize_kernel<<<1, 128, 0, stream>>>(sums1, g1, b1, ab1, 64);
    layer2_kernel<<<NCOL/256, 256, 0, stream>>>(h1, ab1, W2, h2);
    stats_kernel<<<1024, 256, 0, stream>>>(h2, sums2);
    finalize_kernel<<<1, 128, 0, stream>>>(sums2, g2, b2, ab2, 64);
    layer3_kernel<<<NCOL/256, 256, 0, stream>>>(h2, ab2, W3, hmax, hmin, sums3);
    finalize_kernel<<<1, 128, 0, stream>>>(sums3, g3, b3, ab3, 128);
    final_kernel<<<(NB*128*NS)/256, 256, 0, stream>>>(hmax, hmin, ab3, out_feats);
}